// Round 2
// baseline (809.419 us; speedup 1.0000x reference)
//
#include <hip/hip_runtime.h>

#define N_PIX 16384
#define CDIM  256
#define HIDD  1024
#define BNS   0.9999950000374997f   // (1+1e-5)^-0.5

typedef __attribute__((ext_vector_type(8))) short  short8;
typedef __attribute__((ext_vector_type(4))) float  f32x4;
typedef __attribute__((ext_vector_type(4))) int    int4v;
typedef __attribute__((ext_vector_type(2))) int    int2v;

__device__ __forceinline__ float b2f(unsigned short u){
  unsigned int x = ((unsigned int)u) << 16; float f;
  __builtin_memcpy(&f, &x, 4); return f;
}
__device__ __forceinline__ unsigned short f2b(float f){
  unsigned int x; __builtin_memcpy(&x, &f, 4);
  unsigned int r = (x + 0x7fffu + ((x >> 16) & 1u)) >> 16;
  return (unsigned short)r;
}
__device__ __forceinline__ float geluf(float x){
  return 0.5f * x * (1.0f + erff(x * 0.70710678118654752f));
}

// ---------------- fp32 -> bf16 conversion (weights) ---------------------------
__global__ __launch_bounds__(256) void k_cvt(const float* __restrict__ src,
                                             unsigned short* __restrict__ dst, int n){
  int i = (blockIdx.x * 256 + threadIdx.x) * 8;
  if (i >= n) return;
  f32x4 a = *(const f32x4*)(src + i);
  f32x4 b = *(const f32x4*)(src + i + 4);
  unsigned short o[8];
  #pragma unroll
  for (int j = 0; j < 4; ++j){ o[j] = f2b(a[j]); o[4 + j] = f2b(b[j]); }
  *(int4v*)(dst + i) = *(int4v*)o;
}

// ---------------- transpose: x [B,C,4096] f32 -> Xpm [N,256] bf16 --------------
__global__ __launch_bounds__(256) void k_transpose(const float* __restrict__ x,
                                                   unsigned short* __restrict__ xpm){
  __shared__ __align__(16) unsigned short tile[64][72];
  int b = blockIdx.z, c0 = blockIdx.y * 64, p0 = blockIdx.x * 64;
  int t = threadIdx.x;
  int r = t >> 3, k = t & 7;
  for (int s = 0; s < 2; ++s){
    int rr = r + s * 32;
    const float* src = x + (((size_t)(b * CDIM + c0 + rr)) << 12) + p0 + k * 8;
    f32x4 a = *(const f32x4*)src;
    f32x4 c = *(const f32x4*)(src + 4);
    unsigned short tmp[8];
    #pragma unroll
    for (int j = 0; j < 4; ++j){ tmp[j] = f2b(a[j]); tmp[4 + j] = f2b(c[j]); }
    *(int4v*)&tile[rr][k * 8] = *(int4v*)tmp;
  }
  __syncthreads();
  for (int s = 0; s < 2; ++s){
    int pr = r + s * 32;
    unsigned short tmp[8];
    #pragma unroll
    for (int j = 0; j < 8; ++j) tmp[j] = tile[k * 8 + j][pr];
    unsigned short* dst = xpm + (((size_t)(b * 4096 + p0 + pr)) << 8) + c0 + k * 8;
    *(int4v*)dst = *(int4v*)tmp;
  }
}

// ---------------- LayerNorm over C=256 (one row per wave) ----------------------
template<typename IT>
__global__ __launch_bounds__(256) void k_ln(const IT* __restrict__ in,
    const float* __restrict__ w, const float* __restrict__ bia,
    unsigned short* __restrict__ out){
  int row  = blockIdx.x * 4 + (threadIdx.x >> 6);
  int lane = threadIdx.x & 63;
  float v[4];
  const IT* p = in + (size_t)row * CDIM + lane * 4;
  if constexpr (sizeof(IT) == 2){
    int2v d = *(const int2v*)p;
    unsigned short tmp[4]; __builtin_memcpy(tmp, &d, 8);
    #pragma unroll
    for (int j = 0; j < 4; ++j) v[j] = b2f(tmp[j]);
  } else {
    f32x4 d = *(const f32x4*)p;
    #pragma unroll
    for (int j = 0; j < 4; ++j) v[j] = d[j];
  }
  float s  = v[0] + v[1] + v[2] + v[3];
  float s2 = v[0]*v[0] + v[1]*v[1] + v[2]*v[2] + v[3]*v[3];
  #pragma unroll
  for (int m = 1; m < 64; m <<= 1){
    s  += __shfl_xor(s,  m);
    s2 += __shfl_xor(s2, m);
  }
  float mu   = s * (1.0f / 256.0f);
  float var  = s2 * (1.0f / 256.0f) - mu * mu;
  float rstd = rsqrtf(var + 1e-5f);
  unsigned short o[4];
  #pragma unroll
  for (int j = 0; j < 4; ++j){
    int c = lane * 4 + j;
    o[j] = f2b((v[j] - mu) * rstd * w[c] + bia[c]);
  }
  *(int2v*)(out + (size_t)row * CDIM + lane * 4) = *(int2v*)o;
}

// ---------------- MFMA GEMM: C[M,Nout] = A[M,K] * Bw[Nout,ldb]^T + epilogue ----
// 128x128 tile, 4 waves, each wave 64x64 via 4x4 x mfma_f32_16x16x32_bf16
template<int MODE>
__global__ __launch_bounds__(256) void k_gemm(
    const unsigned short* __restrict__ A, const unsigned short* __restrict__ Bw,
    int K, int Nout, int ldb, void* __restrict__ outp,
    const float* __restrict__ bias,
    const float* __restrict__ bng,
    const float* __restrict__ bnb,
    const float* __restrict__ auxf,   // MODE1: x (NCHW f32); MODE3: pool_bias; MODE5: TR f32
    int catoff)
{
  __shared__ __align__(16) unsigned short As[128][40];
  __shared__ __align__(16) unsigned short Bs[128][40];
  int t = threadIdx.x;
  int m0 = blockIdx.y * 128, n0 = blockIdx.x * 128;
  int wave = t >> 6, lane = t & 63;
  int wm = wave >> 1, wn = wave & 1;
  int lr = lane & 15, kb = lane >> 4;

  f32x4 acc[4][4];
  f32x4 z = {0.f, 0.f, 0.f, 0.f};
  #pragma unroll
  for (int i = 0; i < 4; ++i)
    #pragma unroll
    for (int j = 0; j < 4; ++j) acc[i][j] = z;

  int r = t >> 2, cc = t & 3;  // staging: rows r, r+64 ; 4 chunks of 8 bf16 per row
  for (int k0 = 0; k0 < K; k0 += 32){
    #pragma unroll
    for (int s = 0; s < 2; ++s){
      int rr = r + s * 64;
      *(int4v*)&As[rr][cc * 8] = *(const int4v*)&A [(size_t)(m0 + rr) * K   + k0 + cc * 8];
      *(int4v*)&Bs[rr][cc * 8] = *(const int4v*)&Bw[(size_t)(n0 + rr) * ldb + k0 + cc * 8];
    }
    __syncthreads();
    short8 af[4], bf_[4];
    #pragma unroll
    for (int i = 0; i < 4; ++i) af [i] = *(const short8*)&As[wm * 64 + i * 16 + lr][kb * 8];
    #pragma unroll
    for (int j = 0; j < 4; ++j) bf_[j] = *(const short8*)&Bs[wn * 64 + j * 16 + lr][kb * 8];
    #pragma unroll
    for (int i = 0; i < 4; ++i)
      #pragma unroll
      for (int j = 0; j < 4; ++j)
        acc[i][j] = __builtin_amdgcn_mfma_f32_16x16x32_bf16(af[i], bf_[j], acc[i][j], 0, 0, 0);
    __syncthreads();
  }

  #pragma unroll
  for (int i = 0; i < 4; ++i){
    int rowb = m0 + wm * 64 + i * 16 + kb * 4;
    #pragma unroll
    for (int j = 0; j < 4; ++j){
      int col = n0 + wn * 64 + j * 16 + lr;
      #pragma unroll
      for (int rr = 0; rr < 4; ++rr){
        int row = rowb + rr;
        float v = acc[i][j][rr];
        if constexpr (MODE == 0){            // QKV: plain bf16 store
          ((unsigned short*)outp)[(size_t)row * Nout + col] = f2b(v);
        } else if constexpr (MODE == 1){     // proj + bias + residual(x, exact f32) -> CAT
          int b = row >> 12, hw = row & 4095;
          v += bias[col] + auxf[(((size_t)(b * CDIM + col)) << 12) + hw];
          ((unsigned short*)outp)[(size_t)row * HIDD + catoff + col] = f2b(v);
        } else if constexpr (MODE == 2){     // tc_conv: bias, bn1, relu -> CAT[:,0:256]
          v = (v + bias[col]) * (bng[col] * BNS) + bnb[col];
          v = fmaxf(v, 0.0f);
          ((unsigned short*)outp)[(size_t)row * HIDD + col] = f2b(v);
        } else if constexpr (MODE == 3){     // tc_trans: + bias + pool_bias, bn3, relu -> TR f32
          v += bias[col] + auxf[((row >> 12) << 8) + col];
          v = v * (bng[col] * BNS) + bnb[col];
          v = fmaxf(v, 0.0f);
          ((float*)outp)[(size_t)row * CDIM + col] = v;
        } else if constexpr (MODE == 4){     // mlp_c1: bias, gelu, bn1 -> H bf16
          v = geluf(v + bias[col]);
          v = v * (bng[col] * BNS) + bnb[col];
          ((unsigned short*)outp)[(size_t)row * HIDD + col] = f2b(v);
        } else {                             // MODE 5: mlp_c2: bias, bn3, +TR, store NCHW f32
          v = (v + bias[col]) * (bng[col] * BNS) + bnb[col];
          v += auxf[(size_t)row * CDIM + col];
          int b = row >> 12, hw = row & 4095;
          ((float*)outp)[(((size_t)(b * CDIM + col)) << 12) + hw] = v;
        }
      }
    }
  }
}

// ---------------- atrous 9-neighbor attention (per pixel, per head) ------------
__global__ __launch_bounds__(256) void k_attn(const unsigned short* __restrict__ QKV,
                                              unsigned short* __restrict__ ATT, int r){
  int t = blockIdx.x * 256 + threadIdx.x;     // 0 .. 131071
  int head = t & 7, pix = t >> 3;
  int hw = pix & 4095, h = hw >> 6, w = hw & 63;
  const unsigned short* base = QKV + (size_t)pix * 768 + head * 32;

  float q[32];
  #pragma unroll
  for (int c8 = 0; c8 < 4; ++c8){
    int4v d = *(const int4v*)(base + c8 * 8);
    unsigned short tmp[8]; __builtin_memcpy(tmp, &d, 16);
    #pragma unroll
    for (int j = 0; j < 8; ++j) q[c8 * 8 + j] = b2f(tmp[j]);
  }
  float logit[9];
  #pragma unroll
  for (int jj = 0; jj < 9; ++jj){
    int dh = (jj / 3 - 1) * r, dw = (jj % 3 - 1) * r;
    int hh = h + dh, ww = w + dw;
    float d = 0.0f;
    if (hh >= 0 && hh < 64 && ww >= 0 && ww < 64){
      const unsigned short* kr = base + (dh * 64 + dw) * 768 + 256;
      #pragma unroll
      for (int c8 = 0; c8 < 4; ++c8){
        int4v dd = *(const int4v*)(kr + c8 * 8);
        unsigned short tmp[8]; __builtin_memcpy(tmp, &dd, 16);
        #pragma unroll
        for (int j = 0; j < 8; ++j) d += q[c8 * 8 + j] * b2f(tmp[j]);
      }
    }
    logit[jj] = d * 0.17677669529663687f;   // hd^-0.5, OOB taps keep logit 0 (zero-pad)
  }
  float m = logit[0];
  #pragma unroll
  for (int jj = 1; jj < 9; ++jj) m = fmaxf(m, logit[jj]);
  float p[9], s = 0.0f;
  #pragma unroll
  for (int jj = 0; jj < 9; ++jj){ p[jj] = __expf(logit[jj] - m); s += p[jj]; }
  float inv = 1.0f / s;
  float o[32];
  #pragma unroll
  for (int j = 0; j < 32; ++j) o[j] = 0.0f;
  #pragma unroll
  for (int jj = 0; jj < 9; ++jj){
    int dh = (jj / 3 - 1) * r, dw = (jj % 3 - 1) * r;
    int hh = h + dh, ww = w + dw;
    if (hh >= 0 && hh < 64 && ww >= 0 && ww < 64){
      float pj = p[jj] * inv;
      const unsigned short* vr = base + (dh * 64 + dw) * 768 + 512;
      #pragma unroll
      for (int c8 = 0; c8 < 4; ++c8){
        int4v dd = *(const int4v*)(vr + c8 * 8);
        unsigned short tmp[8]; __builtin_memcpy(tmp, &dd, 16);
        #pragma unroll
        for (int j = 0; j < 8; ++j) o[c8 * 8 + j] += pj * b2f(tmp[j]);
      }
    }
  }
  unsigned short ob[32];
  #pragma unroll
  for (int j = 0; j < 32; ++j) ob[j] = f2b(o[j]);
  unsigned short* op = ATT + (size_t)pix * CDIM + head * 32;
  #pragma unroll
  for (int c8 = 0; c8 < 4; ++c8) *(int4v*)(op + c8 * 8) = *(int4v*)&ob[c8 * 8];
}

// ---------------- depthwise 3x3 + gelu + bn2 -----------------------------------
__global__ __launch_bounds__(256) void k_dwconv(const unsigned short* __restrict__ H,
    const float* __restrict__ dww, const float* __restrict__ dwb,
    const float* __restrict__ g, const float* __restrict__ bb,
    unsigned short* __restrict__ H2){
  int t = blockIdx.x * 256 + threadIdx.x;   // 16384 * 128
  int chunk = t & 127, pix = t >> 7;
  int hw = pix & 4095, h = hw >> 6, w = hw & 63;
  int c0 = chunk * 8;
  float acc[8], hc[8];
  {
    int4v dd = *(const int4v*)(H + (size_t)pix * HIDD + c0);
    unsigned short tmp[8]; __builtin_memcpy(tmp, &dd, 16);
    #pragma unroll
    for (int j = 0; j < 8; ++j){ hc[j] = b2f(tmp[j]); acc[j] = 0.0f; }
  }
  #pragma unroll
  for (int di = -1; di <= 1; ++di)
    #pragma unroll
    for (int dj = -1; dj <= 1; ++dj){
      int hh = h + di, ww = w + dj;
      if (hh < 0 || hh >= 64 || ww < 0 || ww >= 64) continue;
      int kk = (di + 1) * 3 + (dj + 1);
      int4v dd = *(const int4v*)(H + ((size_t)(pix + di * 64 + dj)) * HIDD + c0);
      unsigned short tmp[8]; __builtin_memcpy(tmp, &dd, 16);
      #pragma unroll
      for (int j = 0; j < 8; ++j) acc[j] += dww[(c0 + j) * 9 + kk] * b2f(tmp[j]);
    }
  unsigned short ob[8];
  #pragma unroll
  for (int j = 0; j < 8; ++j){
    float v = acc[j] + dwb[c0 + j] + hc[j];
    v = geluf(v);
    v = v * (g[c0 + j] * BNS) + bb[c0 + j];
    ob[j] = f2b(v);
  }
  *(int4v*)(H2 + (size_t)pix * HIDD + c0) = *(int4v*)ob;
}

// ---------------- pool path ----------------------------------------------------
__global__ __launch_bounds__(256) void k_pool_mean(const float* __restrict__ x,
                                                   float* __restrict__ pm){
  int bc = blockIdx.x;
  const float* p = x + ((size_t)bc << 12);
  int t = threadIdx.x;
  float s = 0.0f;
  for (int i = t * 4; i < 4096; i += 1024){
    f32x4 dd = *(const f32x4*)(p + i);
    s += dd[0] + dd[1] + dd[2] + dd[3];
  }
  #pragma unroll
  for (int m = 1; m < 64; m <<= 1) s += __shfl_xor(s, m);
  __shared__ float red[4];
  if ((t & 63) == 0) red[t >> 6] = s;
  __syncthreads();
  if (t == 0) pm[bc] = (red[0] + red[1] + red[2] + red[3]) * (1.0f / 4096.0f);
}

__global__ __launch_bounds__(256) void k_pool_feat(const float* __restrict__ pm,
    const float* __restrict__ pw, const float* __restrict__ g,
    const float* __restrict__ bb, float* __restrict__ pf){
  int b = blockIdx.x, o = threadIdx.x;
  __shared__ float v[256];
  v[o] = pm[b * 256 + o];
  __syncthreads();
  float acc = 0.0f;
  const float* wr = pw + (size_t)o * 256;
  for (int c = 0; c < 256; ++c) acc += v[c] * wr[c];
  float val = acc * (g[o] * BNS) + bb[o];
  pf[b * 256 + o] = fmaxf(val, 0.0f);
}

__global__ __launch_bounds__(256) void k_pool_bias(const float* __restrict__ pf,
    const float* __restrict__ tw, float* __restrict__ pb){
  int b = blockIdx.x, o = threadIdx.x;
  __shared__ float v[256];
  v[o] = pf[b * 256 + o];
  __syncthreads();
  float acc = 0.0f;
  const float* wr = tw + (size_t)o * 1280 + 1024;
  for (int c = 0; c < 256; ++c) acc += v[c] * wr[c];
  pb[b * 256 + o] = acc;
}

// ---------------- launch -------------------------------------------------------
extern "C" void kernel_launch(void* const* d_in, const int* in_sizes, int n_in,
                              void* d_out, int out_size, void* d_ws, size_t ws_size,
                              hipStream_t stream){
  const float* x     = (const float*)d_in[0];
  const float* ln1w  = (const float*)d_in[1];
  const float* ln1b  = (const float*)d_in[2];
  const float* ln2w  = (const float*)d_in[3];
  const float* ln2b  = (const float*)d_in[4];
  const float* qkvw[3]  = {(const float*)d_in[5], (const float*)d_in[8],  (const float*)d_in[11]};
  const float* projw[3] = {(const float*)d_in[6], (const float*)d_in[9],  (const float*)d_in[12]};
  const float* projb[3] = {(const float*)d_in[7], (const float*)d_in[10], (const float*)d_in[13]};
  const float* tcw   = (const float*)d_in[14];
  const float* tcb   = (const float*)d_in[15];
  const float* bn1g  = (const float*)d_in[16];
  const float* bn1b  = (const float*)d_in[17];
  const float* poolw = (const float*)d_in[18];
  const float* bn2g  = (const float*)d_in[19];
  const float* bn2b  = (const float*)d_in[20];
  const float* trw   = (const float*)d_in[21];
  const float* trb   = (const float*)d_in[22];
  const float* bn3g  = (const float*)d_in[23];
  const float* bn3b  = (const float*)d_in[24];
  const float* c1w   = (const float*)d_in[25];
  const float* c1b   = (const float*)d_in[26];
  const float* mbn1g = (const float*)d_in[27];
  const float* mbn1b = (const float*)d_in[28];
  const float* dww   = (const float*)d_in[29];
  const float* dwb   = (const float*)d_in[30];
  const float* mbn2g = (const float*)d_in[31];
  const float* mbn2b = (const float*)d_in[32];
  const float* c2w   = (const float*)d_in[33];
  const float* c2b   = (const float*)d_in[34];
  const float* mbn3g = (const float*)d_in[35];
  const float* mbn3b = (const float*)d_in[36];

  char* ws = (char*)d_ws;
  unsigned short* Xpm = (unsigned short*)(ws);                 //  8.4 MB [N,256] bf16
  unsigned short* N1  = (unsigned short*)(ws + 8388608);       //  8.4 MB [N,256] (later N2)
  unsigned short* CAT = (unsigned short*)(ws + 16777216);      // 33.6 MB [N,1024] xc1|t1|t2|t3
  float*          TR  = (float*)        (ws + 50331648);       // 16.8 MB [N,256] fp32
  unsigned short* E   = (unsigned short*)(ws + 67108864);      // 33.6 MB QKV then H
  unsigned short* F   = (unsigned short*)(ws + 100663296);     // 33.6 MB ATT then H2
  // bf16 weight staging area
  unsigned short* Wb    = (unsigned short*)(ws + 134217728);
  unsigned short* qkvb[3]  = {Wb, Wb + 196608, Wb + 393216};            // 3 x 196608
  unsigned short* projbw[3] = {Wb + 589824, Wb + 655360, Wb + 720896};  // 3 x 65536
  unsigned short* tcwb  = Wb + 786432;                                  // 65536
  unsigned short* trwb  = Wb + 851968;                                  // 327680
  unsigned short* c1wb  = Wb + 1179648;                                 // 262144
  unsigned short* c2wb  = Wb + 1441792;                                 // 262144
  float*          pm  = (float*)(ws + 134217728 + 3407872);
  float*          pf  = pm + 1024;
  float*          pb  = pf + 1024;

  // weight conversion (fp32 -> bf16)
  for (int i = 0; i < 3; ++i){
    k_cvt<<<96, 256, 0, stream>>>(qkvw[i], qkvb[i], 196608);
    k_cvt<<<32, 256, 0, stream>>>(projw[i], projbw[i], 65536);
  }
  k_cvt<<<32,  256, 0, stream>>>(tcw, tcwb, 65536);
  k_cvt<<<160, 256, 0, stream>>>(trw, trwb, 327680);
  k_cvt<<<128, 256, 0, stream>>>(c1w, c1wb, 262144);
  k_cvt<<<128, 256, 0, stream>>>(c2w, c2wb, 262144);

  k_transpose<<<dim3(64, 4, 4), 256, 0, stream>>>(x, Xpm);
  k_pool_mean<<<1024, 256, 0, stream>>>(x, pm);
  k_ln<unsigned short><<<4096, 256, 0, stream>>>(Xpm, ln1w, ln1b, N1);
  k_pool_feat<<<4, 256, 0, stream>>>(pm, poolw, bn2g, bn2b, pf);
  k_pool_bias<<<4, 256, 0, stream>>>(pf, trw, pb);

  for (int i = 0; i < 3; ++i){
    k_gemm<0><<<dim3(6, 128), 256, 0, stream>>>(N1, qkvb[i], 256, 768, 256, E,
                                                nullptr, nullptr, nullptr, nullptr, 0);
    k_attn<<<512, 256, 0, stream>>>(E, F, i + 1);
    k_gemm<1><<<dim3(2, 128), 256, 0, stream>>>(F, projbw[i], 256, 256, 256, CAT,
                                                projb[i], nullptr, nullptr, x,
                                                (i + 1) * 256);
  }
  k_gemm<2><<<dim3(2, 128), 256, 0, stream>>>(Xpm, tcwb, 256, 256, 256, CAT,
                                              tcb, bn1g, bn1b, nullptr, 0);
  k_gemm<3><<<dim3(2, 128), 256, 0, stream>>>(CAT, trwb, 1024, 256, 1280, TR,
                                              trb, bn3g, bn3b, pb, 0);
  k_ln<float><<<4096, 256, 0, stream>>>(TR, ln2w, ln2b, N1);   // N2 reuses N1
  k_gemm<4><<<dim3(8, 128), 256, 0, stream>>>(N1, c1wb, 256, 1024, 256, E,
                                              c1b, mbn1g, mbn1b, nullptr, 0);
  k_dwconv<<<8192, 256, 0, stream>>>(E, dww, dwb, mbn2g, mbn2b, F);
  k_gemm<5><<<dim3(2, 128), 256, 0, stream>>>(F, c2wb, 1024, 256, 1024, d_out,
                                              c2b, mbn3g, mbn3b, TR, 0);
}

// Round 4
// 476.173 us; speedup vs baseline: 1.6998x; 1.6998x over previous
//
#include <hip/hip_runtime.h>

#define N_PIX 16384
#define CDIM  256
#define HIDD  1024
#define BNS   0.9999950000374997f   // (1+1e-5)^-0.5

typedef __attribute__((ext_vector_type(8))) short  short8;
typedef __attribute__((ext_vector_type(4))) float  f32x4;
typedef __attribute__((ext_vector_type(4))) int    int4v;
typedef __attribute__((ext_vector_type(2))) int    int2v;

__device__ __forceinline__ float b2f(unsigned short u){
  unsigned int x = ((unsigned int)u) << 16; float f;
  __builtin_memcpy(&f, &x, 4); return f;
}
__device__ __forceinline__ unsigned short f2b(float f){
  unsigned int x; __builtin_memcpy(&x, &f, 4);
  unsigned int r = (x + 0x7fffu + ((x >> 16) & 1u)) >> 16;
  return (unsigned short)r;
}
__device__ __forceinline__ float geluf(float x){
  return 0.5f * x * (1.0f + erff(x * 0.70710678118654752f));
}

// ---------------- fp32 -> bf16 conversion (weights) ---------------------------
__global__ __launch_bounds__(256) void k_cvt(const float* __restrict__ src,
                                             unsigned short* __restrict__ dst, int n){
  int i = (blockIdx.x * 256 + threadIdx.x) * 8;
  if (i >= n) return;
  f32x4 a = *(const f32x4*)(src + i);
  f32x4 b = *(const f32x4*)(src + i + 4);
  unsigned short o[8];
  #pragma unroll
  for (int j = 0; j < 4; ++j){ o[j] = f2b(a[j]); o[4 + j] = f2b(b[j]); }
  *(int4v*)(dst + i) = *(int4v*)o;
}

// ---------------- dw weights: [1024,1,3,3] f32 -> [9][1024] bf16 ---------------
__global__ __launch_bounds__(256) void k_dwwT(const float* __restrict__ dww,
                                              unsigned short* __restrict__ dwwT){
  int i = blockIdx.x * 256 + threadIdx.x;     // 0..9215
  if (i >= 9216) return;
  int kk = i >> 10, c = i & 1023;
  dwwT[i] = f2b(dww[c * 9 + kk]);
}

// ------- transpose: x [B,C,4096] f32 -> Xpm [N,256] bf16 + Xpm32 [N,256] f32 ---
__global__ __launch_bounds__(256) void k_transpose(const float* __restrict__ x,
                                                   unsigned short* __restrict__ xpm,
                                                   float* __restrict__ xpm32){
  __shared__ __align__(16) float tile[64][65];
  int b = blockIdx.z, c0 = blockIdx.y * 64, p0 = blockIdx.x * 64;
  int t = threadIdx.x;
  int r = t >> 3, k = t & 7;
  for (int s = 0; s < 2; ++s){
    int rr = r + s * 32;
    const float* src = x + (((size_t)(b * CDIM + c0 + rr)) << 12) + p0 + k * 8;
    f32x4 a = *(const f32x4*)src;
    f32x4 c = *(const f32x4*)(src + 4);
    #pragma unroll
    for (int j = 0; j < 4; ++j){ tile[rr][k * 8 + j] = a[j]; tile[rr][k * 8 + 4 + j] = c[j]; }
  }
  __syncthreads();
  for (int s = 0; s < 2; ++s){
    int pr = r + s * 32;
    float tf[8];
    unsigned short tb[8];
    #pragma unroll
    for (int j = 0; j < 8; ++j){ tf[j] = tile[k * 8 + j][pr]; tb[j] = f2b(tf[j]); }
    size_t rowoff = ((size_t)(b * 4096 + p0 + pr)) << 8;
    *(int4v*)(xpm + rowoff + c0 + k * 8) = *(int4v*)tb;
    *(f32x4*)(xpm32 + rowoff + c0 + k * 8)     = *(f32x4*)&tf[0];
    *(f32x4*)(xpm32 + rowoff + c0 + k * 8 + 4) = *(f32x4*)&tf[4];
  }
}

// ---------------- LayerNorm over C=256 (one row per wave) ----------------------
template<typename IT>
__global__ __launch_bounds__(256) void k_ln(const IT* __restrict__ in,
    const float* __restrict__ w, const float* __restrict__ bia,
    unsigned short* __restrict__ out){
  int row  = blockIdx.x * 4 + (threadIdx.x >> 6);
  int lane = threadIdx.x & 63;
  float v[4];
  const IT* p = in + (size_t)row * CDIM + lane * 4;
  if constexpr (sizeof(IT) == 2){
    int2v d = *(const int2v*)p;
    unsigned short tmp[4]; __builtin_memcpy(tmp, &d, 8);
    #pragma unroll
    for (int j = 0; j < 4; ++j) v[j] = b2f(tmp[j]);
  } else {
    f32x4 d = *(const f32x4*)p;
    #pragma unroll
    for (int j = 0; j < 4; ++j) v[j] = d[j];
  }
  float s  = v[0] + v[1] + v[2] + v[3];
  float s2 = v[0]*v[0] + v[1]*v[1] + v[2]*v[2] + v[3]*v[3];
  #pragma unroll
  for (int m = 1; m < 64; m <<= 1){
    s  += __shfl_xor(s,  m);
    s2 += __shfl_xor(s2, m);
  }
  float mu   = s * (1.0f / 256.0f);
  float var  = s2 * (1.0f / 256.0f) - mu * mu;
  float rstd = rsqrtf(var + 1e-5f);
  unsigned short o[4];
  #pragma unroll
  for (int j = 0; j < 4; ++j){
    int c = lane * 4 + j;
    o[j] = f2b((v[j] - mu) * rstd * w[c] + bia[c]);
  }
  *(int2v*)(out + (size_t)row * CDIM + lane * 4) = *(int2v*)o;
}

// ---------------- MFMA GEMM: C[M,Nout] = A[M,K] * Bw[Nout,ldb]^T + epilogue ----
// 128x128 tile, 4 waves, each wave 64x64 via 4x4 x mfma_f32_16x16x32_bf16
template<int MODE>
__global__ __launch_bounds__(256) void k_gemm(
    const unsigned short* __restrict__ A, const unsigned short* __restrict__ Bw,
    int K, int Nout, int ldb, void* __restrict__ outp,
    const float* __restrict__ bias,
    const float* __restrict__ bng,
    const float* __restrict__ bnb,
    const float* __restrict__ auxf,   // MODE1: Xpm32; MODE3: pool_bias; MODE5: TR f32
    int catoff)
{
  __shared__ __align__(16) unsigned short As[128][40];
  __shared__ __align__(16) unsigned short Bs[128][40];
  int t = threadIdx.x;
  int m0 = blockIdx.y * 128, n0 = blockIdx.x * 128;
  int wave = t >> 6, lane = t & 63;
  int wm = wave >> 1, wn = wave & 1;
  int lr = lane & 15, kb = lane >> 4;

  f32x4 acc[4][4];
  f32x4 z = {0.f, 0.f, 0.f, 0.f};
  #pragma unroll
  for (int i = 0; i < 4; ++i)
    #pragma unroll
    for (int j = 0; j < 4; ++j) acc[i][j] = z;

  int r = t >> 2, cc = t & 3;  // staging: rows r, r+64 ; 4 chunks of 8 bf16 per row
  for (int k0 = 0; k0 < K; k0 += 32){
    #pragma unroll
    for (int s = 0; s < 2; ++s){
      int rr = r + s * 64;
      *(int4v*)&As[rr][cc * 8] = *(const int4v*)&A [(size_t)(m0 + rr) * K   + k0 + cc * 8];
      *(int4v*)&Bs[rr][cc * 8] = *(const int4v*)&Bw[(size_t)(n0 + rr) * ldb + k0 + cc * 8];
    }
    __syncthreads();
    short8 af[4], bf_[4];
    #pragma unroll
    for (int i = 0; i < 4; ++i) af [i] = *(const short8*)&As[wm * 64 + i * 16 + lr][kb * 8];
    #pragma unroll
    for (int j = 0; j < 4; ++j) bf_[j] = *(const short8*)&Bs[wn * 64 + j * 16 + lr][kb * 8];
    #pragma unroll
    for (int i = 0; i < 4; ++i)
      #pragma unroll
      for (int j = 0; j < 4; ++j)
        acc[i][j] = __builtin_amdgcn_mfma_f32_16x16x32_bf16(af[i], bf_[j], acc[i][j], 0, 0, 0);
    __syncthreads();
  }

  #pragma unroll
  for (int i = 0; i < 4; ++i){
    int rowb = m0 + wm * 64 + i * 16 + kb * 4;
    #pragma unroll
    for (int j = 0; j < 4; ++j){
      int col = n0 + wn * 64 + j * 16 + lr;
      #pragma unroll
      for (int rr = 0; rr < 4; ++rr){
        int row = rowb + rr;
        float v = acc[i][j][rr];
        if constexpr (MODE == 0){            // QKV: plain bf16 store
          ((unsigned short*)outp)[(size_t)row * Nout + col] = f2b(v);
        } else if constexpr (MODE == 1){     // proj + bias + residual(Xpm32) -> CAT
          v += bias[col] + auxf[(size_t)row * CDIM + col];
          ((unsigned short*)outp)[(size_t)row * HIDD + catoff + col] = f2b(v);
        } else if constexpr (MODE == 2){     // tc_conv: bias, bn1, relu -> CAT[:,0:256]
          v = (v + bias[col]) * (bng[col] * BNS) + bnb[col];
          v = fmaxf(v, 0.0f);
          ((unsigned short*)outp)[(size_t)row * HIDD + col] = f2b(v);
        } else if constexpr (MODE == 3){     // tc_trans: + bias + pool_bias, bn3, relu -> TR f32
          v += bias[col] + auxf[((row >> 12) << 8) + col];
          v = v * (bng[col] * BNS) + bnb[col];
          v = fmaxf(v, 0.0f);
          ((float*)outp)[(size_t)row * CDIM + col] = v;
        } else if constexpr (MODE == 4){     // mlp_c1: bias, gelu, bn1 -> H bf16
          v = geluf(v + bias[col]);
          v = v * (bng[col] * BNS) + bnb[col];
          ((unsigned short*)outp)[(size_t)row * HIDD + col] = f2b(v);
        } else {                             // MODE 5: mlp_c2: bias, bn3, +TR, store NCHW f32
          v = (v + bias[col]) * (bng[col] * BNS) + bnb[col];
          v += auxf[(size_t)row * CDIM + col];
          int b = row >> 12, hw = row & 4095;
          ((float*)outp)[(((size_t)(b * CDIM + col)) << 12) + hw] = v;
        }
      }
    }
  }
}

// ---------------- atrous 9-neighbor attention (per pixel, per head) ------------
__global__ __launch_bounds__(256) void k_attn(const unsigned short* __restrict__ QKV,
                                              unsigned short* __restrict__ ATT, int r){
  int t = blockIdx.x * 256 + threadIdx.x;     // 0 .. 131071
  int head = t & 7, pix = t >> 3;
  int hw = pix & 4095, h = hw >> 6, w = hw & 63;
  const unsigned short* base = QKV + (size_t)pix * 768 + head * 32;

  float q[32];
  #pragma unroll
  for (int c8 = 0; c8 < 4; ++c8){
    int4v d = *(const int4v*)(base + c8 * 8);
    unsigned short tmp[8]; __builtin_memcpy(tmp, &d, 16);
    #pragma unroll
    for (int j = 0; j < 8; ++j) q[c8 * 8 + j] = b2f(tmp[j]);
  }
  float logit[9];
  #pragma unroll
  for (int jj = 0; jj < 9; ++jj){
    int dh = (jj / 3 - 1) * r, dw = (jj % 3 - 1) * r;
    int hh = h + dh, ww = w + dw;
    float d = 0.0f;
    if (hh >= 0 && hh < 64 && ww >= 0 && ww < 64){
      const unsigned short* kr = base + (dh * 64 + dw) * 768 + 256;
      #pragma unroll
      for (int c8 = 0; c8 < 4; ++c8){
        int4v dd = *(const int4v*)(kr + c8 * 8);
        unsigned short tmp[8]; __builtin_memcpy(tmp, &dd, 16);
        #pragma unroll
        for (int j = 0; j < 8; ++j) d += q[c8 * 8 + j] * b2f(tmp[j]);
      }
    }
    logit[jj] = d * 0.17677669529663687f;   // hd^-0.5, OOB taps keep logit 0 (zero-pad)
  }
  float m = logit[0];
  #pragma unroll
  for (int jj = 1; jj < 9; ++jj) m = fmaxf(m, logit[jj]);
  float p[9], s = 0.0f;
  #pragma unroll
  for (int jj = 0; jj < 9; ++jj){ p[jj] = __expf(logit[jj] - m); s += p[jj]; }
  float inv = 1.0f / s;
  float o[32];
  #pragma unroll
  for (int j = 0; j < 32; ++j) o[j] = 0.0f;
  #pragma unroll
  for (int jj = 0; jj < 9; ++jj){
    int dh = (jj / 3 - 1) * r, dw = (jj % 3 - 1) * r;
    int hh = h + dh, ww = w + dw;
    if (hh >= 0 && hh < 64 && ww >= 0 && ww < 64){
      float pj = p[jj] * inv;
      const unsigned short* vr = base + (dh * 64 + dw) * 768 + 512;
      #pragma unroll
      for (int c8 = 0; c8 < 4; ++c8){
        int4v dd = *(const int4v*)(vr + c8 * 8);
        unsigned short tmp[8]; __builtin_memcpy(tmp, &dd, 16);
        #pragma unroll
        for (int j = 0; j < 8; ++j) o[c8 * 8 + j] += pj * b2f(tmp[j]);
      }
    }
  }
  unsigned short ob[32];
  #pragma unroll
  for (int j = 0; j < 32; ++j) ob[j] = f2b(o[j]);
  unsigned short* op = ATT + (size_t)pix * CDIM + head * 32;
  #pragma unroll
  for (int c8 = 0; c8 < 4; ++c8) *(int4v*)(op + c8 * 8) = *(int4v*)&ob[c8 * 8];
}

// ---------------- depthwise 3x3 + gelu + bn2 -----------------------------------
__global__ __launch_bounds__(256) void k_dwconv(const unsigned short* __restrict__ H,
    const unsigned short* __restrict__ dwwT, const float* __restrict__ dwb,
    const float* __restrict__ g, const float* __restrict__ bb,
    unsigned short* __restrict__ H2){
  int t = blockIdx.x * 256 + threadIdx.x;   // 16384 * 128
  int chunk = t & 127, pix = t >> 7;
  int hw = pix & 4095, h = hw >> 6, w = hw & 63;
  int c0 = chunk * 8;
  float acc[8], hc[8];
  {
    int4v dd = *(const int4v*)(H + (size_t)pix * HIDD + c0);
    unsigned short tmp[8]; __builtin_memcpy(tmp, &dd, 16);
    #pragma unroll
    for (int j = 0; j < 8; ++j){ hc[j] = b2f(tmp[j]); acc[j] = 0.0f; }
  }
  #pragma unroll
  for (int di = -1; di <= 1; ++di)
    #pragma unroll
    for (int dj = -1; dj <= 1; ++dj){
      int hh = h + di, ww = w + dj;
      if (hh < 0 || hh >= 64 || ww < 0 || ww >= 64) continue;
      int kk = (di + 1) * 3 + (dj + 1);
      int4v dd = *(const int4v*)(H + ((size_t)(pix + di * 64 + dj)) * HIDD + c0);
      int4v wv = *(const int4v*)(dwwT + kk * 1024 + c0);
      unsigned short tmp[8], wt[8];
      __builtin_memcpy(tmp, &dd, 16);
      __builtin_memcpy(wt,  &wv, 16);
      #pragma unroll
      for (int j = 0; j < 8; ++j) acc[j] += b2f(wt[j]) * b2f(tmp[j]);
    }
  f32x4 bv0 = *(const f32x4*)(dwb + c0), bv1 = *(const f32x4*)(dwb + c0 + 4);
  f32x4 gv0 = *(const f32x4*)(g   + c0), gv1 = *(const f32x4*)(g   + c0 + 4);
  f32x4 cv0 = *(const f32x4*)(bb  + c0), cv1 = *(const f32x4*)(bb  + c0 + 4);
  float bvv[8], gvv[8], cvv[8];
  #pragma unroll
  for (int j = 0; j < 4; ++j){
    bvv[j] = bv0[j]; bvv[4 + j] = bv1[j];
    gvv[j] = gv0[j]; gvv[4 + j] = gv1[j];
    cvv[j] = cv0[j]; cvv[4 + j] = cv1[j];
  }
  unsigned short ob[8];
  #pragma unroll
  for (int j = 0; j < 8; ++j){
    float v = acc[j] + bvv[j] + hc[j];
    v = geluf(v);
    v = v * (gvv[j] * BNS) + cvv[j];
    ob[j] = f2b(v);
  }
  *(int4v*)(H2 + (size_t)pix * HIDD + c0) = *(int4v*)ob;
}

// ---------------- pool path ----------------------------------------------------
__global__ __launch_bounds__(256) void k_pool_mean(const float* __restrict__ x,
                                                   float* __restrict__ pm){
  int bc = blockIdx.x;
  const float* p = x + ((size_t)bc << 12);
  int t = threadIdx.x;
  float s = 0.0f;
  for (int i = t * 4; i < 4096; i += 1024){
    f32x4 dd = *(const f32x4*)(p + i);
    s += dd[0] + dd[1] + dd[2] + dd[3];
  }
  #pragma unroll
  for (int m = 1; m < 64; m <<= 1) s += __shfl_xor(s, m);
  __shared__ float red[4];
  if ((t & 63) == 0) red[t >> 6] = s;
  __syncthreads();
  if (t == 0) pm[bc] = (red[0] + red[1] + red[2] + red[3]) * (1.0f / 4096.0f);
}

__global__ __launch_bounds__(256) void k_pool_feat(const float* __restrict__ pm,
    const float* __restrict__ pw, const float* __restrict__ g,
    const float* __restrict__ bb, float* __restrict__ pf){
  int b = blockIdx.x, o = threadIdx.x;
  __shared__ float v[256];
  v[o] = pm[b * 256 + o];
  __syncthreads();
  float acc = 0.0f;
  const float* wr = pw + (size_t)o * 256;
  for (int c = 0; c < 256; ++c) acc += v[c] * wr[c];
  float val = acc * (g[o] * BNS) + bb[o];
  pf[b * 256 + o] = fmaxf(val, 0.0f);
}

__global__ __launch_bounds__(256) void k_pool_bias(const float* __restrict__ pf,
    const float* __restrict__ tw, float* __restrict__ pb){
  int b = blockIdx.x, o = threadIdx.x;
  __shared__ float v[256];
  v[o] = pf[b * 256 + o];
  __syncthreads();
  float acc = 0.0f;
  const float* wr = tw + (size_t)o * 1280 + 1024;
  for (int c = 0; c < 256; ++c) acc += v[c] * wr[c];
  pb[b * 256 + o] = acc;
}

// ---------------- launch -------------------------------------------------------
extern "C" void kernel_launch(void* const* d_in, const int* in_sizes, int n_in,
                              void* d_out, int out_size, void* d_ws, size_t ws_size,
                              hipStream_t stream){
  const float* x     = (const float*)d_in[0];
  const float* ln1w  = (const float*)d_in[1];
  const float* ln1b  = (const float*)d_in[2];
  const float* ln2w  = (const float*)d_in[3];
  const float* ln2b  = (const float*)d_in[4];
  const float* qkvw[3]  = {(const float*)d_in[5], (const float*)d_in[8],  (const float*)d_in[11]};
  const float* projw[3] = {(const float*)d_in[6], (const float*)d_in[9],  (const float*)d_in[12]};
  const float* projb[3] = {(const float*)d_in[7], (const float*)d_in[10], (const float*)d_in[13]};
  const float* tcw   = (const float*)d_in[14];
  const float* tcb   = (const float*)d_in[15];
  const float* bn1g  = (const float*)d_in[16];
  const float* bn1b  = (const float*)d_in[17];
  const float* poolw = (const float*)d_in[18];
  const float* bn2g  = (const float*)d_in[19];
  const float* bn2b  = (const float*)d_in[20];
  const float* trw   = (const float*)d_in[21];
  const float* trb   = (const float*)d_in[22];
  const float* bn3g  = (const float*)d_in[23];
  const float* bn3b  = (const float*)d_in[24];
  const float* c1w   = (const float*)d_in[25];
  const float* c1b   = (const float*)d_in[26];
  const float* mbn1g = (const float*)d_in[27];
  const float* mbn1b = (const float*)d_in[28];
  const float* dww   = (const float*)d_in[29];
  const float* dwb   = (const float*)d_in[30];
  const float* mbn2g = (const float*)d_in[31];
  const float* mbn2b = (const float*)d_in[32];
  const float* c2w   = (const float*)d_in[33];
  const float* c2b   = (const float*)d_in[34];
  const float* mbn3g = (const float*)d_in[35];
  const float* mbn3b = (const float*)d_in[36];

  char* ws = (char*)d_ws;
  unsigned short* Xpm = (unsigned short*)(ws);                 //  8.4 MB [N,256] bf16
  unsigned short* N1  = (unsigned short*)(ws + 8388608);       //  8.4 MB [N,256] (later N2)
  unsigned short* CAT = (unsigned short*)(ws + 16777216);      // 33.6 MB [N,1024] xc1|t1|t2|t3
  float*          TR  = (float*)        (ws + 50331648);       // 16.8 MB: Xpm32 (early), TR (late)
  float*          Xpm32 = TR;                                  // alias — disjoint live ranges
  unsigned short* E   = (unsigned short*)(ws + 67108864);      // 33.6 MB QKV then H
  unsigned short* F   = (unsigned short*)(ws + 100663296);     // 33.6 MB ATT then H2
  // bf16 weight staging area
  unsigned short* Wb    = (unsigned short*)(ws + 134217728);
  unsigned short* qkvb[3]  = {Wb, Wb + 196608, Wb + 393216};            // 3 x 196608
  unsigned short* projbw[3] = {Wb + 589824, Wb + 655360, Wb + 720896};  // 3 x 65536
  unsigned short* tcwb  = Wb + 786432;                                  // 65536
  unsigned short* trwb  = Wb + 851968;                                  // 327680
  unsigned short* c1wb  = Wb + 1179648;                                 // 262144
  unsigned short* c2wb  = Wb + 1441792;                                 // 262144
  unsigned short* dwwT  = Wb + 1703936;                                 // 9216
  float*          pm  = (float*)(ws + 134217728 + 3428352);
  float*          pf  = pm + 1024;
  float*          pb  = pf + 1024;

  // weight conversion (fp32 -> bf16)
  for (int i = 0; i < 3; ++i){
    k_cvt<<<96, 256, 0, stream>>>(qkvw[i], qkvb[i], 196608);
    k_cvt<<<32, 256, 0, stream>>>(projw[i], projbw[i], 65536);
  }
  k_cvt<<<32,  256, 0, stream>>>(tcw, tcwb, 65536);
  k_cvt<<<160, 256, 0, stream>>>(trw, trwb, 327680);
  k_cvt<<<128, 256, 0, stream>>>(c1w, c1wb, 262144);
  k_cvt<<<128, 256, 0, stream>>>(c2w, c2wb, 262144);
  k_dwwT<<<36, 256, 0, stream>>>(dww, dwwT);

  k_transpose<<<dim3(64, 4, 4), 256, 0, stream>>>(x, Xpm, Xpm32);
  k_pool_mean<<<1024, 256, 0, stream>>>(x, pm);
  k_ln<unsigned short><<<4096, 256, 0, stream>>>(Xpm, ln1w, ln1b, N1);
  k_pool_feat<<<4, 256, 0, stream>>>(pm, poolw, bn2g, bn2b, pf);
  k_pool_bias<<<4, 256, 0, stream>>>(pf, trw, pb);

  for (int i = 0; i < 3; ++i){
    k_gemm<0><<<dim3(6, 128), 256, 0, stream>>>(N1, qkvb[i], 256, 768, 256, E,
                                                nullptr, nullptr, nullptr, nullptr, 0);
    k_attn<<<512, 256, 0, stream>>>(E, F, i + 1);
    k_gemm<1><<<dim3(2, 128), 256, 0, stream>>>(F, projbw[i], 256, 256, 256, CAT,
                                                projb[i], nullptr, nullptr, Xpm32,
                                                (i + 1) * 256);
  }
  k_gemm<2><<<dim3(2, 128), 256, 0, stream>>>(Xpm, tcwb, 256, 256, 256, CAT,
                                              tcb, bn1g, bn1b, nullptr, 0);
  k_gemm<3><<<dim3(2, 128), 256, 0, stream>>>(CAT, trwb, 1024, 256, 1280, TR,
                                              trb, bn3g, bn3b, pb, 0);
  k_ln<float><<<4096, 256, 0, stream>>>(TR, ln2w, ln2b, N1);   // N2 reuses N1
  k_gemm<4><<<dim3(8, 128), 256, 0, stream>>>(N1, c1wb, 256, 1024, 256, E,
                                              c1b, mbn1g, mbn1b, nullptr, 0);
  k_dwconv<<<8192, 256, 0, stream>>>(E, dwwT, dwb, mbn2g, mbn2b, F);
  k_gemm<5><<<dim3(2, 128), 256, 0, stream>>>(F, c2wb, 1024, 256, 1024, d_out,
                                              c2b, mbn3g, mbn3b, TR, 0);
}

// Round 5
// 458.800 us; speedup vs baseline: 1.7642x; 1.0379x over previous
//
#include <hip/hip_runtime.h>

#define N_PIX 16384
#define CDIM  256
#define HIDD  1024
#define BNS   0.9999950000374997f   // (1+1e-5)^-0.5
#define LP    36                    // LDS row pitch in shorts (18 dwords -> conflict-free b128)

typedef __attribute__((ext_vector_type(8))) short  short8;
typedef __attribute__((ext_vector_type(4))) float  f32x4;
typedef __attribute__((ext_vector_type(4))) int    int4v;
typedef __attribute__((ext_vector_type(2))) int    int2v;

__device__ __forceinline__ float b2f(unsigned short u){
  unsigned int x = ((unsigned int)u) << 16; float f;
  __builtin_memcpy(&f, &x, 4); return f;
}
__device__ __forceinline__ unsigned short f2b(float f){
  unsigned int x; __builtin_memcpy(&x, &f, 4);
  unsigned int r = (x + 0x7fffu + ((x >> 16) & 1u)) >> 16;
  return (unsigned short)r;
}
__device__ __forceinline__ float geluf(float x){
  return 0.5f * x * (1.0f + erff(x * 0.70710678118654752f));
}

// ---------------- fp32 -> bf16 conversion (weights) ---------------------------
__global__ __launch_bounds__(256) void k_cvt(const float* __restrict__ src,
                                             unsigned short* __restrict__ dst, int n){
  int i = (blockIdx.x * 256 + threadIdx.x) * 8;
  if (i >= n) return;
  f32x4 a = *(const f32x4*)(src + i);
  f32x4 b = *(const f32x4*)(src + i + 4);
  unsigned short o[8];
  #pragma unroll
  for (int j = 0; j < 4; ++j){ o[j] = f2b(a[j]); o[4 + j] = f2b(b[j]); }
  *(int4v*)(dst + i) = *(int4v*)o;
}

// ---------------- dw weights: [1024,1,3,3] f32 -> [9][1024] bf16 ---------------
__global__ __launch_bounds__(256) void k_dwwT(const float* __restrict__ dww,
                                              unsigned short* __restrict__ dwwT){
  int i = blockIdx.x * 256 + threadIdx.x;     // 0..9215
  if (i >= 9216) return;
  int kk = i >> 10, c = i & 1023;
  dwwT[i] = f2b(dww[c * 9 + kk]);
}

// ------- transpose: x [B,C,4096] f32 -> Xpm [N,256] bf16 + Xpm32 [N,256] f32 ---
__global__ __launch_bounds__(256) void k_transpose(const float* __restrict__ x,
                                                   unsigned short* __restrict__ xpm,
                                                   float* __restrict__ xpm32){
  __shared__ __align__(16) float tile[64][65];
  int b = blockIdx.z, c0 = blockIdx.y * 64, p0 = blockIdx.x * 64;
  int t = threadIdx.x;
  int r = t >> 3, k = t & 7;
  for (int s = 0; s < 2; ++s){
    int rr = r + s * 32;
    const float* src = x + (((size_t)(b * CDIM + c0 + rr)) << 12) + p0 + k * 8;
    f32x4 a = *(const f32x4*)src;
    f32x4 c = *(const f32x4*)(src + 4);
    #pragma unroll
    for (int j = 0; j < 4; ++j){ tile[rr][k * 8 + j] = a[j]; tile[rr][k * 8 + 4 + j] = c[j]; }
  }
  __syncthreads();
  for (int s = 0; s < 2; ++s){
    int pr = r + s * 32;
    float tf[8];
    unsigned short tb[8];
    #pragma unroll
    for (int j = 0; j < 8; ++j){ tf[j] = tile[k * 8 + j][pr]; tb[j] = f2b(tf[j]); }
    size_t rowoff = ((size_t)(b * 4096 + p0 + pr)) << 8;
    *(int4v*)(xpm + rowoff + c0 + k * 8) = *(int4v*)tb;
    *(f32x4*)(xpm32 + rowoff + c0 + k * 8)     = *(f32x4*)&tf[0];
    *(f32x4*)(xpm32 + rowoff + c0 + k * 8 + 4) = *(f32x4*)&tf[4];
  }
}

// ---------------- LayerNorm over C=256 (one row per wave) ----------------------
template<typename IT>
__global__ __launch_bounds__(256) void k_ln(const IT* __restrict__ in,
    const float* __restrict__ w, const float* __restrict__ bia,
    unsigned short* __restrict__ out){
  int row  = blockIdx.x * 4 + (threadIdx.x >> 6);
  int lane = threadIdx.x & 63;
  float v[4];
  const IT* p = in + (size_t)row * CDIM + lane * 4;
  if constexpr (sizeof(IT) == 2){
    int2v d = *(const int2v*)p;
    unsigned short tmp[4]; __builtin_memcpy(tmp, &d, 8);
    #pragma unroll
    for (int j = 0; j < 4; ++j) v[j] = b2f(tmp[j]);
  } else {
    f32x4 d = *(const f32x4*)p;
    #pragma unroll
    for (int j = 0; j < 4; ++j) v[j] = d[j];
  }
  float s  = v[0] + v[1] + v[2] + v[3];
  float s2 = v[0]*v[0] + v[1]*v[1] + v[2]*v[2] + v[3]*v[3];
  #pragma unroll
  for (int m = 1; m < 64; m <<= 1){
    s  += __shfl_xor(s,  m);
    s2 += __shfl_xor(s2, m);
  }
  float mu   = s * (1.0f / 256.0f);
  float var  = s2 * (1.0f / 256.0f) - mu * mu;
  float rstd = rsqrtf(var + 1e-5f);
  unsigned short o[4];
  #pragma unroll
  for (int j = 0; j < 4; ++j){
    int c = lane * 4 + j;
    o[j] = f2b((v[j] - mu) * rstd * w[c] + bia[c]);
  }
  *(int2v*)(out + (size_t)row * CDIM + lane * 4) = *(int2v*)o;
}

// ---------------- MFMA GEMM: C[M,Nout] = A[M,K] * Bw[Nout,ldb]^T + epilogue ----
// 64x128 tile (BM x BN), 4 waves, each wave 32x64 via 2x4 x mfma_f32_16x16x32_bf16
template<int MODE>
__global__ __launch_bounds__(256) void k_gemm(
    const unsigned short* __restrict__ A, const unsigned short* __restrict__ Bw,
    int K, int Nout, int ldb, void* __restrict__ outp,
    const float* __restrict__ bias,
    const float* __restrict__ bng,
    const float* __restrict__ bnb,
    const float* __restrict__ auxf,   // MODE1: Xpm32; MODE3: pool_bias; MODE5: TR f32
    int catoff)
{
  __shared__ __align__(16) unsigned short As[64][LP];
  __shared__ __align__(16) unsigned short Bs[128][LP];
  int t = threadIdx.x;
  int m0 = blockIdx.y * 64, n0 = blockIdx.x * 128;
  int wave = t >> 6, lane = t & 63;
  int wm = wave >> 1, wn = wave & 1;
  int lr = lane & 15, kb = lane >> 4;

  f32x4 acc[2][4];
  f32x4 z = {0.f, 0.f, 0.f, 0.f};
  #pragma unroll
  for (int i = 0; i < 2; ++i)
    #pragma unroll
    for (int j = 0; j < 4; ++j) acc[i][j] = z;

  int r = t >> 2, cc = t & 3;  // staging: A row r (64); B rows r, r+64; 16B chunks
  for (int k0 = 0; k0 < K; k0 += 32){
    *(int4v*)&As[r][cc * 8]      = *(const int4v*)&A [(size_t)(m0 + r) * K        + k0 + cc * 8];
    *(int4v*)&Bs[r][cc * 8]      = *(const int4v*)&Bw[(size_t)(n0 + r) * ldb      + k0 + cc * 8];
    *(int4v*)&Bs[r + 64][cc * 8] = *(const int4v*)&Bw[(size_t)(n0 + r + 64) * ldb + k0 + cc * 8];
    __syncthreads();
    short8 af[2], bf_[4];
    #pragma unroll
    for (int i = 0; i < 2; ++i) af [i] = *(const short8*)&As[wm * 32 + i * 16 + lr][kb * 8];
    #pragma unroll
    for (int j = 0; j < 4; ++j) bf_[j] = *(const short8*)&Bs[wn * 64 + j * 16 + lr][kb * 8];
    #pragma unroll
    for (int i = 0; i < 2; ++i)
      #pragma unroll
      for (int j = 0; j < 4; ++j)
        acc[i][j] = __builtin_amdgcn_mfma_f32_16x16x32_bf16(af[i], bf_[j], acc[i][j], 0, 0, 0);
    __syncthreads();
  }

  #pragma unroll
  for (int i = 0; i < 2; ++i){
    int rowb = m0 + wm * 32 + i * 16 + kb * 4;
    #pragma unroll
    for (int j = 0; j < 4; ++j){
      int col = n0 + wn * 64 + j * 16 + lr;
      #pragma unroll
      for (int rr = 0; rr < 4; ++rr){
        int row = rowb + rr;
        float v = acc[i][j][rr];
        if constexpr (MODE == 0){            // QKV: plain bf16 store
          ((unsigned short*)outp)[(size_t)row * Nout + col] = f2b(v);
        } else if constexpr (MODE == 1){     // proj + bias + residual(Xpm32) -> CAT
          v += bias[col] + auxf[(size_t)row * CDIM + col];
          ((unsigned short*)outp)[(size_t)row * HIDD + catoff + col] = f2b(v);
        } else if constexpr (MODE == 2){     // tc_conv: bias, bn1, relu -> CAT[:,0:256]
          v = (v + bias[col]) * (bng[col] * BNS) + bnb[col];
          v = fmaxf(v, 0.0f);
          ((unsigned short*)outp)[(size_t)row * HIDD + col] = f2b(v);
        } else if constexpr (MODE == 3){     // tc_trans: + bias + pool_bias, bn3, relu -> TR f32
          v += bias[col] + auxf[((row >> 12) << 8) + col];
          v = v * (bng[col] * BNS) + bnb[col];
          v = fmaxf(v, 0.0f);
          ((float*)outp)[(size_t)row * CDIM + col] = v;
        } else if constexpr (MODE == 4){     // mlp_c1: bias, gelu, bn1 -> H bf16
          v = geluf(v + bias[col]);
          v = v * (bng[col] * BNS) + bnb[col];
          ((unsigned short*)outp)[(size_t)row * HIDD + col] = f2b(v);
        } else {                             // MODE 5: mlp_c2: bias, bn3, +TR, store NCHW f32
          v = (v + bias[col]) * (bng[col] * BNS) + bnb[col];
          v += auxf[(size_t)row * CDIM + col];
          int b = row >> 12, hw = row & 4095;
          ((float*)outp)[(((size_t)(b * CDIM + col)) << 12) + hw] = v;
        }
      }
    }
  }
}

// ---------------- atrous 9-neighbor attention (per pixel, per head) ------------
__global__ __launch_bounds__(256) void k_attn(const unsigned short* __restrict__ QKV,
                                              unsigned short* __restrict__ ATT, int r){
  int t = blockIdx.x * 256 + threadIdx.x;     // 0 .. 131071
  int head = t & 7, pix = t >> 3;
  int hw = pix & 4095, h = hw >> 6, w = hw & 63;
  const unsigned short* base = QKV + (size_t)pix * 768 + head * 32;

  float q[32];
  #pragma unroll
  for (int c8 = 0; c8 < 4; ++c8){
    int4v d = *(const int4v*)(base + c8 * 8);
    unsigned short tmp[8]; __builtin_memcpy(tmp, &d, 16);
    #pragma unroll
    for (int j = 0; j < 8; ++j) q[c8 * 8 + j] = b2f(tmp[j]);
  }
  float logit[9];
  #pragma unroll
  for (int jj = 0; jj < 9; ++jj){
    int dh = (jj / 3 - 1) * r, dw = (jj % 3 - 1) * r;
    int hh = h + dh, ww = w + dw;
    float d = 0.0f;
    if (hh >= 0 && hh < 64 && ww >= 0 && ww < 64){
      const unsigned short* kr = base + (dh * 64 + dw) * 768 + 256;
      #pragma unroll
      for (int c8 = 0; c8 < 4; ++c8){
        int4v dd = *(const int4v*)(kr + c8 * 8);
        unsigned short tmp[8]; __builtin_memcpy(tmp, &dd, 16);
        #pragma unroll
        for (int j = 0; j < 8; ++j) d += q[c8 * 8 + j] * b2f(tmp[j]);
      }
    }
    logit[jj] = d * 0.17677669529663687f;   // hd^-0.5, OOB taps keep logit 0 (zero-pad)
  }
  float m = logit[0];
  #pragma unroll
  for (int jj = 1; jj < 9; ++jj) m = fmaxf(m, logit[jj]);
  float p[9], s = 0.0f;
  #pragma unroll
  for (int jj = 0; jj < 9; ++jj){ p[jj] = __expf(logit[jj] - m); s += p[jj]; }
  float inv = 1.0f / s;
  float o[32];
  #pragma unroll
  for (int j = 0; j < 32; ++j) o[j] = 0.0f;
  #pragma unroll
  for (int jj = 0; jj < 9; ++jj){
    int dh = (jj / 3 - 1) * r, dw = (jj % 3 - 1) * r;
    int hh = h + dh, ww = w + dw;
    if (hh >= 0 && hh < 64 && ww >= 0 && ww < 64){
      float pj = p[jj] * inv;
      const unsigned short* vr = base + (dh * 64 + dw) * 768 + 512;
      #pragma unroll
      for (int c8 = 0; c8 < 4; ++c8){
        int4v dd = *(const int4v*)(vr + c8 * 8);
        unsigned short tmp[8]; __builtin_memcpy(tmp, &dd, 16);
        #pragma unroll
        for (int j = 0; j < 8; ++j) o[c8 * 8 + j] += pj * b2f(tmp[j]);
      }
    }
  }
  unsigned short ob[32];
  #pragma unroll
  for (int j = 0; j < 32; ++j) ob[j] = f2b(o[j]);
  unsigned short* op = ATT + (size_t)pix * CDIM + head * 32;
  #pragma unroll
  for (int c8 = 0; c8 < 4; ++c8) *(int4v*)(op + c8 * 8) = *(int4v*)&ob[c8 * 8];
}

// ---------------- depthwise 3x3 + gelu + bn2 -----------------------------------
__global__ __launch_bounds__(256) void k_dwconv(const unsigned short* __restrict__ H,
    const unsigned short* __restrict__ dwwT, const float* __restrict__ dwb,
    const float* __restrict__ g, const float* __restrict__ bb,
    unsigned short* __restrict__ H2){
  int t = blockIdx.x * 256 + threadIdx.x;   // 16384 * 128
  int chunk = t & 127, pix = t >> 7;
  int hw = pix & 4095, h = hw >> 6, w = hw & 63;
  int c0 = chunk * 8;
  float acc[8], hc[8];
  {
    int4v dd = *(const int4v*)(H + (size_t)pix * HIDD + c0);
    unsigned short tmp[8]; __builtin_memcpy(tmp, &dd, 16);
    #pragma unroll
    for (int j = 0; j < 8; ++j){ hc[j] = b2f(tmp[j]); acc[j] = 0.0f; }
  }
  #pragma unroll
  for (int di = -1; di <= 1; ++di)
    #pragma unroll
    for (int dj = -1; dj <= 1; ++dj){
      int hh = h + di, ww = w + dj;
      if (hh < 0 || hh >= 64 || ww < 0 || ww >= 64) continue;
      int kk = (di + 1) * 3 + (dj + 1);
      int4v dd = *(const int4v*)(H + ((size_t)(pix + di * 64 + dj)) * HIDD + c0);
      int4v wv = *(const int4v*)(dwwT + kk * 1024 + c0);
      unsigned short tmp[8], wt[8];
      __builtin_memcpy(tmp, &dd, 16);
      __builtin_memcpy(wt,  &wv, 16);
      #pragma unroll
      for (int j = 0; j < 8; ++j) acc[j] += b2f(wt[j]) * b2f(tmp[j]);
    }
  f32x4 bv0 = *(const f32x4*)(dwb + c0), bv1 = *(const f32x4*)(dwb + c0 + 4);
  f32x4 gv0 = *(const f32x4*)(g   + c0), gv1 = *(const f32x4*)(g   + c0 + 4);
  f32x4 cv0 = *(const f32x4*)(bb  + c0), cv1 = *(const f32x4*)(bb  + c0 + 4);
  float bvv[8], gvv[8], cvv[8];
  #pragma unroll
  for (int j = 0; j < 4; ++j){
    bvv[j] = bv0[j]; bvv[4 + j] = bv1[j];
    gvv[j] = gv0[j]; gvv[4 + j] = gv1[j];
    cvv[j] = cv0[j]; cvv[4 + j] = cv1[j];
  }
  unsigned short ob[8];
  #pragma unroll
  for (int j = 0; j < 8; ++j){
    float v = acc[j] + bvv[j] + hc[j];
    v = geluf(v);
    v = v * (gvv[j] * BNS) + cvv[j];
    ob[j] = f2b(v);
  }
  *(int4v*)(H2 + (size_t)pix * HIDD + c0) = *(int4v*)ob;
}

// ---------------- pool path ----------------------------------------------------
__global__ __launch_bounds__(256) void k_pool_mean(const float* __restrict__ x,
                                                   float* __restrict__ pm){
  int bc = blockIdx.x;
  const float* p = x + ((size_t)bc << 12);
  int t = threadIdx.x;
  float s = 0.0f;
  for (int i = t * 4; i < 4096; i += 1024){
    f32x4 dd = *(const f32x4*)(p + i);
    s += dd[0] + dd[1] + dd[2] + dd[3];
  }
  #pragma unroll
  for (int m = 1; m < 64; m <<= 1) s += __shfl_xor(s, m);
  __shared__ float red[4];
  if ((t & 63) == 0) red[t >> 6] = s;
  __syncthreads();
  if (t == 0) pm[bc] = (red[0] + red[1] + red[2] + red[3]) * (1.0f / 4096.0f);
}

__global__ __launch_bounds__(256) void k_pool_feat(const float* __restrict__ pm,
    const float* __restrict__ pw, const float* __restrict__ g,
    const float* __restrict__ bb, float* __restrict__ pf){
  int b = blockIdx.x, o = threadIdx.x;
  __shared__ float v[256];
  v[o] = pm[b * 256 + o];
  __syncthreads();
  float acc = 0.0f;
  const float* wr = pw + (size_t)o * 256;
  for (int c = 0; c < 256; ++c) acc += v[c] * wr[c];
  float val = acc * (g[o] * BNS) + bb[o];
  pf[b * 256 + o] = fmaxf(val, 0.0f);
}

__global__ __launch_bounds__(256) void k_pool_bias(const float* __restrict__ pf,
    const float* __restrict__ tw, float* __restrict__ pb){
  int b = blockIdx.x, o = threadIdx.x;
  __shared__ float v[256];
  v[o] = pf[b * 256 + o];
  __syncthreads();
  float acc = 0.0f;
  const float* wr = tw + (size_t)o * 1280 + 1024;
  for (int c = 0; c < 256; ++c) acc += v[c] * wr[c];
  pb[b * 256 + o] = acc;
}

// ---------------- launch -------------------------------------------------------
extern "C" void kernel_launch(void* const* d_in, const int* in_sizes, int n_in,
                              void* d_out, int out_size, void* d_ws, size_t ws_size,
                              hipStream_t stream){
  const float* x     = (const float*)d_in[0];
  const float* ln1w  = (const float*)d_in[1];
  const float* ln1b  = (const float*)d_in[2];
  const float* ln2w  = (const float*)d_in[3];
  const float* ln2b  = (const float*)d_in[4];
  const float* qkvw[3]  = {(const float*)d_in[5], (const float*)d_in[8],  (const float*)d_in[11]};
  const float* projw[3] = {(const float*)d_in[6], (const float*)d_in[9],  (const float*)d_in[12]};
  const float* projb[3] = {(const float*)d_in[7], (const float*)d_in[10], (const float*)d_in[13]};
  const float* tcw   = (const float*)d_in[14];
  const float* tcb   = (const float*)d_in[15];
  const float* bn1g  = (const float*)d_in[16];
  const float* bn1b  = (const float*)d_in[17];
  const float* poolw = (const float*)d_in[18];
  const float* bn2g  = (const float*)d_in[19];
  const float* bn2b  = (const float*)d_in[20];
  const float* trw   = (const float*)d_in[21];
  const float* trb   = (const float*)d_in[22];
  const float* bn3g  = (const float*)d_in[23];
  const float* bn3b  = (const float*)d_in[24];
  const float* c1w   = (const float*)d_in[25];
  const float* c1b   = (const float*)d_in[26];
  const float* mbn1g = (const float*)d_in[27];
  const float* mbn1b = (const float*)d_in[28];
  const float* dww   = (const float*)d_in[29];
  const float* dwb   = (const float*)d_in[30];
  const float* mbn2g = (const float*)d_in[31];
  const float* mbn2b = (const float*)d_in[32];
  const float* c2w   = (const float*)d_in[33];
  const float* c2b   = (const float*)d_in[34];
  const float* mbn3g = (const float*)d_in[35];
  const float* mbn3b = (const float*)d_in[36];

  char* ws = (char*)d_ws;
  unsigned short* Xpm = (unsigned short*)(ws);                 //  8.4 MB [N,256] bf16
  unsigned short* N1  = (unsigned short*)(ws + 8388608);       //  8.4 MB [N,256] (later N2)
  unsigned short* CAT = (unsigned short*)(ws + 16777216);      // 33.6 MB [N,1024] xc1|t1|t2|t3
  float*          TR  = (float*)        (ws + 50331648);       // 16.8 MB: Xpm32 (early), TR (late)
  float*          Xpm32 = TR;                                  // alias — disjoint live ranges
  unsigned short* E   = (unsigned short*)(ws + 67108864);      // 33.6 MB QKV then H
  unsigned short* F   = (unsigned short*)(ws + 100663296);     // 33.6 MB ATT then H2
  // bf16 weight staging area
  unsigned short* Wb    = (unsigned short*)(ws + 134217728);
  unsigned short* qkvb[3]  = {Wb, Wb + 196608, Wb + 393216};            // 3 x 196608
  unsigned short* projbw[3] = {Wb + 589824, Wb + 655360, Wb + 720896};  // 3 x 65536
  unsigned short* tcwb  = Wb + 786432;                                  // 65536
  unsigned short* trwb  = Wb + 851968;                                  // 327680
  unsigned short* c1wb  = Wb + 1179648;                                 // 262144
  unsigned short* c2wb  = Wb + 1441792;                                 // 262144
  unsigned short* dwwT  = Wb + 1703936;                                 // 9216
  float*          pm  = (float*)(ws + 134217728 + 3428352);
  float*          pf  = pm + 1024;
  float*          pb  = pf + 1024;

  // weight conversion (fp32 -> bf16)
  for (int i = 0; i < 3; ++i){
    k_cvt<<<96, 256, 0, stream>>>(qkvw[i], qkvb[i], 196608);
    k_cvt<<<32, 256, 0, stream>>>(projw[i], projbw[i], 65536);
  }
  k_cvt<<<32,  256, 0, stream>>>(tcw, tcwb, 65536);
  k_cvt<<<160, 256, 0, stream>>>(trw, trwb, 327680);
  k_cvt<<<128, 256, 0, stream>>>(c1w, c1wb, 262144);
  k_cvt<<<128, 256, 0, stream>>>(c2w, c2wb, 262144);
  k_dwwT<<<36, 256, 0, stream>>>(dww, dwwT);

  k_transpose<<<dim3(64, 4, 4), 256, 0, stream>>>(x, Xpm, Xpm32);
  k_pool_mean<<<1024, 256, 0, stream>>>(x, pm);
  k_ln<unsigned short><<<4096, 256, 0, stream>>>(Xpm, ln1w, ln1b, N1);
  k_pool_feat<<<4, 256, 0, stream>>>(pm, poolw, bn2g, bn2b, pf);
  k_pool_bias<<<4, 256, 0, stream>>>(pf, trw, pb);

  for (int i = 0; i < 3; ++i){
    k_gemm<0><<<dim3(6, 256), 256, 0, stream>>>(N1, qkvb[i], 256, 768, 256, E,
                                                nullptr, nullptr, nullptr, nullptr, 0);
    k_attn<<<512, 256, 0, stream>>>(E, F, i + 1);
    k_gemm<1><<<dim3(2, 256), 256, 0, stream>>>(F, projbw[i], 256, 256, 256, CAT,
                                                projb[i], nullptr, nullptr, Xpm32,
                                                (i + 1) * 256);
  }
  k_gemm<2><<<dim3(2, 256), 256, 0, stream>>>(Xpm, tcwb, 256, 256, 256, CAT,
                                              tcb, bn1g, bn1b, nullptr, 0);
  k_gemm<3><<<dim3(2, 256), 256, 0, stream>>>(CAT, trwb, 1024, 256, 1280, TR,
                                              trb, bn3g, bn3b, pb, 0);
  k_ln<float><<<4096, 256, 0, stream>>>(TR, ln2w, ln2b, N1);   // N2 reuses N1
  k_gemm<4><<<dim3(8, 256), 256, 0, stream>>>(N1, c1wb, 256, 1024, 256, E,
                                              c1b, mbn1g, mbn1b, nullptr, 0);
  k_dwconv<<<8192, 256, 0, stream>>>(E, dwwT, dwb, mbn2g, mbn2b, F);
  k_gemm<5><<<dim3(2, 256), 256, 0, stream>>>(F, c2wb, 1024, 256, 1024, d_out,
                                              c2b, mbn3g, mbn3b, TR, 0);
}

// Round 6
// 433.847 us; speedup vs baseline: 1.8657x; 1.0575x over previous
//
#include <hip/hip_runtime.h>

#define N_PIX 16384
#define CDIM  256
#define HIDD  1024
#define BNS   0.9999950000374997f   // (1+1e-5)^-0.5

typedef __attribute__((ext_vector_type(8))) short  short8;
typedef __attribute__((ext_vector_type(4))) float  f32x4;
typedef __attribute__((ext_vector_type(4))) int    int4v;
typedef __attribute__((ext_vector_type(2))) int    int2v;

__device__ __forceinline__ float b2f(unsigned short u){
  unsigned int x = ((unsigned int)u) << 16; float f;
  __builtin_memcpy(&f, &x, 4); return f;
}
__device__ __forceinline__ unsigned short f2b(float f){
  unsigned int x; __builtin_memcpy(&x, &f, 4);
  unsigned int r = (x + 0x7fffu + ((x >> 16) & 1u)) >> 16;
  return (unsigned short)r;
}
__device__ __forceinline__ float geluf(float x){
  return 0.5f * x * (1.0f + erff(x * 0.70710678118654752f));
}

// async global->LDS DMA, 16B per lane, wave-uniform LDS base + lane*16
typedef const __attribute__((address_space(1))) unsigned int* gas_t;
typedef __attribute__((address_space(3))) unsigned int*       las_t;
__device__ __forceinline__ void gload16(const void* g, void* l){
  __builtin_amdgcn_global_load_lds((gas_t)g, (las_t)l, 16, 0, 0);
}

// ---------------- fused fp32 -> bf16 weight conversion (10 segments) ----------
__global__ __launch_bounds__(256) void k_cvt_all(
    const float* __restrict__ s0, const float* __restrict__ s1, const float* __restrict__ s2,
    const float* __restrict__ s3, const float* __restrict__ s4, const float* __restrict__ s5,
    const float* __restrict__ s6, const float* __restrict__ s7, const float* __restrict__ s8,
    const float* __restrict__ s9, unsigned short* __restrict__ wb){
  const float* srcs[10] = {s0,s1,s2,s3,s4,s5,s6,s7,s8,s9};
  const int n[10]   = {196608,196608,196608,65536,65536,65536,65536,327680,262144,262144};
  const int off[10] = {0,196608,393216,589824,655360,720896,786432,851968,1179648,1441792};
  int seg = blockIdx.y;
  int i = (blockIdx.x * 256 + threadIdx.x) * 8;
  if (i >= n[seg]) return;
  const float* src = srcs[seg];
  unsigned short* dst = wb + off[seg];
  f32x4 a = *(const f32x4*)(src + i);
  f32x4 b = *(const f32x4*)(src + i + 4);
  unsigned short o[8];
  #pragma unroll
  for (int j = 0; j < 4; ++j){ o[j] = f2b(a[j]); o[4 + j] = f2b(b[j]); }
  *(int4v*)(dst + i) = *(int4v*)o;
}

// ---------------- dw weights: [1024,1,3,3] f32 -> [9][1024] bf16 ---------------
__global__ __launch_bounds__(256) void k_dwwT(const float* __restrict__ dww,
                                              unsigned short* __restrict__ dwwT){
  int i = blockIdx.x * 256 + threadIdx.x;     // 0..9215
  if (i >= 9216) return;
  int kk = i >> 10, c = i & 1023;
  dwwT[i] = f2b(dww[c * 9 + kk]);
}

// ------- transpose: x [B,C,4096] f32 -> Xpm [N,256] bf16 + Xpm32 [N,256] f32 ---
__global__ __launch_bounds__(256) void k_transpose(const float* __restrict__ x,
                                                   unsigned short* __restrict__ xpm,
                                                   float* __restrict__ xpm32){
  __shared__ __align__(16) float tile[64][65];
  int b = blockIdx.z, c0 = blockIdx.y * 64, p0 = blockIdx.x * 64;
  int t = threadIdx.x;
  int r = t >> 3, k = t & 7;
  for (int s = 0; s < 2; ++s){
    int rr = r + s * 32;
    const float* src = x + (((size_t)(b * CDIM + c0 + rr)) << 12) + p0 + k * 8;
    f32x4 a = *(const f32x4*)src;
    f32x4 c = *(const f32x4*)(src + 4);
    #pragma unroll
    for (int j = 0; j < 4; ++j){ tile[rr][k * 8 + j] = a[j]; tile[rr][k * 8 + 4 + j] = c[j]; }
  }
  __syncthreads();
  for (int s = 0; s < 2; ++s){
    int pr = r + s * 32;
    float tf[8];
    unsigned short tb[8];
    #pragma unroll
    for (int j = 0; j < 8; ++j){ tf[j] = tile[k * 8 + j][pr]; tb[j] = f2b(tf[j]); }
    size_t rowoff = ((size_t)(b * 4096 + p0 + pr)) << 8;
    *(int4v*)(xpm + rowoff + c0 + k * 8) = *(int4v*)tb;
    *(f32x4*)(xpm32 + rowoff + c0 + k * 8)     = *(f32x4*)&tf[0];
    *(f32x4*)(xpm32 + rowoff + c0 + k * 8 + 4) = *(f32x4*)&tf[4];
  }
}

// ---------------- LayerNorm over C=256 (one row per wave) ----------------------
template<typename IT>
__global__ __launch_bounds__(256) void k_ln(const IT* __restrict__ in,
    const float* __restrict__ w, const float* __restrict__ bia,
    unsigned short* __restrict__ out){
  int row  = blockIdx.x * 4 + (threadIdx.x >> 6);
  int lane = threadIdx.x & 63;
  float v[4];
  const IT* p = in + (size_t)row * CDIM + lane * 4;
  if constexpr (sizeof(IT) == 2){
    int2v d = *(const int2v*)p;
    unsigned short tmp[4]; __builtin_memcpy(tmp, &d, 8);
    #pragma unroll
    for (int j = 0; j < 4; ++j) v[j] = b2f(tmp[j]);
  } else {
    f32x4 d = *(const f32x4*)p;
    #pragma unroll
    for (int j = 0; j < 4; ++j) v[j] = d[j];
  }
  float s  = v[0] + v[1] + v[2] + v[3];
  float s2 = v[0]*v[0] + v[1]*v[1] + v[2]*v[2] + v[3]*v[3];
  #pragma unroll
  for (int m = 1; m < 64; m <<= 1){
    s  += __shfl_xor(s,  m);
    s2 += __shfl_xor(s2, m);
  }
  float mu   = s * (1.0f / 256.0f);
  float var  = s2 * (1.0f / 256.0f) - mu * mu;
  float rstd = rsqrtf(var + 1e-5f);
  unsigned short o[4];
  #pragma unroll
  for (int j = 0; j < 4; ++j){
    int c = lane * 4 + j;
    o[j] = f2b((v[j] - mu) * rstd * w[c] + bia[c]);
  }
  *(int2v*)(out + (size_t)row * CDIM + lane * 4) = *(int2v*)o;
}

// ---------------- MFMA GEMM: C[M,Nout] = A[M,K] * Bw[Nout,ldb]^T + epilogue ----
// 64x128 tile, 4 waves, each wave 32x64 via 2x4 x mfma_f32_16x16x32_bf16.
// Staging via global_load_lds dwordx4: per K-step each wave DMAs 3x1KB
// (A rows 16w..16w+15; B rows 16w.. and 64+16w..). BK=32 => 64B LDS rows:
// linear layout is bank-bandwidth-minimal for ds_read_b128 (no swizzle needed).
template<int MODE>
__global__ __launch_bounds__(256) void k_gemm(
    const unsigned short* __restrict__ A, const unsigned short* __restrict__ Bw,
    int K, int Nout, int ldb, void* __restrict__ outp,
    const float* __restrict__ bias,
    const float* __restrict__ bng,
    const float* __restrict__ bnb,
    const float* __restrict__ auxf,   // MODE1: Xpm32; MODE3: pool_bias; MODE5: TR f32
    int catoff)
{
  __shared__ __align__(16) unsigned short As[64 * 32];    // 4KB
  __shared__ __align__(16) unsigned short Bs[128 * 32];   // 8KB
  int t = threadIdx.x;
  int m0 = blockIdx.y * 64, n0 = blockIdx.x * 128;
  int lane = t & 63;
  int w  = __builtin_amdgcn_readfirstlane(t >> 6);   // wave id (uniform)
  int wm = w >> 1, wn = w & 1;
  int lr = lane & 15, kb = lane >> 4;

  f32x4 acc[2][4];
  f32x4 z = {0.f, 0.f, 0.f, 0.f};
  #pragma unroll
  for (int i = 0; i < 2; ++i)
    #pragma unroll
    for (int j = 0; j < 4; ++j) acc[i][j] = z;

  // per-lane global sources for the DMA (row = w*16 + lane/4, 16B chunk = lane%4)
  int srow = lane >> 2, schunk = (lane & 3) * 8;
  const unsigned short* gA  = A  + (size_t)(m0 + w * 16 + srow) * K   + schunk;
  const unsigned short* gB0 = Bw + (size_t)(n0 + w * 16 + srow) * ldb + schunk;
  const unsigned short* gB1 = Bw + (size_t)(n0 + 64 + w * 16 + srow) * ldb + schunk;
  unsigned short* lA  = As + w * 512;          // 1KB per wave-load
  unsigned short* lB0 = Bs + w * 512;
  unsigned short* lB1 = Bs + 2048 + w * 512;

  for (int k0 = 0; k0 < K; k0 += 32){
    gload16(gA  + k0, lA);
    gload16(gB0 + k0, lB0);
    gload16(gB1 + k0, lB1);
    __syncthreads();
    short8 af[2], bf_[4];
    #pragma unroll
    for (int i = 0; i < 2; ++i) af [i] = *(const short8*)&As[(wm * 32 + i * 16 + lr) * 32 + kb * 8];
    #pragma unroll
    for (int j = 0; j < 4; ++j) bf_[j] = *(const short8*)&Bs[(wn * 64 + j * 16 + lr) * 32 + kb * 8];
    #pragma unroll
    for (int i = 0; i < 2; ++i)
      #pragma unroll
      for (int j = 0; j < 4; ++j)
        acc[i][j] = __builtin_amdgcn_mfma_f32_16x16x32_bf16(af[i], bf_[j], acc[i][j], 0, 0, 0);
    __syncthreads();
  }

  #pragma unroll
  for (int i = 0; i < 2; ++i){
    int rowb = m0 + wm * 32 + i * 16 + kb * 4;
    #pragma unroll
    for (int j = 0; j < 4; ++j){
      int col = n0 + wn * 64 + j * 16 + lr;
      #pragma unroll
      for (int rr = 0; rr < 4; ++rr){
        int row = rowb + rr;
        float v = acc[i][j][rr];
        if constexpr (MODE == 0){            // QKV: plain bf16 store
          ((unsigned short*)outp)[(size_t)row * Nout + col] = f2b(v);
        } else if constexpr (MODE == 1){     // proj + bias + residual(Xpm32) -> CAT
          v += bias[col] + auxf[(size_t)row * CDIM + col];
          ((unsigned short*)outp)[(size_t)row * HIDD + catoff + col] = f2b(v);
        } else if constexpr (MODE == 2){     // tc_conv: bias, bn1, relu -> CAT[:,0:256]
          v = (v + bias[col]) * (bng[col] * BNS) + bnb[col];
          v = fmaxf(v, 0.0f);
          ((unsigned short*)outp)[(size_t)row * HIDD + col] = f2b(v);
        } else if constexpr (MODE == 3){     // tc_trans: + bias + pool_bias, bn3, relu -> TR f32
          v += bias[col] + auxf[((row >> 12) << 8) + col];
          v = v * (bng[col] * BNS) + bnb[col];
          v = fmaxf(v, 0.0f);
          ((float*)outp)[(size_t)row * CDIM + col] = v;
        } else if constexpr (MODE == 4){     // mlp_c1: bias, gelu, bn1 -> H bf16
          v = geluf(v + bias[col]);
          v = v * (bng[col] * BNS) + bnb[col];
          ((unsigned short*)outp)[(size_t)row * HIDD + col] = f2b(v);
        } else {                             // MODE 5: mlp_c2: bias, bn3, +TR, store NCHW f32
          v = (v + bias[col]) * (bng[col] * BNS) + bnb[col];
          v += auxf[(size_t)row * CDIM + col];
          int b = row >> 12, hw = row & 4095;
          ((float*)outp)[(((size_t)(b * CDIM + col)) << 12) + hw] = v;
        }
      }
    }
  }
}

// ---------------- atrous 9-neighbor attention (per pixel, per head) ------------
__global__ __launch_bounds__(256) void k_attn(const unsigned short* __restrict__ QKV,
                                              unsigned short* __restrict__ ATT, int r){
  int t = blockIdx.x * 256 + threadIdx.x;     // 0 .. 131071
  int head = t & 7, pix = t >> 3;
  int hw = pix & 4095, h = hw >> 6, w = hw & 63;
  const unsigned short* base = QKV + (size_t)pix * 768 + head * 32;

  float q[32];
  #pragma unroll
  for (int c8 = 0; c8 < 4; ++c8){
    int4v d = *(const int4v*)(base + c8 * 8);
    unsigned short tmp[8]; __builtin_memcpy(tmp, &d, 16);
    #pragma unroll
    for (int j = 0; j < 8; ++j) q[c8 * 8 + j] = b2f(tmp[j]);
  }
  float logit[9];
  #pragma unroll
  for (int jj = 0; jj < 9; ++jj){
    int dh = (jj / 3 - 1) * r, dw = (jj % 3 - 1) * r;
    int hh = h + dh, ww = w + dw;
    float d = 0.0f;
    if (hh >= 0 && hh < 64 && ww >= 0 && ww < 64){
      const unsigned short* kr = base + (dh * 64 + dw) * 768 + 256;
      #pragma unroll
      for (int c8 = 0; c8 < 4; ++c8){
        int4v dd = *(const int4v*)(kr + c8 * 8);
        unsigned short tmp[8]; __builtin_memcpy(tmp, &dd, 16);
        #pragma unroll
        for (int j = 0; j < 8; ++j) d += q[c8 * 8 + j] * b2f(tmp[j]);
      }
    }
    logit[jj] = d * 0.17677669529663687f;   // hd^-0.5, OOB taps keep logit 0 (zero-pad)
  }
  float m = logit[0];
  #pragma unroll
  for (int jj = 1; jj < 9; ++jj) m = fmaxf(m, logit[jj]);
  float p[9], s = 0.0f;
  #pragma unroll
  for (int jj = 0; jj < 9; ++jj){ p[jj] = __expf(logit[jj] - m); s += p[jj]; }
  float inv = 1.0f / s;
  float o[32];
  #pragma unroll
  for (int j = 0; j < 32; ++j) o[j] = 0.0f;
  #pragma unroll
  for (int jj = 0; jj < 9; ++jj){
    int dh = (jj / 3 - 1) * r, dw = (jj % 3 - 1) * r;
    int hh = h + dh, ww = w + dw;
    if (hh >= 0 && hh < 64 && ww >= 0 && ww < 64){
      float pj = p[jj] * inv;
      const unsigned short* vr = base + (dh * 64 + dw) * 768 + 512;
      #pragma unroll
      for (int c8 = 0; c8 < 4; ++c8){
        int4v dd = *(const int4v*)(vr + c8 * 8);
        unsigned short tmp[8]; __builtin_memcpy(tmp, &dd, 16);
        #pragma unroll
        for (int j = 0; j < 8; ++j) o[c8 * 8 + j] += pj * b2f(tmp[j]);
      }
    }
  }
  unsigned short ob[32];
  #pragma unroll
  for (int j = 0; j < 32; ++j) ob[j] = f2b(o[j]);
  unsigned short* op = ATT + (size_t)pix * CDIM + head * 32;
  #pragma unroll
  for (int c8 = 0; c8 < 4; ++c8) *(int4v*)(op + c8 * 8) = *(int4v*)&ob[c8 * 8];
}

// ---------------- depthwise 3x3 + gelu + bn2 -----------------------------------
__global__ __launch_bounds__(256) void k_dwconv(const unsigned short* __restrict__ H,
    const unsigned short* __restrict__ dwwT, const float* __restrict__ dwb,
    const float* __restrict__ g, const float* __restrict__ bb,
    unsigned short* __restrict__ H2){
  int t = blockIdx.x * 256 + threadIdx.x;   // 16384 * 128
  int chunk = t & 127, pix = t >> 7;
  int hw = pix & 4095, h = hw >> 6, w = hw & 63;
  int c0 = chunk * 8;
  float acc[8], hc[8];
  {
    int4v dd = *(const int4v*)(H + (size_t)pix * HIDD + c0);
    unsigned short tmp[8]; __builtin_memcpy(tmp, &dd, 16);
    #pragma unroll
    for (int j = 0; j < 8; ++j){ hc[j] = b2f(tmp[j]); acc[j] = 0.0f; }
  }
  #pragma unroll
  for (int di = -1; di <= 1; ++di)
    #pragma unroll
    for (int dj = -1; dj <= 1; ++dj){
      int hh = h + di, ww = w + dj;
      if (hh < 0 || hh >= 64 || ww < 0 || ww >= 64) continue;
      int kk = (di + 1) * 3 + (dj + 1);
      int4v dd = *(const int4v*)(H + ((size_t)(pix + di * 64 + dj)) * HIDD + c0);
      int4v wv = *(const int4v*)(dwwT + kk * 1024 + c0);
      unsigned short tmp[8], wt[8];
      __builtin_memcpy(tmp, &dd, 16);
      __builtin_memcpy(wt,  &wv, 16);
      #pragma unroll
      for (int j = 0; j < 8; ++j) acc[j] += b2f(wt[j]) * b2f(tmp[j]);
    }
  f32x4 bv0 = *(const f32x4*)(dwb + c0), bv1 = *(const f32x4*)(dwb + c0 + 4);
  f32x4 gv0 = *(const f32x4*)(g   + c0), gv1 = *(const f32x4*)(g   + c0 + 4);
  f32x4 cv0 = *(const f32x4*)(bb  + c0), cv1 = *(const f32x4*)(bb  + c0 + 4);
  float bvv[8], gvv[8], cvv[8];
  #pragma unroll
  for (int j = 0; j < 4; ++j){
    bvv[j] = bv0[j]; bvv[4 + j] = bv1[j];
    gvv[j] = gv0[j]; gvv[4 + j] = gv1[j];
    cvv[j] = cv0[j]; cvv[4 + j] = cv1[j];
  }
  unsigned short ob[8];
  #pragma unroll
  for (int j = 0; j < 8; ++j){
    float v = acc[j] + bvv[j] + hc[j];
    v = geluf(v);
    v = v * (gvv[j] * BNS) + cvv[j];
    ob[j] = f2b(v);
  }
  *(int4v*)(H2 + (size_t)pix * HIDD + c0) = *(int4v*)ob;
}

// ---------------- pool path ----------------------------------------------------
__global__ __launch_bounds__(256) void k_pool_mean(const float* __restrict__ x,
                                                   float* __restrict__ pm){
  int bc = blockIdx.x;
  const float* p = x + ((size_t)bc << 12);
  int t = threadIdx.x;
  float s = 0.0f;
  for (int i = t * 4; i < 4096; i += 1024){
    f32x4 dd = *(const f32x4*)(p + i);
    s += dd[0] + dd[1] + dd[2] + dd[3];
  }
  #pragma unroll
  for (int m = 1; m < 64; m <<= 1) s += __shfl_xor(s, m);
  __shared__ float red[4];
  if ((t & 63) == 0) red[t >> 6] = s;
  __syncthreads();
  if (t == 0) pm[bc] = (red[0] + red[1] + red[2] + red[3]) * (1.0f / 4096.0f);
}

// fused: pf = relu(bn(poolw @ pm)); pb = trw[:,1024:1280] @ pf
__global__ __launch_bounds__(256) void k_poolfb(const float* __restrict__ pm,
    const float* __restrict__ pw, const float* __restrict__ g,
    const float* __restrict__ bb, const float* __restrict__ tw,
    float* __restrict__ pb){
  int b = blockIdx.x, o = threadIdx.x;
  __shared__ float v[256];
  __shared__ float pfs[256];
  v[o] = pm[b * 256 + o];
  __syncthreads();
  float acc = 0.0f;
  const float* wr = pw + (size_t)o * 256;
  for (int c = 0; c < 256; ++c) acc += v[c] * wr[c];
  float val = acc * (g[o] * BNS) + bb[o];
  pfs[o] = fmaxf(val, 0.0f);
  __syncthreads();
  float acc2 = 0.0f;
  const float* tr = tw + (size_t)o * 1280 + 1024;
  for (int c = 0; c < 256; ++c) acc2 += pfs[c] * tr[c];
  pb[b * 256 + o] = acc2;
}

// ---------------- launch -------------------------------------------------------
extern "C" void kernel_launch(void* const* d_in, const int* in_sizes, int n_in,
                              void* d_out, int out_size, void* d_ws, size_t ws_size,
                              hipStream_t stream){
  const float* x     = (const float*)d_in[0];
  const float* ln1w  = (const float*)d_in[1];
  const float* ln1b  = (const float*)d_in[2];
  const float* ln2w  = (const float*)d_in[3];
  const float* ln2b  = (const float*)d_in[4];
  const float* qkvw[3]  = {(const float*)d_in[5], (const float*)d_in[8],  (const float*)d_in[11]};
  const float* projw[3] = {(const float*)d_in[6], (const float*)d_in[9],  (const float*)d_in[12]};
  const float* projb[3] = {(const float*)d_in[7], (const float*)d_in[10], (const float*)d_in[13]};
  const float* tcw   = (const float*)d_in[14];
  const float* tcb   = (const float*)d_in[15];
  const float* bn1g  = (const float*)d_in[16];
  const float* bn1b  = (const float*)d_in[17];
  const float* poolw = (const float*)d_in[18];
  const float* bn2g  = (const float*)d_in[19];
  const float* bn2b  = (const float*)d_in[20];
  const float* trw   = (const float*)d_in[21];
  const float* trb   = (const float*)d_in[22];
  const float* bn3g  = (const float*)d_in[23];
  const float* bn3b  = (const float*)d_in[24];
  const float* c1w   = (const float*)d_in[25];
  const float* c1b   = (const float*)d_in[26];
  const float* mbn1g = (const float*)d_in[27];
  const float* mbn1b = (const float*)d_in[28];
  const float* dww   = (const float*)d_in[29];
  const float* dwb   = (const float*)d_in[30];
  const float* mbn2g = (const float*)d_in[31];
  const float* mbn2b = (const float*)d_in[32];
  const float* c2w   = (const float*)d_in[33];
  const float* c2b   = (const float*)d_in[34];
  const float* mbn3g = (const float*)d_in[35];
  const float* mbn3b = (const float*)d_in[36];

  char* ws = (char*)d_ws;
  unsigned short* Xpm = (unsigned short*)(ws);                 //  8.4 MB [N,256] bf16
  unsigned short* N1  = (unsigned short*)(ws + 8388608);       //  8.4 MB [N,256] (later N2)
  unsigned short* CAT = (unsigned short*)(ws + 16777216);      // 33.6 MB [N,1024] xc1|t1|t2|t3
  float*          TR  = (float*)        (ws + 50331648);       // 16.8 MB: Xpm32 (early), TR (late)
  float*          Xpm32 = TR;                                  // alias — disjoint live ranges
  unsigned short* E   = (unsigned short*)(ws + 67108864);      // 33.6 MB QKV then H
  unsigned short* F   = (unsigned short*)(ws + 100663296);     // 33.6 MB ATT then H2
  // bf16 weight staging area (contiguous, in k_cvt_all segment order)
  unsigned short* Wb    = (unsigned short*)(ws + 134217728);
  unsigned short* qkvb[3]  = {Wb, Wb + 196608, Wb + 393216};            // 3 x 196608
  unsigned short* projbw[3] = {Wb + 589824, Wb + 655360, Wb + 720896};  // 3 x 65536
  unsigned short* tcwb  = Wb + 786432;                                  // 65536
  unsigned short* trwb  = Wb + 851968;                                  // 327680
  unsigned short* c1wb  = Wb + 1179648;                                 // 262144
  unsigned short* c2wb  = Wb + 1441792;                                 // 262144
  unsigned short* dwwT  = Wb + 1703936;                                 // 9216
  float*          pm  = (float*)(ws + 134217728 + 3428352);
  float*          pb  = pm + 1024;

  // weight conversion (fp32 -> bf16), one fused launch + dw transpose
  k_cvt_all<<<dim3(160, 10), 256, 0, stream>>>(qkvw[0], qkvw[1], qkvw[2],
                                               projw[0], projw[1], projw[2],
                                               tcw, trw, c1w, c2w, Wb);
  k_dwwT<<<36, 256, 0, stream>>>(dww, dwwT);

  k_transpose<<<dim3(64, 4, 4), 256, 0, stream>>>(x, Xpm, Xpm32);
  k_pool_mean<<<1024, 256, 0, stream>>>(x, pm);
  k_ln<unsigned short><<<4096, 256, 0, stream>>>(Xpm, ln1w, ln1b, N1);
  k_poolfb<<<4, 256, 0, stream>>>(pm, poolw, bn2g, bn2b, trw, pb);

  for (int i = 0; i < 3; ++i){
    k_gemm<0><<<dim3(6, 256), 256, 0, stream>>>(N1, qkvb[i], 256, 768, 256, E,
                                                nullptr, nullptr, nullptr, nullptr, 0);
    k_attn<<<512, 256, 0, stream>>>(E, F, i + 1);
    k_gemm<1><<<dim3(2, 256), 256, 0, stream>>>(F, projbw[i], 256, 256, 256, CAT,
                                                projb[i], nullptr, nullptr, Xpm32,
                                                (i + 1) * 256);
  }
  k_gemm<2><<<dim3(2, 256), 256, 0, stream>>>(Xpm, tcwb, 256, 256, 256, CAT,
                                              tcb, bn1g, bn1b, nullptr, 0);
  k_gemm<3><<<dim3(2, 256), 256, 0, stream>>>(CAT, trwb, 1024, 256, 1280, TR,
                                              trb, bn3g, bn3b, pb, 0);
  k_ln<float><<<4096, 256, 0, stream>>>(TR, ln2w, ln2b, N1);   // N2 reuses N1
  k_gemm<4><<<dim3(8, 256), 256, 0, stream>>>(N1, c1wb, 256, 1024, 256, E,
                                              c1b, mbn1g, mbn1b, nullptr, 0);
  k_dwconv<<<8192, 256, 0, stream>>>(E, dwwT, dwb, mbn2g, mbn2b, F);
  k_gemm<5><<<dim3(2, 256), 256, 0, stream>>>(F, c2wb, 1024, 256, 1024, d_out,
                                              c2b, mbn3g, mbn3b, TR, 0);
}

// Round 8
// 428.763 us; speedup vs baseline: 1.8878x; 1.0119x over previous
//
#include <hip/hip_runtime.h>

#define N_PIX 16384
#define CDIM  256
#define HIDD  1024
#define BNS   0.9999950000374997f   // (1+1e-5)^-0.5

typedef __attribute__((ext_vector_type(8))) short  short8;
typedef __attribute__((ext_vector_type(4))) float  f32x4;
typedef __attribute__((ext_vector_type(4))) int    int4v;
typedef __attribute__((ext_vector_type(2))) int    int2v;

__device__ __forceinline__ float b2f(unsigned short u){
  unsigned int x = ((unsigned int)u) << 16; float f;
  __builtin_memcpy(&f, &x, 4); return f;
}
__device__ __forceinline__ unsigned short f2b(float f){
  unsigned int x; __builtin_memcpy(&x, &f, 4);
  unsigned int r = (x + 0x7fffu + ((x >> 16) & 1u)) >> 16;
  return (unsigned short)r;
}
__device__ __forceinline__ float geluf(float x){
  return 0.5f * x * (1.0f + erff(x * 0.70710678118654752f));
}

// async global->LDS DMA, 16B per lane, wave-uniform LDS base + lane*16
typedef const __attribute__((address_space(1))) unsigned int* gas_t;
typedef __attribute__((address_space(3))) unsigned int*       las_t;
__device__ __forceinline__ void gload16(const void* g, void* l){
  __builtin_amdgcn_global_load_lds((gas_t)g, (las_t)l, 16, 0, 0);
}

// ---------------- fused fp32 -> bf16 weight conversion (10 segments) ----------
__global__ __launch_bounds__(256) void k_cvt_all(
    const float* __restrict__ s0, const float* __restrict__ s1, const float* __restrict__ s2,
    const float* __restrict__ s3, const float* __restrict__ s4, const float* __restrict__ s5,
    const float* __restrict__ s6, const float* __restrict__ s7, const float* __restrict__ s8,
    const float* __restrict__ s9, unsigned short* __restrict__ wb){
  const float* srcs[10] = {s0,s1,s2,s3,s4,s5,s6,s7,s8,s9};
  const int n[10]   = {196608,196608,196608,65536,65536,65536,65536,327680,262144,262144};
  const int off[10] = {0,196608,393216,589824,655360,720896,786432,851968,1179648,1441792};
  int seg = blockIdx.y;
  int i = (blockIdx.x * 256 + threadIdx.x) * 8;
  if (i >= n[seg]) return;
  const float* src = srcs[seg];
  unsigned short* dst = wb + off[seg];
  f32x4 a = *(const f32x4*)(src + i);
  f32x4 b = *(const f32x4*)(src + i + 4);
  unsigned short o[8];
  #pragma unroll
  for (int j = 0; j < 4; ++j){ o[j] = f2b(a[j]); o[4 + j] = f2b(b[j]); }
  *(int4v*)(dst + i) = *(int4v*)o;
}

// ---------------- dw weights: [1024,1,3,3] f32 -> [9][1024] bf16 ---------------
__global__ __launch_bounds__(256) void k_dwwT(const float* __restrict__ dww,
                                              unsigned short* __restrict__ dwwT){
  int i = blockIdx.x * 256 + threadIdx.x;     // 0..9215
  if (i >= 9216) return;
  int kk = i >> 10, c = i & 1023;
  dwwT[i] = f2b(dww[c * 9 + kk]);
}

// ------- transpose: x [B,C,4096] f32 -> Xpm [N,256] bf16 + Xpm32 [N,256] f32 ---
__global__ __launch_bounds__(256) void k_transpose(const float* __restrict__ x,
                                                   unsigned short* __restrict__ xpm,
                                                   float* __restrict__ xpm32){
  __shared__ __align__(16) float tile[64][65];
  int b = blockIdx.z, c0 = blockIdx.y * 64, p0 = blockIdx.x * 64;
  int t = threadIdx.x;
  int r = t >> 3, k = t & 7;
  for (int s = 0; s < 2; ++s){
    int rr = r + s * 32;
    const float* src = x + (((size_t)(b * CDIM + c0 + rr)) << 12) + p0 + k * 8;
    f32x4 a = *(const f32x4*)src;
    f32x4 c = *(const f32x4*)(src + 4);
    #pragma unroll
    for (int j = 0; j < 4; ++j){ tile[rr][k * 8 + j] = a[j]; tile[rr][k * 8 + 4 + j] = c[j]; }
  }
  __syncthreads();
  for (int s = 0; s < 2; ++s){
    int pr = r + s * 32;
    float tf[8];
    unsigned short tb[8];
    #pragma unroll
    for (int j = 0; j < 8; ++j){ tf[j] = tile[k * 8 + j][pr]; tb[j] = f2b(tf[j]); }
    size_t rowoff = ((size_t)(b * 4096 + p0 + pr)) << 8;
    *(int4v*)(xpm + rowoff + c0 + k * 8) = *(int4v*)tb;
    *(f32x4*)(xpm32 + rowoff + c0 + k * 8)     = *(f32x4*)&tf[0];
    *(f32x4*)(xpm32 + rowoff + c0 + k * 8 + 4) = *(f32x4*)&tf[4];
  }
}

// ---------------- LayerNorm over C=256 (one row per wave) ----------------------
template<typename IT>
__global__ __launch_bounds__(256) void k_ln(const IT* __restrict__ in,
    const float* __restrict__ w, const float* __restrict__ bia,
    unsigned short* __restrict__ out){
  int row  = blockIdx.x * 4 + (threadIdx.x >> 6);
  int lane = threadIdx.x & 63;
  float v[4];
  const IT* p = in + (size_t)row * CDIM + lane * 4;
  if constexpr (sizeof(IT) == 2){
    int2v d = *(const int2v*)p;
    unsigned short tmp[4]; __builtin_memcpy(tmp, &d, 8);
    #pragma unroll
    for (int j = 0; j < 4; ++j) v[j] = b2f(tmp[j]);
  } else {
    f32x4 d = *(const f32x4*)p;
    #pragma unroll
    for (int j = 0; j < 4; ++j) v[j] = d[j];
  }
  float s  = v[0] + v[1] + v[2] + v[3];
  float s2 = v[0]*v[0] + v[1]*v[1] + v[2]*v[2] + v[3]*v[3];
  #pragma unroll
  for (int m = 1; m < 64; m <<= 1){
    s  += __shfl_xor(s,  m);
    s2 += __shfl_xor(s2, m);
  }
  float mu   = s * (1.0f / 256.0f);
  float var  = s2 * (1.0f / 256.0f) - mu * mu;
  float rstd = rsqrtf(var + 1e-5f);
  unsigned short o[4];
  #pragma unroll
  for (int j = 0; j < 4; ++j){
    int c = lane * 4 + j;
    o[j] = f2b((v[j] - mu) * rstd * w[c] + bia[c]);
  }
  *(int2v*)(out + (size_t)row * CDIM + lane * 4) = *(int2v*)o;
}

// ---------------- MFMA GEMM: C[M,Nout] = A[M,K] * Bw[Nout,ldb]^T + epilogue ----
// 64x128 tile, 4 waves, each wave 32x64 via 2x4 x mfma_f32_16x16x32_bf16.
// Double-buffered global_load_lds staging (2-phase): prefetch K-step t+1 into
// buf^1 BEFORE computing buf; __syncthreads() (implicit vmcnt drain) at the end
// of each step — load latency hides under ds_read+MFMA instead of stalling.
template<int MODE>
__global__ __launch_bounds__(256) void k_gemm(
    const unsigned short* __restrict__ A, const unsigned short* __restrict__ Bw,
    int K, int Nout, int ldb, void* __restrict__ outp,
    const float* __restrict__ bias,
    const float* __restrict__ bng,
    const float* __restrict__ bnb,
    const float* __restrict__ auxf,   // MODE1: Xpm32; MODE3: pool_bias; MODE5: TR f32
    int catoff)
{
  __shared__ __align__(16) unsigned short As[2][64 * 32];    // 2 x 4KB
  __shared__ __align__(16) unsigned short Bs[2][128 * 32];   // 2 x 8KB
  int t = threadIdx.x;
  int m0 = blockIdx.y * 64, n0 = blockIdx.x * 128;
  int lane = t & 63;
  int w  = __builtin_amdgcn_readfirstlane(t >> 6);   // wave id (uniform)
  int wm = w >> 1, wn = w & 1;
  int lr = lane & 15, kb = lane >> 4;

  f32x4 acc[2][4];
  f32x4 z = {0.f, 0.f, 0.f, 0.f};
  #pragma unroll
  for (int i = 0; i < 2; ++i)
    #pragma unroll
    for (int j = 0; j < 4; ++j) acc[i][j] = z;

  // per-lane global sources for the DMA (row = w*16 + lane/4, 16B chunk = lane%4)
  int srow = lane >> 2, schunk = (lane & 3) * 8;
  const unsigned short* gA  = A  + (size_t)(m0 + w * 16 + srow) * K   + schunk;
  const unsigned short* gB0 = Bw + (size_t)(n0 + w * 16 + srow) * ldb + schunk;
  const unsigned short* gB1 = Bw + (size_t)(n0 + 64 + w * 16 + srow) * ldb + schunk;

  const int nt = K >> 5;
  // prologue: stage K-step 0 into buf 0
  gload16(gA,  As[0] + w * 512);
  gload16(gB0, Bs[0] + w * 512);
  gload16(gB1, Bs[0] + 2048 + w * 512);
  __syncthreads();

  for (int tt = 0; tt < nt; ++tt){
    int cur = tt & 1;
    if (tt + 1 < nt){
      int k1 = (tt + 1) << 5;
      gload16(gA  + k1, As[cur ^ 1] + w * 512);
      gload16(gB0 + k1, Bs[cur ^ 1] + w * 512);
      gload16(gB1 + k1, Bs[cur ^ 1] + 2048 + w * 512);
    }
    short8 af[2], bf_[4];
    #pragma unroll
    for (int i = 0; i < 2; ++i)
      af [i] = *(const short8*)&As[cur][(wm * 32 + i * 16 + lr) * 32 + kb * 8];
    #pragma unroll
    for (int j = 0; j < 4; ++j)
      bf_[j] = *(const short8*)&Bs[cur][(wn * 64 + j * 16 + lr) * 32 + kb * 8];
    #pragma unroll
    for (int i = 0; i < 2; ++i)
      #pragma unroll
      for (int j = 0; j < 4; ++j)
        acc[i][j] = __builtin_amdgcn_mfma_f32_16x16x32_bf16(af[i], bf_[j], acc[i][j], 0, 0, 0);
    __syncthreads();   // drains prefetch vmcnt + protects buffer reuse
  }

  #pragma unroll
  for (int i = 0; i < 2; ++i){
    int rowb = m0 + wm * 32 + i * 16 + kb * 4;
    #pragma unroll
    for (int j = 0; j < 4; ++j){
      int col = n0 + wn * 64 + j * 16 + lr;
      #pragma unroll
      for (int rr = 0; rr < 4; ++rr){
        int row = rowb + rr;
        float v = acc[i][j][rr];
        if constexpr (MODE == 0){            // QKV: plain bf16 store
          ((unsigned short*)outp)[(size_t)row * Nout + col] = f2b(v);
        } else if constexpr (MODE == 1){     // proj + bias + residual(Xpm32) -> CAT
          v += bias[col] + auxf[(size_t)row * CDIM + col];
          ((unsigned short*)outp)[(size_t)row * HIDD + catoff + col] = f2b(v);
        } else if constexpr (MODE == 2){     // tc_conv: bias, bn1, relu -> CAT[:,0:256]
          v = (v + bias[col]) * (bng[col] * BNS) + bnb[col];
          v = fmaxf(v, 0.0f);
          ((unsigned short*)outp)[(size_t)row * HIDD + col] = f2b(v);
        } else if constexpr (MODE == 3){     // tc_trans: + bias + pool_bias, bn3, relu -> TR f32
          v += bias[col] + auxf[((row >> 12) << 8) + col];
          v = v * (bng[col] * BNS) + bnb[col];
          v = fmaxf(v, 0.0f);
          ((float*)outp)[(size_t)row * CDIM + col] = v;
        } else if constexpr (MODE == 4){     // mlp_c1: bias, gelu, bn1 -> H bf16
          v = geluf(v + bias[col]);
          v = v * (bng[col] * BNS) + bnb[col];
          ((unsigned short*)outp)[(size_t)row * HIDD + col] = f2b(v);
        } else {                             // MODE 5: mlp_c2: bias, bn3, +TR, store NCHW f32
          v = (v + bias[col]) * (bng[col] * BNS) + bnb[col];
          v += auxf[(size_t)row * CDIM + col];
          int b = row >> 12, hw = row & 4095;
          ((float*)outp)[(((size_t)(b * CDIM + col)) << 12) + hw] = v;
        }
      }
    }
  }
}

// ---------------- atrous 9-neighbor attention (per pixel, per head) ------------
__global__ __launch_bounds__(256) void k_attn(const unsigned short* __restrict__ QKV,
                                              unsigned short* __restrict__ ATT, int r){
  int t = blockIdx.x * 256 + threadIdx.x;     // 0 .. 131071
  int head = t & 7, pix = t >> 3;
  int hw = pix & 4095, h = hw >> 6, w = hw & 63;
  const unsigned short* base = QKV + (size_t)pix * 768 + head * 32;

  float q[32];
  #pragma unroll
  for (int c8 = 0; c8 < 4; ++c8){
    int4v d = *(const int4v*)(base + c8 * 8);
    unsigned short tmp[8]; __builtin_memcpy(tmp, &d, 16);
    #pragma unroll
    for (int j = 0; j < 8; ++j) q[c8 * 8 + j] = b2f(tmp[j]);
  }
  float logit[9];
  #pragma unroll
  for (int jj = 0; jj < 9; ++jj){
    int dh = (jj / 3 - 1) * r, dw = (jj % 3 - 1) * r;
    int hh = h + dh, ww = w + dw;
    float d = 0.0f;
    if (hh >= 0 && hh < 64 && ww >= 0 && ww < 64){
      const unsigned short* kr = base + (dh * 64 + dw) * 768 + 256;
      #pragma unroll
      for (int c8 = 0; c8 < 4; ++c8){
        int4v dd = *(const int4v*)(kr + c8 * 8);
        unsigned short tmp[8]; __builtin_memcpy(tmp, &dd, 16);
        #pragma unroll
        for (int j = 0; j < 8; ++j) d += q[c8 * 8 + j] * b2f(tmp[j]);
      }
    }
    logit[jj] = d * 0.17677669529663687f;   // hd^-0.5, OOB taps keep logit 0 (zero-pad)
  }
  float m = logit[0];
  #pragma unroll
  for (int jj = 1; jj < 9; ++jj) m = fmaxf(m, logit[jj]);
  float p[9], s = 0.0f;
  #pragma unroll
  for (int jj = 0; jj < 9; ++jj){ p[jj] = __expf(logit[jj] - m); s += p[jj]; }
  float inv = 1.0f / s;
  float o[32];
  #pragma unroll
  for (int j = 0; j < 32; ++j) o[j] = 0.0f;
  #pragma unroll
  for (int jj = 0; jj < 9; ++jj){
    int dh = (jj / 3 - 1) * r, dw = (jj % 3 - 1) * r;
    int hh = h + dh, ww = w + dw;
    if (hh >= 0 && hh < 64 && ww >= 0 && ww < 64){
      float pj = p[jj] * inv;
      const unsigned short* vr = base + (dh * 64 + dw) * 768 + 512;
      #pragma unroll
      for (int c8 = 0; c8 < 4; ++c8){
        int4v dd = *(const int4v*)(vr + c8 * 8);
        unsigned short tmp[8]; __builtin_memcpy(tmp, &dd, 16);
        #pragma unroll
        for (int j = 0; j < 8; ++j) o[c8 * 8 + j] += pj * b2f(tmp[j]);
      }
    }
  }
  unsigned short ob[32];
  #pragma unroll
  for (int j = 0; j < 32; ++j) ob[j] = f2b(o[j]);
  unsigned short* op = ATT + (size_t)pix * CDIM + head * 32;
  #pragma unroll
  for (int c8 = 0; c8 < 4; ++c8) *(int4v*)(op + c8 * 8) = *(int4v*)&ob[c8 * 8];
}

// ---------------- depthwise 3x3 + gelu + bn2 -----------------------------------
__global__ __launch_bounds__(256) void k_dwconv(const unsigned short* __restrict__ H,
    const unsigned short* __restrict__ dwwT, const float* __restrict__ dwb,
    const float* __restrict__ g, const float* __restrict__ bb,
    unsigned short* __restrict__ H2){
  int t = blockIdx.x * 256 + threadIdx.x;   // 16384 * 128
  int chunk = t & 127, pix = t >> 7;
  int hw = pix & 4095, h = hw >> 6, w = hw & 63;
  int c0 = chunk * 8;
  float acc[8], hc[8];
  {
    int4v dd = *(const int4v*)(H + (size_t)pix * HIDD + c0);
    unsigned short tmp[8]; __builtin_memcpy(tmp, &dd, 16);
    #pragma unroll
    for (int j = 0; j < 8; ++j){ hc[j] = b2f(tmp[j]); acc[j] = 0.0f; }
  }
  #pragma unroll
  for (int di = -1; di <= 1; ++di)
    #pragma unroll
    for (int dj = -1; dj <= 1; ++dj){
      int hh = h + di, ww = w + dj;
      if (hh < 0 || hh >= 64 || ww < 0 || ww >= 64) continue;
      int kk = (di + 1) * 3 + (dj + 1);
      int4v dd = *(const int4v*)(H + ((size_t)(pix + di * 64 + dj)) * HIDD + c0);
      int4v wv = *(const int4v*)(dwwT + kk * 1024 + c0);
      unsigned short tmp[8], wt[8];
      __builtin_memcpy(tmp, &dd, 16);
      __builtin_memcpy(wt,  &wv, 16);
      #pragma unroll
      for (int j = 0; j < 8; ++j) acc[j] += b2f(wt[j]) * b2f(tmp[j]);
    }
  f32x4 bv0 = *(const f32x4*)(dwb + c0), bv1 = *(const f32x4*)(dwb + c0 + 4);
  f32x4 gv0 = *(const f32x4*)(g   + c0), gv1 = *(const f32x4*)(g   + c0 + 4);
  f32x4 cv0 = *(const f32x4*)(bb  + c0), cv1 = *(const f32x4*)(bb  + c0 + 4);
  float bvv[8], gvv[8], cvv[8];
  #pragma unroll
  for (int j = 0; j < 4; ++j){
    bvv[j] = bv0[j]; bvv[4 + j] = bv1[j];
    gvv[j] = gv0[j]; gvv[4 + j] = gv1[j];
    cvv[j] = cv0[j]; cvv[4 + j] = cv1[j];
  }
  unsigned short ob[8];
  #pragma unroll
  for (int j = 0; j < 8; ++j){
    float v = acc[j] + bvv[j] + hc[j];
    v = geluf(v);
    v = v * (gvv[j] * BNS) + cvv[j];
    ob[j] = f2b(v);
  }
  *(int4v*)(H2 + (size_t)pix * HIDD + c0) = *(int4v*)ob;
}

// ---------------- pool path ----------------------------------------------------
__global__ __launch_bounds__(256) void k_pool_mean(const float* __restrict__ x,
                                                   float* __restrict__ pm){
  int bc = blockIdx.x;
  const float* p = x + ((size_t)bc << 12);
  int t = threadIdx.x;
  float s = 0.0f;
  for (int i = t * 4; i < 4096; i += 1024){
    f32x4 dd = *(const f32x4*)(p + i);
    s += dd[0] + dd[1] + dd[2] + dd[3];
  }
  #pragma unroll
  for (int m = 1; m < 64; m <<= 1) s += __shfl_xor(s, m);
  __shared__ float red[4];
  if ((t & 63) == 0) red[t >> 6] = s;
  __syncthreads();
  if (t == 0) pm[bc] = (red[0] + red[1] + red[2] + red[3]) * (1.0f / 4096.0f);
}

// fused: pf = relu(bn(poolw @ pm)); pb = trw[:,1024:1280] @ pf
__global__ __launch_bounds__(256) void k_poolfb(const float* __restrict__ pm,
    const float* __restrict__ pw, const float* __restrict__ g,
    const float* __restrict__ bb, const float* __restrict__ tw,
    float* __restrict__ pb){
  int b = blockIdx.x, o = threadIdx.x;
  __shared__ float v[256];
  __shared__ float pfs[256];
  v[o] = pm[b * 256 + o];
  __syncthreads();
  float acc = 0.0f;
  const float* wr = pw + (size_t)o * 256;
  for (int c = 0; c < 256; ++c) acc += v[c] * wr[c];
  float val = acc * (g[o] * BNS) + bb[o];
  pfs[o] = fmaxf(val, 0.0f);
  __syncthreads();
  float acc2 = 0.0f;
  const float* tr = tw + (size_t)o * 1280 + 1024;
  for (int c = 0; c < 256; ++c) acc2 += pfs[c] * tr[c];
  pb[b * 256 + o] = acc2;
}

// ---------------- launch -------------------------------------------------------
extern "C" void kernel_launch(void* const* d_in, const int* in_sizes, int n_in,
                              void* d_out, int out_size, void* d_ws, size_t ws_size,
                              hipStream_t stream){
  const float* x     = (const float*)d_in[0];
  const float* ln1w  = (const float*)d_in[1];
  const float* ln1b  = (const float*)d_in[2];
  const float* ln2w  = (const float*)d_in[3];
  const float* ln2b  = (const float*)d_in[4];
  const float* qkvw[3]  = {(const float*)d_in[5], (const float*)d_in[8],  (const float*)d_in[11]};
  const float* projw[3] = {(const float*)d_in[6], (const float*)d_in[9],  (const float*)d_in[12]};
  const float* projb[3] = {(const float*)d_in[7], (const float*)d_in[10], (const float*)d_in[13]};
  const float* tcw   = (const float*)d_in[14];
  const float* tcb   = (const float*)d_in[15];
  const float* bn1g  = (const float*)d_in[16];
  const float* bn1b  = (const float*)d_in[17];
  const float* poolw = (const float*)d_in[18];
  const float* bn2g  = (const float*)d_in[19];
  const float* bn2b  = (const float*)d_in[20];
  const float* trw   = (const float*)d_in[21];
  const float* trb   = (const float*)d_in[22];
  const float* bn3g  = (const float*)d_in[23];
  const float* bn3b  = (const float*)d_in[24];
  const float* c1w   = (const float*)d_in[25];
  const float* c1b   = (const float*)d_in[26];
  const float* mbn1g = (const float*)d_in[27];
  const float* mbn1b = (const float*)d_in[28];
  const float* dww   = (const float*)d_in[29];
  const float* dwb   = (const float*)d_in[30];
  const float* mbn2g = (const float*)d_in[31];
  const float* mbn2b = (const float*)d_in[32];
  const float* c2w   = (const float*)d_in[33];
  const float* c2b   = (const float*)d_in[34];
  const float* mbn3g = (const float*)d_in[35];
  const float* mbn3b = (const float*)d_in[36];

  char* ws = (char*)d_ws;
  unsigned short* Xpm = (unsigned short*)(ws);                 //  8.4 MB [N,256] bf16
  unsigned short* N1  = (unsigned short*)(ws + 8388608);       //  8.4 MB [N,256] (later N2)
  unsigned short* CAT = (unsigned short*)(ws + 16777216);      // 33.6 MB [N,1024] xc1|t1|t2|t3
  float*          TR  = (float*)        (ws + 50331648);       // 16.8 MB: Xpm32 (early), TR (late)
  float*          Xpm32 = TR;                                  // alias — disjoint live ranges
  unsigned short* E   = (unsigned short*)(ws + 67108864);      // 33.6 MB QKV then H
  unsigned short* F   = (unsigned short*)(ws + 100663296);     // 33.6 MB ATT then H2
  // bf16 weight staging area (contiguous, in k_cvt_all segment order)
  unsigned short* Wb    = (unsigned short*)(ws + 134217728);
  unsigned short* qkvb[3]  = {Wb, Wb + 196608, Wb + 393216};            // 3 x 196608
  unsigned short* projbw[3] = {Wb + 589824, Wb + 655360, Wb + 720896};  // 3 x 65536
  unsigned short* tcwb  = Wb + 786432;                                  // 65536
  unsigned short* trwb  = Wb + 851968;                                  // 327680
  unsigned short* c1wb  = Wb + 1179648;                                 // 262144
  unsigned short* c2wb  = Wb + 1441792;                                 // 262144
  unsigned short* dwwT  = Wb + 1703936;                                 // 9216
  float*          pm  = (float*)(ws + 134217728 + 3428352);
  float*          pb  = pm + 1024;

  // weight conversion (fp32 -> bf16), one fused launch + dw transpose
  k_cvt_all<<<dim3(160, 10), 256, 0, stream>>>(qkvw[0], qkvw[1], qkvw[2],
                                               projw[0], projw[1], projw[2],
                                               tcw, trw, c1w, c2w, Wb);
  k_dwwT<<<36, 256, 0, stream>>>(dww, dwwT);

  k_transpose<<<dim3(64, 4, 4), 256, 0, stream>>>(x, Xpm, Xpm32);
  k_pool_mean<<<1024, 256, 0, stream>>>(x, pm);
  k_ln<unsigned short><<<4096, 256, 0, stream>>>(Xpm, ln1w, ln1b, N1);
  k_poolfb<<<4, 256, 0, stream>>>(pm, poolw, bn2g, bn2b, trw, pb);

  for (int i = 0; i < 3; ++i){
    k_gemm<0><<<dim3(6, 256), 256, 0, stream>>>(N1, qkvb[i], 256, 768, 256, E,
                                                nullptr, nullptr, nullptr, nullptr, 0);
    k_attn<<<512, 256, 0, stream>>>(E, F, i + 1);
    k_gemm<1><<<dim3(2, 256), 256, 0, stream>>>(F, projbw[i], 256, 256, 256, CAT,
                                                projb[i], nullptr, nullptr, Xpm32,
                                                (i + 1) * 256);
  }
  k_gemm<2><<<dim3(2, 256), 256, 0, stream>>>(Xpm, tcwb, 256, 256, 256, CAT,
                                              tcb, bn1g, bn1b, nullptr, 0);
  k_gemm<3><<<dim3(2, 256), 256, 0, stream>>>(CAT, trwb, 1024, 256, 1280, TR,
                                              trb, bn3g, bn3b, pb, 0);
  k_ln<float><<<4096, 256, 0, stream>>>(TR, ln2w, ln2b, N1);   // N2 reuses N1
  k_gemm<4><<<dim3(8, 256), 256, 0, stream>>>(N1, c1wb, 256, 1024, 256, E,
                                              c1b, mbn1g, mbn1b, nullptr, 0);
  k_dwconv<<<8192, 256, 0, stream>>>(E, dwwT, dwb, mbn2g, mbn2b, F);
  k_gemm<5><<<dim3(2, 256), 256, 0, stream>>>(F, c2wb, 1024, 256, 1024, d_out,
                                              c2b, mbn3g, mbn3b, TR, 0);
}

// Round 9
// 425.335 us; speedup vs baseline: 1.9030x; 1.0081x over previous
//
#include <hip/hip_runtime.h>

#define N_PIX 16384
#define CDIM  256
#define HIDD  1024
#define BNS   0.9999950000374997f   // (1+1e-5)^-0.5

typedef __attribute__((ext_vector_type(8))) short  short8;
typedef __attribute__((ext_vector_type(4))) float  f32x4;
typedef __attribute__((ext_vector_type(4))) int    int4v;
typedef __attribute__((ext_vector_type(2))) int    int2v;

__device__ __forceinline__ float b2f(unsigned short u){
  unsigned int x = ((unsigned int)u) << 16; float f;
  __builtin_memcpy(&f, &x, 4); return f;
}
__device__ __forceinline__ unsigned short f2b(float f){
  unsigned int x; __builtin_memcpy(&x, &f, 4);
  unsigned int r = (x + 0x7fffu + ((x >> 16) & 1u)) >> 16;
  return (unsigned short)r;
}
__device__ __forceinline__ float geluf(float x){
  return 0.5f * x * (1.0f + erff(x * 0.70710678118654752f));
}

// async global->LDS DMA, 16B per lane, wave-uniform LDS base + lane*16
typedef const __attribute__((address_space(1))) unsigned int* gas_t;
typedef __attribute__((address_space(3))) unsigned int*       las_t;
__device__ __forceinline__ void gload16(const void* g, void* l){
  __builtin_amdgcn_global_load_lds((gas_t)g, (las_t)l, 16, 0, 0);
}

// ---------------- fused fp32 -> bf16 weight conversion (10 segments) ----------
__global__ __launch_bounds__(256) void k_cvt_all(
    const float* __restrict__ s0, const float* __restrict__ s1, const float* __restrict__ s2,
    const float* __restrict__ s3, const float* __restrict__ s4, const float* __restrict__ s5,
    const float* __restrict__ s6, const float* __restrict__ s7, const float* __restrict__ s8,
    const float* __restrict__ s9, unsigned short* __restrict__ wb){
  const float* srcs[10] = {s0,s1,s2,s3,s4,s5,s6,s7,s8,s9};
  const int n[10]   = {196608,196608,196608,65536,65536,65536,65536,327680,262144,262144};
  const int off[10] = {0,196608,393216,589824,655360,720896,786432,851968,1179648,1441792};
  int seg = blockIdx.y;
  int i = (blockIdx.x * 256 + threadIdx.x) * 8;
  if (i >= n[seg]) return;
  const float* src = srcs[seg];
  unsigned short* dst = wb + off[seg];
  f32x4 a = *(const f32x4*)(src + i);
  f32x4 b = *(const f32x4*)(src + i + 4);
  unsigned short o[8];
  #pragma unroll
  for (int j = 0; j < 4; ++j){ o[j] = f2b(a[j]); o[4 + j] = f2b(b[j]); }
  *(int4v*)(dst + i) = *(int4v*)o;
}

// ------ dw weights: [1024,1,3,3] f32 -> [9][1024] bf16 ; also zero pm ---------
__global__ __launch_bounds__(256) void k_dwwT(const float* __restrict__ dww,
                                              unsigned short* __restrict__ dwwT,
                                              float* __restrict__ pm){
  int i = blockIdx.x * 256 + threadIdx.x;     // 0..9215
  if (i < 1024) pm[i] = 0.0f;                 // zero pool accumulator (pre-transpose)
  if (i >= 9216) return;
  int kk = i >> 10, c = i & 1023;
  dwwT[i] = f2b(dww[c * 9 + kk]);
}

// transpose: x [B,C,4096] f32 -> Xpm [N,256] bf16 + Xpm32 [N,256] f32
// + accumulates per-(b,c) pixel sums into pm via atomics (pool path)
__global__ __launch_bounds__(256) void k_transpose(const float* __restrict__ x,
                                                   unsigned short* __restrict__ xpm,
                                                   float* __restrict__ xpm32,
                                                   float* __restrict__ pm){
  __shared__ __align__(16) float tile[64][65];
  int b = blockIdx.z, c0 = blockIdx.y * 64, p0 = blockIdx.x * 64;
  int t = threadIdx.x;
  int r = t >> 3, k = t & 7;
  float psum[2];
  for (int s = 0; s < 2; ++s){
    int rr = r + s * 32;
    const float* src = x + (((size_t)(b * CDIM + c0 + rr)) << 12) + p0 + k * 8;
    f32x4 a = *(const f32x4*)src;
    f32x4 c = *(const f32x4*)(src + 4);
    psum[s] = a[0] + a[1] + a[2] + a[3] + c[0] + c[1] + c[2] + c[3];
    #pragma unroll
    for (int j = 0; j < 4; ++j){ tile[rr][k * 8 + j] = a[j]; tile[rr][k * 8 + 4 + j] = c[j]; }
  }
  #pragma unroll
  for (int s = 0; s < 2; ++s){
    float v = psum[s];
    v += __shfl_xor(v, 1); v += __shfl_xor(v, 2); v += __shfl_xor(v, 4);
    if ((t & 7) == 0) atomicAdd(&pm[b * 256 + c0 + r + s * 32], v);
  }
  __syncthreads();
  for (int s = 0; s < 2; ++s){
    int pr = r + s * 32;
    float tf[8];
    unsigned short tb[8];
    #pragma unroll
    for (int j = 0; j < 8; ++j){ tf[j] = tile[k * 8 + j][pr]; tb[j] = f2b(tf[j]); }
    size_t rowoff = ((size_t)(b * 4096 + p0 + pr)) << 8;
    *(int4v*)(xpm + rowoff + c0 + k * 8) = *(int4v*)tb;
    *(f32x4*)(xpm32 + rowoff + c0 + k * 8)     = *(f32x4*)&tf[0];
    *(f32x4*)(xpm32 + rowoff + c0 + k * 8 + 4) = *(f32x4*)&tf[4];
  }
}

// ---------------- LayerNorm over C=256 (one row per wave) ----------------------
template<typename IT>
__global__ __launch_bounds__(256) void k_ln(const IT* __restrict__ in,
    const float* __restrict__ w, const float* __restrict__ bia,
    unsigned short* __restrict__ out){
  int row  = blockIdx.x * 4 + (threadIdx.x >> 6);
  int lane = threadIdx.x & 63;
  float v[4];
  const IT* p = in + (size_t)row * CDIM + lane * 4;
  if constexpr (sizeof(IT) == 2){
    int2v d = *(const int2v*)p;
    unsigned short tmp[4]; __builtin_memcpy(tmp, &d, 8);
    #pragma unroll
    for (int j = 0; j < 4; ++j) v[j] = b2f(tmp[j]);
  } else {
    f32x4 d = *(const f32x4*)p;
    #pragma unroll
    for (int j = 0; j < 4; ++j) v[j] = d[j];
  }
  float s  = v[0] + v[1] + v[2] + v[3];
  float s2 = v[0]*v[0] + v[1]*v[1] + v[2]*v[2] + v[3]*v[3];
  #pragma unroll
  for (int m = 1; m < 64; m <<= 1){
    s  += __shfl_xor(s,  m);
    s2 += __shfl_xor(s2, m);
  }
  float mu   = s * (1.0f / 256.0f);
  float var  = s2 * (1.0f / 256.0f) - mu * mu;
  float rstd = rsqrtf(var + 1e-5f);
  unsigned short o[4];
  #pragma unroll
  for (int j = 0; j < 4; ++j){
    int c = lane * 4 + j;
    o[j] = f2b((v[j] - mu) * rstd * w[c] + bia[c]);
  }
  *(int2v*)(out + (size_t)row * CDIM + lane * 4) = *(int2v*)o;
}

// ---------------- MFMA GEMM: C[M,Nout] = A[M,K] * Bw[Nout,ldb]^T + epilogue ----
// 64x128 tile, 4 waves, each wave 32x64; double-buffered global_load_lds staging.
template<int MODE>
__global__ __launch_bounds__(256) void k_gemm(
    const unsigned short* __restrict__ A, const unsigned short* __restrict__ Bw,
    int K, int Nout, int ldb, void* __restrict__ outp,
    const float* __restrict__ bias,
    const float* __restrict__ bng,
    const float* __restrict__ bnb,
    const float* __restrict__ auxf,   // MODE3: pool_bias; MODE5: TR f32
    int catoff)
{
  __shared__ __align__(16) unsigned short As[2][64 * 32];    // 2 x 4KB
  __shared__ __align__(16) unsigned short Bs[2][128 * 32];   // 2 x 8KB
  int t = threadIdx.x;
  int m0 = blockIdx.y * 64, n0 = blockIdx.x * 128;
  int lane = t & 63;
  int w  = __builtin_amdgcn_readfirstlane(t >> 6);   // wave id (uniform)
  int wm = w >> 1, wn = w & 1;
  int lr = lane & 15, kb = lane >> 4;

  f32x4 acc[2][4];
  f32x4 z = {0.f, 0.f, 0.f, 0.f};
  #pragma unroll
  for (int i = 0; i < 2; ++i)
    #pragma unroll
    for (int j = 0; j < 4; ++j) acc[i][j] = z;

  int srow = lane >> 2, schunk = (lane & 3) * 8;
  const unsigned short* gA  = A  + (size_t)(m0 + w * 16 + srow) * K   + schunk;
  const unsigned short* gB0 = Bw + (size_t)(n0 + w * 16 + srow) * ldb + schunk;
  const unsigned short* gB1 = Bw + (size_t)(n0 + 64 + w * 16 + srow) * ldb + schunk;

  const int nt = K >> 5;
  gload16(gA,  As[0] + w * 512);
  gload16(gB0, Bs[0] + w * 512);
  gload16(gB1, Bs[0] + 2048 + w * 512);
  __syncthreads();

  for (int tt = 0; tt < nt; ++tt){
    int cur = tt & 1;
    if (tt + 1 < nt){
      int k1 = (tt + 1) << 5;
      gload16(gA  + k1, As[cur ^ 1] + w * 512);
      gload16(gB0 + k1, Bs[cur ^ 1] + w * 512);
      gload16(gB1 + k1, Bs[cur ^ 1] + 2048 + w * 512);
    }
    short8 af[2], bf_[4];
    #pragma unroll
    for (int i = 0; i < 2; ++i)
      af [i] = *(const short8*)&As[cur][(wm * 32 + i * 16 + lr) * 32 + kb * 8];
    #pragma unroll
    for (int j = 0; j < 4; ++j)
      bf_[j] = *(const short8*)&Bs[cur][(wn * 64 + j * 16 + lr) * 32 + kb * 8];
    #pragma unroll
    for (int i = 0; i < 2; ++i)
      #pragma unroll
      for (int j = 0; j < 4; ++j)
        acc[i][j] = __builtin_amdgcn_mfma_f32_16x16x32_bf16(af[i], bf_[j], acc[i][j], 0, 0, 0);
    __syncthreads();
  }

  #pragma unroll
  for (int i = 0; i < 2; ++i){
    int rowb = m0 + wm * 32 + i * 16 + kb * 4;
    #pragma unroll
    for (int j = 0; j < 4; ++j){
      int col = n0 + wn * 64 + j * 16 + lr;
      #pragma unroll
      for (int rr = 0; rr < 4; ++rr){
        int row = rowb + rr;
        float v = acc[i][j][rr];
        if constexpr (MODE == 0){            // QKV fused: plain bf16 store [N,2304]
          ((unsigned short*)outp)[(size_t)row * Nout + col] = f2b(v);
        } else if constexpr (MODE == 3){     // tc_trans: + bias + pool_bias, bn3, relu -> TR f32
          v += bias[col] + auxf[((row >> 12) << 8) + col];
          v = v * (bng[col] * BNS) + bnb[col];
          v = fmaxf(v, 0.0f);
          ((float*)outp)[(size_t)row * CDIM + col] = v;
        } else if constexpr (MODE == 4){     // mlp_c1: bias, gelu, bn1 -> H bf16
          v = geluf(v + bias[col]);
          v = v * (bng[col] * BNS) + bnb[col];
          ((unsigned short*)outp)[(size_t)row * HIDD + col] = f2b(v);
        } else {                             // MODE 5: mlp_c2: bias, bn3, +TR, store NCHW f32
          v = (v + bias[col]) * (bng[col] * BNS) + bnb[col];
          v += auxf[(size_t)row * CDIM + col];
          int b = row >> 12, hw = row & 4095;
          ((float*)outp)[(((size_t)(b * CDIM + col)) << 12) + hw] = v;
        }
      }
    }
  }
}

// -------- grouped GEMM: groups 0-2 = proj_i (bias+residual->CAT), 3 = tc_conv --
struct GrpArgs {
  const unsigned short* A[4];
  const unsigned short* B[4];
  const float* bias[4];
  int lda[4];
  int catoff[4];
};

__global__ __launch_bounds__(256) void k_gemm_grp(GrpArgs ga,
    const float* __restrict__ xpm32, const float* __restrict__ bng,
    const float* __restrict__ bnb, unsigned short* __restrict__ CAT)
{
  __shared__ __align__(16) unsigned short As[2][64 * 32];
  __shared__ __align__(16) unsigned short Bs[2][128 * 32];
  int t = threadIdx.x;
  int g  = blockIdx.x >> 1;               // group 0..3 (uniform)
  int n0 = (blockIdx.x & 1) * 128;        // column tile within group's 256
  int m0 = blockIdx.y * 64;
  const unsigned short* A  = ga.A[g];
  const unsigned short* Bw = ga.B[g];
  const float* bias = ga.bias[g];
  int lda = ga.lda[g];
  int catoff = ga.catoff[g];

  int lane = t & 63;
  int w  = __builtin_amdgcn_readfirstlane(t >> 6);
  int wm = w >> 1, wn = w & 1;
  int lr = lane & 15, kb = lane >> 4;

  f32x4 acc[2][4];
  f32x4 z = {0.f, 0.f, 0.f, 0.f};
  #pragma unroll
  for (int i = 0; i < 2; ++i)
    #pragma unroll
    for (int j = 0; j < 4; ++j) acc[i][j] = z;

  int srow = lane >> 2, schunk = (lane & 3) * 8;
  const unsigned short* gA  = A  + (size_t)(m0 + w * 16 + srow) * lda + schunk;
  const unsigned short* gB0 = Bw + (size_t)(n0 + w * 16 + srow) * 256 + schunk;
  const unsigned short* gB1 = Bw + (size_t)(n0 + 64 + w * 16 + srow) * 256 + schunk;

  gload16(gA,  As[0] + w * 512);
  gload16(gB0, Bs[0] + w * 512);
  gload16(gB1, Bs[0] + 2048 + w * 512);
  __syncthreads();

  for (int tt = 0; tt < 8; ++tt){         // K = 256
    int cur = tt & 1;
    if (tt + 1 < 8){
      int k1 = (tt + 1) << 5;
      gload16(gA  + k1, As[cur ^ 1] + w * 512);
      gload16(gB0 + k1, Bs[cur ^ 1] + w * 512);
      gload16(gB1 + k1, Bs[cur ^ 1] + 2048 + w * 512);
    }
    short8 af[2], bf_[4];
    #pragma unroll
    for (int i = 0; i < 2; ++i)
      af [i] = *(const short8*)&As[cur][(wm * 32 + i * 16 + lr) * 32 + kb * 8];
    #pragma unroll
    for (int j = 0; j < 4; ++j)
      bf_[j] = *(const short8*)&Bs[cur][(wn * 64 + j * 16 + lr) * 32 + kb * 8];
    #pragma unroll
    for (int i = 0; i < 2; ++i)
      #pragma unroll
      for (int j = 0; j < 4; ++j)
        acc[i][j] = __builtin_amdgcn_mfma_f32_16x16x32_bf16(af[i], bf_[j], acc[i][j], 0, 0, 0);
    __syncthreads();
  }

  #pragma unroll
  for (int i = 0; i < 2; ++i){
    int rowb = m0 + wm * 32 + i * 16 + kb * 4;
    #pragma unroll
    for (int j = 0; j < 4; ++j){
      int col = n0 + wn * 64 + j * 16 + lr;
      #pragma unroll
      for (int rr = 0; rr < 4; ++rr){
        int row = rowb + rr;
        float v = acc[i][j][rr];
        if (g == 3){                         // tc_conv: bias, bn1, relu
          v = (v + bias[col]) * (bng[col] * BNS) + bnb[col];
          v = fmaxf(v, 0.0f);
        } else {                             // proj: bias + residual(Xpm32)
          v += bias[col] + xpm32[(size_t)row * CDIM + col];
        }
        CAT[(size_t)row * HIDD + catoff + col] = f2b(v);
      }
    }
  }
}

// -------- atrous attention, all 3 branches in one launch (group = bid>>9) ------
__global__ __launch_bounds__(256) void k_attn3(const unsigned short* __restrict__ QKV3,
                                               unsigned short* __restrict__ F3){
  int grp = blockIdx.x >> 9;                  // 0..2, r = grp+1
  int r = grp + 1;
  int t = (blockIdx.x & 511) * 256 + threadIdx.x;   // 0 .. 131071
  int head = t & 7, pix = t >> 3;
  int hw = pix & 4095, h = hw >> 6, w = hw & 63;
  const unsigned short* base = QKV3 + (size_t)pix * 2304 + grp * 768 + head * 32;

  float q[32];
  #pragma unroll
  for (int c8 = 0; c8 < 4; ++c8){
    int4v d = *(const int4v*)(base + c8 * 8);
    unsigned short tmp[8]; __builtin_memcpy(tmp, &d, 16);
    #pragma unroll
    for (int j = 0; j < 8; ++j) q[c8 * 8 + j] = b2f(tmp[j]);
  }
  float logit[9];
  #pragma unroll
  for (int jj = 0; jj < 9; ++jj){
    int dh = (jj / 3 - 1) * r, dw = (jj % 3 - 1) * r;
    int hh = h + dh, ww = w + dw;
    float d = 0.0f;
    if (hh >= 0 && hh < 64 && ww >= 0 && ww < 64){
      const unsigned short* kr = base + (dh * 64 + dw) * 2304 + 256;
      #pragma unroll
      for (int c8 = 0; c8 < 4; ++c8){
        int4v dd = *(const int4v*)(kr + c8 * 8);
        unsigned short tmp[8]; __builtin_memcpy(tmp, &dd, 16);
        #pragma unroll
        for (int j = 0; j < 8; ++j) d += q[c8 * 8 + j] * b2f(tmp[j]);
      }
    }
    logit[jj] = d * 0.17677669529663687f;   // hd^-0.5, OOB taps keep logit 0 (zero-pad)
  }
  float m = logit[0];
  #pragma unroll
  for (int jj = 1; jj < 9; ++jj) m = fmaxf(m, logit[jj]);
  float p[9], s = 0.0f;
  #pragma unroll
  for (int jj = 0; jj < 9; ++jj){ p[jj] = __expf(logit[jj] - m); s += p[jj]; }
  float inv = 1.0f / s;
  float o[32];
  #pragma unroll
  for (int j = 0; j < 32; ++j) o[j] = 0.0f;
  #pragma unroll
  for (int jj = 0; jj < 9; ++jj){
    int dh = (jj / 3 - 1) * r, dw = (jj % 3 - 1) * r;
    int hh = h + dh, ww = w + dw;
    if (hh >= 0 && hh < 64 && ww >= 0 && ww < 64){
      float pj = p[jj] * inv;
      const unsigned short* vr = base + (dh * 64 + dw) * 2304 + 512;
      #pragma unroll
      for (int c8 = 0; c8 < 4; ++c8){
        int4v dd = *(const int4v*)(vr + c8 * 8);
        unsigned short tmp[8]; __builtin_memcpy(tmp, &dd, 16);
        #pragma unroll
        for (int j = 0; j < 8; ++j) o[c8 * 8 + j] += pj * b2f(tmp[j]);
      }
    }
  }
  unsigned short ob[32];
  #pragma unroll
  for (int j = 0; j < 32; ++j) ob[j] = f2b(o[j]);
  unsigned short* op = F3 + (size_t)pix * 768 + grp * 256 + head * 32;
  #pragma unroll
  for (int c8 = 0; c8 < 4; ++c8) *(int4v*)(op + c8 * 8) = *(int4v*)&ob[c8 * 8];
}

// ---------------- depthwise 3x3 + gelu + bn2 -----------------------------------
__global__ __launch_bounds__(256) void k_dwconv(const unsigned short* __restrict__ H,
    const unsigned short* __restrict__ dwwT, const float* __restrict__ dwb,
    const float* __restrict__ g, const float* __restrict__ bb,
    unsigned short* __restrict__ H2){
  int t = blockIdx.x * 256 + threadIdx.x;   // 16384 * 128
  int chunk = t & 127, pix = t >> 7;
  int hw = pix & 4095, h = hw >> 6, w = hw & 63;
  int c0 = chunk * 8;
  float acc[8], hc[8];
  {
    int4v dd = *(const int4v*)(H + (size_t)pix * HIDD + c0);
    unsigned short tmp[8]; __builtin_memcpy(tmp, &dd, 16);
    #pragma unroll
    for (int j = 0; j < 8; ++j){ hc[j] = b2f(tmp[j]); acc[j] = 0.0f; }
  }
  #pragma unroll
  for (int di = -1; di <= 1; ++di)
    #pragma unroll
    for (int dj = -1; dj <= 1; ++dj){
      int hh = h + di, ww = w + dj;
      if (hh < 0 || hh >= 64 || ww < 0 || ww >= 64) continue;
      int kk = (di + 1) * 3 + (dj + 1);
      int4v dd = *(const int4v*)(H + ((size_t)(pix + di * 64 + dj)) * HIDD + c0);
      int4v wv = *(const int4v*)(dwwT + kk * 1024 + c0);
      unsigned short tmp[8], wt[8];
      __builtin_memcpy(tmp, &dd, 16);
      __builtin_memcpy(wt,  &wv, 16);
      #pragma unroll
      for (int j = 0; j < 8; ++j) acc[j] += b2f(wt[j]) * b2f(tmp[j]);
    }
  f32x4 bv0 = *(const f32x4*)(dwb + c0), bv1 = *(const f32x4*)(dwb + c0 + 4);
  f32x4 gv0 = *(const f32x4*)(g   + c0), gv1 = *(const f32x4*)(g   + c0 + 4);
  f32x4 cv0 = *(const f32x4*)(bb  + c0), cv1 = *(const f32x4*)(bb  + c0 + 4);
  float bvv[8], gvv[8], cvv[8];
  #pragma unroll
  for (int j = 0; j < 4; ++j){
    bvv[j] = bv0[j]; bvv[4 + j] = bv1[j];
    gvv[j] = gv0[j]; gvv[4 + j] = gv1[j];
    cvv[j] = cv0[j]; cvv[4 + j] = cv1[j];
  }
  unsigned short ob[8];
  #pragma unroll
  for (int j = 0; j < 8; ++j){
    float v = acc[j] + bvv[j] + hc[j];
    v = geluf(v);
    v = v * (gvv[j] * BNS) + cvv[j];
    ob[j] = f2b(v);
  }
  *(int4v*)(H2 + (size_t)pix * HIDD + c0) = *(int4v*)ob;
}

// fused pool tail: pf = relu(bn(poolw @ mean)); pb = trw[:,1024:1280] @ pf
__global__ __launch_bounds__(256) void k_poolfb(const float* __restrict__ pm,
    const float* __restrict__ pw, const float* __restrict__ g,
    const float* __restrict__ bb, const float* __restrict__ tw,
    float* __restrict__ pb){
  int b = blockIdx.x, o = threadIdx.x;
  __shared__ float v[256];
  __shared__ float pfs[256];
  v[o] = pm[b * 256 + o] * (1.0f / 4096.0f);
  __syncthreads();
  float acc = 0.0f;
  const float* wr = pw + (size_t)o * 256;
  for (int c = 0; c < 256; ++c) acc += v[c] * wr[c];
  float val = acc * (g[o] * BNS) + bb[o];
  pfs[o] = fmaxf(val, 0.0f);
  __syncthreads();
  float acc2 = 0.0f;
  const float* tr = tw + (size_t)o * 1280 + 1024;
  for (int c = 0; c < 256; ++c) acc2 += pfs[c] * tr[c];
  pb[b * 256 + o] = acc2;
}

// ---------------- launch -------------------------------------------------------
extern "C" void kernel_launch(void* const* d_in, const int* in_sizes, int n_in,
                              void* d_out, int out_size, void* d_ws, size_t ws_size,
                              hipStream_t stream){
  const float* x     = (const float*)d_in[0];
  const float* ln1w  = (const float*)d_in[1];
  const float* ln1b  = (const float*)d_in[2];
  const float* ln2w  = (const float*)d_in[3];
  const float* ln2b  = (const float*)d_in[4];
  const float* qkvw[3]  = {(const float*)d_in[5], (const float*)d_in[8],  (const float*)d_in[11]};
  const float* projw[3] = {(const float*)d_in[6], (const float*)d_in[9],  (const float*)d_in[12]};
  const float* projb[3] = {(const float*)d_in[7], (const float*)d_in[10], (const float*)d_in[13]};
  const float* tcw   = (const float*)d_in[14];
  const float* tcb   = (const float*)d_in[15];
  const float* bn1g  = (const float*)d_in[16];
  const float* bn1b  = (const float*)d_in[17];
  const float* poolw = (const float*)d_in[18];
  const float* bn2g  = (const float*)d_in[19];
  const float* bn2b  = (const float*)d_in[20];
  const float* trw   = (const float*)d_in[21];
  const float* trb   = (const float*)d_in[22];
  const float* bn3g  = (const float*)d_in[23];
  const float* bn3b  = (const float*)d_in[24];
  const float* c1w   = (const float*)d_in[25];
  const float* c1b   = (const float*)d_in[26];
  const float* mbn1g = (const float*)d_in[27];
  const float* mbn1b = (const float*)d_in[28];
  const float* dww   = (const float*)d_in[29];
  const float* dwb   = (const float*)d_in[30];
  const float* mbn2g = (const float*)d_in[31];
  const float* mbn2b = (const float*)d_in[32];
  const float* c2w   = (const float*)d_in[33];
  const float* c2b   = (const float*)d_in[34];
  const float* mbn3g = (const float*)d_in[35];
  const float* mbn3b = (const float*)d_in[36];

  char* ws = (char*)d_ws;
  unsigned short* Xpm = (unsigned short*)(ws);                 //  8.4 MB [N,256] bf16
  unsigned short* N1  = (unsigned short*)(ws + 8388608);       //  8.4 MB [N,256] (later N2)
  unsigned short* CAT = (unsigned short*)(ws + 16777216);      // 33.6 MB [N,1024]
  float*          TR  = (float*)        (ws + 50331648);       // 16.8 MB: Xpm32 early, TR late
  float*          Xpm32 = TR;                                  // alias — disjoint live ranges
  unsigned short* H   = (unsigned short*)(ws + 67108864);      // 33.6 MB mlp hidden
  unsigned short* H2  = (unsigned short*)(ws + 100663296);     // 33.6 MB mlp hidden 2
  unsigned short* Wb  = (unsigned short*)(ws + 134217728);     // bf16 weights, contiguous
  unsigned short* projbw[3] = {Wb + 589824, Wb + 655360, Wb + 720896};
  unsigned short* tcwb  = Wb + 786432;
  unsigned short* trwb  = Wb + 851968;
  unsigned short* c1wb  = Wb + 1179648;
  unsigned short* c2wb  = Wb + 1441792;
  unsigned short* dwwT  = Wb + 1703936;
  float*          pm  = (float*)(ws + 134217728 + 3428352);    // 1024 f32 pool sums
  float*          pb  = pm + 1024;                             // 1024 f32 pool bias
  unsigned short* E3  = (unsigned short*)(ws + 140509184);     // 75.5 MB [N,2304] qkv x3
  unsigned short* F3  = (unsigned short*)(ws + 216006656);     // 25.2 MB [N,768] att x3

  k_cvt_all<<<dim3(160, 10), 256, 0, stream>>>(qkvw[0], qkvw[1], qkvw[2],
                                               projw[0], projw[1], projw[2],
                                               tcw, trw, c1w, c2w, Wb);
  k_dwwT<<<36, 256, 0, stream>>>(dww, dwwT, pm);
  k_transpose<<<dim3(64, 4, 4), 256, 0, stream>>>(x, Xpm, Xpm32, pm);
  k_ln<unsigned short><<<4096, 256, 0, stream>>>(Xpm, ln1w, ln1b, N1);
  k_poolfb<<<4, 256, 0, stream>>>(pm, poolw, bn2g, bn2b, trw, pb);

  // fused QKV: one GEMM over concatenated weights [2304,256] -> E3 [N,2304]
  k_gemm<0><<<dim3(18, 256), 256, 0, stream>>>(N1, Wb, 256, 2304, 256, E3,
                                               nullptr, nullptr, nullptr, nullptr, 0);
  // all 3 attention branches
  k_attn3<<<1536, 256, 0, stream>>>(E3, F3);
  // grouped proj x3 + tc_conv -> CAT
  {
    GrpArgs ga;
    ga.A[0] = F3;       ga.A[1] = F3 + 256; ga.A[2] = F3 + 512; ga.A[3] = Xpm;
    ga.B[0] = projbw[0]; ga.B[1] = projbw[1]; ga.B[2] = projbw[2]; ga.B[3] = tcwb;
    ga.bias[0] = projb[0]; ga.bias[1] = projb[1]; ga.bias[2] = projb[2]; ga.bias[3] = tcb;
    ga.lda[0] = 768; ga.lda[1] = 768; ga.lda[2] = 768; ga.lda[3] = 256;
    ga.catoff[0] = 256; ga.catoff[1] = 512; ga.catoff[2] = 768; ga.catoff[3] = 0;
    k_gemm_grp<<<dim3(8, 256), 256, 0, stream>>>(ga, Xpm32, bn1g, bn1b, CAT);
  }
  k_gemm<3><<<dim3(2, 256), 256, 0, stream>>>(CAT, trwb, 1024, 256, 1280, TR,
                                              trb, bn3g, bn3b, pb, 0);
  k_ln<float><<<4096, 256, 0, stream>>>(TR, ln2w, ln2b, N1);   // N2 reuses N1
  k_gemm<4><<<dim3(8, 256), 256, 0, stream>>>(N1, c1wb, 256, 1024, 256, H,
                                              c1b, mbn1g, mbn1b, nullptr, 0);
  k_dwconv<<<8192, 256, 0, stream>>>(H, dwwT, dwb, mbn2g, mbn2b, H2);
  k_gemm<5><<<dim3(2, 256), 256, 0, stream>>>(H2, c2wb, 1024, 256, 1024, d_out,
                                              c2b, mbn3g, mbn3b, TR, 0);
}

// Round 10
// 402.179 us; speedup vs baseline: 2.0126x; 1.0576x over previous
//
#include <hip/hip_runtime.h>

#define N_PIX 16384
#define CDIM  256
#define HIDD  1024
#define BNS   0.9999950000374997f   // (1+1e-5)^-0.5

typedef __attribute__((ext_vector_type(8))) short  short8;
typedef __attribute__((ext_vector_type(4))) float  f32x4;
typedef __attribute__((ext_vector_type(4))) int    int4v;
typedef __attribute__((ext_vector_type(2))) int    int2v;

__device__ __forceinline__ float b2f(unsigned short u){
  unsigned int x = ((unsigned int)u) << 16; float f;
  __builtin_memcpy(&f, &x, 4); return f;
}
__device__ __forceinline__ unsigned short f2b(float f){
  unsigned int x; __builtin_memcpy(&x, &f, 4);
  unsigned int r = (x + 0x7fffu + ((x >> 16) & 1u)) >> 16;
  return (unsigned short)r;
}
__device__ __forceinline__ float geluf(float x){
  return 0.5f * x * (1.0f + erff(x * 0.70710678118654752f));
}

// async global->LDS DMA, 16B per lane, wave-uniform LDS base + lane*16
typedef const __attribute__((address_space(1))) unsigned int* gas_t;
typedef __attribute__((address_space(3))) unsigned int*       las_t;
__device__ __forceinline__ void gload16(const void* g, void* l){
  __builtin_amdgcn_global_load_lds((gas_t)g, (las_t)l, 16, 0, 0);
}

// ---------------- fused fp32 -> bf16 weight conversion (10 segments) ----------
__global__ __launch_bounds__(256) void k_cvt_all(
    const float* __restrict__ s0, const float* __restrict__ s1, const float* __restrict__ s2,
    const float* __restrict__ s3, const float* __restrict__ s4, const float* __restrict__ s5,
    const float* __restrict__ s6, const float* __restrict__ s7, const float* __restrict__ s8,
    const float* __restrict__ s9, unsigned short* __restrict__ wb){
  const float* srcs[10] = {s0,s1,s2,s3,s4,s5,s6,s7,s8,s9};
  const int n[10]   = {196608,196608,196608,65536,65536,65536,65536,327680,262144,262144};
  const int off[10] = {0,196608,393216,589824,655360,720896,786432,851968,1179648,1441792};
  int seg = blockIdx.y;
  int i = (blockIdx.x * 256 + threadIdx.x) * 8;
  if (i >= n[seg]) return;
  const float* src = srcs[seg];
  unsigned short* dst = wb + off[seg];
  f32x4 a = *(const f32x4*)(src + i);
  f32x4 b = *(const f32x4*)(src + i + 4);
  unsigned short o[8];
  #pragma unroll
  for (int j = 0; j < 4; ++j){ o[j] = f2b(a[j]); o[4 + j] = f2b(b[j]); }
  *(int4v*)(dst + i) = *(int4v*)o;
}

// ------ dw weights: [1024,1,3,3] f32 -> [9][1024] bf16 ; also zero pm ---------
__global__ __launch_bounds__(256) void k_dwwT(const float* __restrict__ dww,
                                              unsigned short* __restrict__ dwwT,
                                              float* __restrict__ pm){
  int i = blockIdx.x * 256 + threadIdx.x;     // 0..9215
  if (i < 1024) pm[i] = 0.0f;                 // zero pool accumulator (pre-transpose)
  if (i >= 9216) return;
  int kk = i >> 10, c = i & 1023;
  dwwT[i] = f2b(dww[c * 9 + kk]);
}

// transpose: x [B,C,4096] f32 -> Xpm [N,256] bf16 + Xpm32 [N,256] f32
// + accumulates per-(b,c) pixel sums into pm via atomics (pool path)
__global__ __launch_bounds__(256) void k_transpose(const float* __restrict__ x,
                                                   unsigned short* __restrict__ xpm,
                                                   float* __restrict__ xpm32,
                                                   float* __restrict__ pm){
  __shared__ __align__(16) float tile[64][65];
  int b = blockIdx.z, c0 = blockIdx.y * 64, p0 = blockIdx.x * 64;
  int t = threadIdx.x;
  int r = t >> 3, k = t & 7;
  float psum[2];
  for (int s = 0; s < 2; ++s){
    int rr = r + s * 32;
    const float* src = x + (((size_t)(b * CDIM + c0 + rr)) << 12) + p0 + k * 8;
    f32x4 a = *(const f32x4*)src;
    f32x4 c = *(const f32x4*)(src + 4);
    psum[s] = a[0] + a[1] + a[2] + a[3] + c[0] + c[1] + c[2] + c[3];
    #pragma unroll
    for (int j = 0; j < 4; ++j){ tile[rr][k * 8 + j] = a[j]; tile[rr][k * 8 + 4 + j] = c[j]; }
  }
  #pragma unroll
  for (int s = 0; s < 2; ++s){
    float v = psum[s];
    v += __shfl_xor(v, 1); v += __shfl_xor(v, 2); v += __shfl_xor(v, 4);
    if ((t & 7) == 0) atomicAdd(&pm[b * 256 + c0 + r + s * 32], v);
  }
  __syncthreads();
  for (int s = 0; s < 2; ++s){
    int pr = r + s * 32;
    float tf[8];
    unsigned short tb[8];
    #pragma unroll
    for (int j = 0; j < 8; ++j){ tf[j] = tile[k * 8 + j][pr]; tb[j] = f2b(tf[j]); }
    size_t rowoff = ((size_t)(b * 4096 + p0 + pr)) << 8;
    *(int4v*)(xpm + rowoff + c0 + k * 8) = *(int4v*)tb;
    *(f32x4*)(xpm32 + rowoff + c0 + k * 8)     = *(f32x4*)&tf[0];
    *(f32x4*)(xpm32 + rowoff + c0 + k * 8 + 4) = *(f32x4*)&tf[4];
  }
}

// ---------------- LayerNorm over C=256 (one row per wave) ----------------------
template<typename IT>
__global__ __launch_bounds__(256) void k_ln(const IT* __restrict__ in,
    const float* __restrict__ w, const float* __restrict__ bia,
    unsigned short* __restrict__ out){
  int row  = blockIdx.x * 4 + (threadIdx.x >> 6);
  int lane = threadIdx.x & 63;
  float v[4];
  const IT* p = in + (size_t)row * CDIM + lane * 4;
  if constexpr (sizeof(IT) == 2){
    int2v d = *(const int2v*)p;
    unsigned short tmp[4]; __builtin_memcpy(tmp, &d, 8);
    #pragma unroll
    for (int j = 0; j < 4; ++j) v[j] = b2f(tmp[j]);
  } else {
    f32x4 d = *(const f32x4*)p;
    #pragma unroll
    for (int j = 0; j < 4; ++j) v[j] = d[j];
  }
  float s  = v[0] + v[1] + v[2] + v[3];
  float s2 = v[0]*v[0] + v[1]*v[1] + v[2]*v[2] + v[3]*v[3];
  #pragma unroll
  for (int m = 1; m < 64; m <<= 1){
    s  += __shfl_xor(s,  m);
    s2 += __shfl_xor(s2, m);
  }
  float mu   = s * (1.0f / 256.0f);
  float var  = s2 * (1.0f / 256.0f) - mu * mu;
  float rstd = rsqrtf(var + 1e-5f);
  unsigned short o[4];
  #pragma unroll
  for (int j = 0; j < 4; ++j){
    int c = lane * 4 + j;
    o[j] = f2b((v[j] - mu) * rstd * w[c] + bia[c]);
  }
  *(int2v*)(out + (size_t)row * CDIM + lane * 4) = *(int2v*)o;
}

// ---------------- MFMA GEMM: C[M,Nout] = A[M,K] * Bw[Nout,ldb]^T + epilogue ----
// BMx128 tile (BM=64 or 32), 4 waves; double-buffered global_load_lds staging.
// BM=32 halves A-panel per block -> 2x grid -> 4 blocks/CU (same HBM traffic).
template<int MODE, int BM>
__global__ __launch_bounds__(256) void k_gemm(
    const unsigned short* __restrict__ A, const unsigned short* __restrict__ Bw,
    int K, int Nout, int ldb, void* __restrict__ outp,
    const float* __restrict__ bias,
    const float* __restrict__ bng,
    const float* __restrict__ bnb,
    const float* __restrict__ auxf,   // MODE3: pool_bias; MODE5: TR f32
    int catoff)
{
  constexpr int NI = BM / 32;     // A fragments per wave
  __shared__ __align__(16) unsigned short As[2][BM * 32];
  __shared__ __align__(16) unsigned short Bs[2][128 * 32];
  int t = threadIdx.x;
  int m0 = blockIdx.y * BM, n0 = blockIdx.x * 128;
  int lane = t & 63;
  int w  = __builtin_amdgcn_readfirstlane(t >> 6);   // wave id (uniform)
  int wm = w >> 1, wn = w & 1;
  int lr = lane & 15, kb = lane >> 4;
  const bool doA = (w * 16 < BM);

  f32x4 acc[NI][4];
  f32x4 z = {0.f, 0.f, 0.f, 0.f};
  #pragma unroll
  for (int i = 0; i < NI; ++i)
    #pragma unroll
    for (int j = 0; j < 4; ++j) acc[i][j] = z;

  int srow = lane >> 2, schunk = (lane & 3) * 8;
  const unsigned short* gA  = A  + (size_t)(m0 + w * 16 + srow) * K   + schunk;
  const unsigned short* gB0 = Bw + (size_t)(n0 + w * 16 + srow) * ldb + schunk;
  const unsigned short* gB1 = Bw + (size_t)(n0 + 64 + w * 16 + srow) * ldb + schunk;

  const int nt = K >> 5;
  if (doA) gload16(gA, As[0] + w * 512);
  gload16(gB0, Bs[0] + w * 512);
  gload16(gB1, Bs[0] + 2048 + w * 512);
  __syncthreads();

  for (int tt = 0; tt < nt; ++tt){
    int cur = tt & 1;
    if (tt + 1 < nt){
      int k1 = (tt + 1) << 5;
      if (doA) gload16(gA + k1, As[cur ^ 1] + w * 512);
      gload16(gB0 + k1, Bs[cur ^ 1] + w * 512);
      gload16(gB1 + k1, Bs[cur ^ 1] + 2048 + w * 512);
    }
    short8 af[NI], bf_[4];
    #pragma unroll
    for (int i = 0; i < NI; ++i)
      af [i] = *(const short8*)&As[cur][(wm * (BM / 2) + i * 16 + lr) * 32 + kb * 8];
    #pragma unroll
    for (int j = 0; j < 4; ++j)
      bf_[j] = *(const short8*)&Bs[cur][(wn * 64 + j * 16 + lr) * 32 + kb * 8];
    #pragma unroll
    for (int i = 0; i < NI; ++i)
      #pragma unroll
      for (int j = 0; j < 4; ++j)
        acc[i][j] = __builtin_amdgcn_mfma_f32_16x16x32_bf16(af[i], bf_[j], acc[i][j], 0, 0, 0);
    __syncthreads();
  }

  #pragma unroll
  for (int i = 0; i < NI; ++i){
    int rowb = m0 + wm * (BM / 2) + i * 16 + kb * 4;
    #pragma unroll
    for (int j = 0; j < 4; ++j){
      int col = n0 + wn * 64 + j * 16 + lr;
      #pragma unroll
      for (int rr = 0; rr < 4; ++rr){
        int row = rowb + rr;
        float v = acc[i][j][rr];
        if constexpr (MODE == 0){            // QKV fused: plain bf16 store [N,2304]
          ((unsigned short*)outp)[(size_t)row * Nout + col] = f2b(v);
        } else if constexpr (MODE == 3){     // tc_trans: + bias + pool_bias, bn3, relu -> TR f32
          v += bias[col] + auxf[((row >> 12) << 8) + col];
          v = v * (bng[col] * BNS) + bnb[col];
          v = fmaxf(v, 0.0f);
          ((float*)outp)[(size_t)row * CDIM + col] = v;
        } else if constexpr (MODE == 4){     // mlp_c1: bias, gelu, bn1 -> H bf16
          v = geluf(v + bias[col]);
          v = v * (bng[col] * BNS) + bnb[col];
          ((unsigned short*)outp)[(size_t)row * HIDD + col] = f2b(v);
        } else {                             // MODE 5: mlp_c2: bias, bn3, +TR, store NCHW f32
          v = (v + bias[col]) * (bng[col] * BNS) + bnb[col];
          v += auxf[(size_t)row * CDIM + col];
          int b = row >> 12, hw = row & 4095;
          ((float*)outp)[(((size_t)(b * CDIM + col)) << 12) + hw] = v;
        }
      }
    }
  }
}

// -------- grouped GEMM: groups 0-2 = proj_i (bias+residual->CAT), 3 = tc_conv --
struct GrpArgs {
  const unsigned short* A[4];
  const unsigned short* B[4];
  const float* bias[4];
  int lda[4];
  int catoff[4];
};

__global__ __launch_bounds__(256) void k_gemm_grp(GrpArgs ga,
    const float* __restrict__ xpm32, const float* __restrict__ bng,
    const float* __restrict__ bnb, unsigned short* __restrict__ CAT)
{
  __shared__ __align__(16) unsigned short As[2][64 * 32];
  __shared__ __align__(16) unsigned short Bs[2][128 * 32];
  int t = threadIdx.x;
  int g  = blockIdx.x >> 1;               // group 0..3 (uniform)
  int n0 = (blockIdx.x & 1) * 128;        // column tile within group's 256
  int m0 = blockIdx.y * 64;
  const unsigned short* A  = ga.A[g];
  const unsigned short* Bw = ga.B[g];
  const float* bias = ga.bias[g];
  int lda = ga.lda[g];
  int catoff = ga.catoff[g];

  int lane = t & 63;
  int w  = __builtin_amdgcn_readfirstlane(t >> 6);
  int wm = w >> 1, wn = w & 1;
  int lr = lane & 15, kb = lane >> 4;

  f32x4 acc[2][4];
  f32x4 z = {0.f, 0.f, 0.f, 0.f};
  #pragma unroll
  for (int i = 0; i < 2; ++i)
    #pragma unroll
    for (int j = 0; j < 4; ++j) acc[i][j] = z;

  int srow = lane >> 2, schunk = (lane & 3) * 8;
  const unsigned short* gA  = A  + (size_t)(m0 + w * 16 + srow) * lda + schunk;
  const unsigned short* gB0 = Bw + (size_t)(n0 + w * 16 + srow) * 256 + schunk;
  const unsigned short* gB1 = Bw + (size_t)(n0 + 64 + w * 16 + srow) * 256 + schunk;

  gload16(gA,  As[0] + w * 512);
  gload16(gB0, Bs[0] + w * 512);
  gload16(gB1, Bs[0] + 2048 + w * 512);
  __syncthreads();

  for (int tt = 0; tt < 8; ++tt){         // K = 256
    int cur = tt & 1;
    if (tt + 1 < 8){
      int k1 = (tt + 1) << 5;
      gload16(gA  + k1, As[cur ^ 1] + w * 512);
      gload16(gB0 + k1, Bs[cur ^ 1] + w * 512);
      gload16(gB1 + k1, Bs[cur ^ 1] + 2048 + w * 512);
    }
    short8 af[2], bf_[4];
    #pragma unroll
    for (int i = 0; i < 2; ++i)
      af [i] = *(const short8*)&As[cur][(wm * 32 + i * 16 + lr) * 32 + kb * 8];
    #pragma unroll
    for (int j = 0; j < 4; ++j)
      bf_[j] = *(const short8*)&Bs[cur][(wn * 64 + j * 16 + lr) * 32 + kb * 8];
    #pragma unroll
    for (int i = 0; i < 2; ++i)
      #pragma unroll
      for (int j = 0; j < 4; ++j)
        acc[i][j] = __builtin_amdgcn_mfma_f32_16x16x32_bf16(af[i], bf_[j], acc[i][j], 0, 0, 0);
    __syncthreads();
  }

  #pragma unroll
  for (int i = 0; i < 2; ++i){
    int rowb = m0 + wm * 32 + i * 16 + kb * 4;
    #pragma unroll
    for (int j = 0; j < 4; ++j){
      int col = n0 + wn * 64 + j * 16 + lr;
      #pragma unroll
      for (int rr = 0; rr < 4; ++rr){
        int row = rowb + rr;
        float v = acc[i][j][rr];
        if (g == 3){                         // tc_conv: bias, bn1, relu
          v = (v + bias[col]) * (bng[col] * BNS) + bnb[col];
          v = fmaxf(v, 0.0f);
        } else {                             // proj: bias + residual(Xpm32)
          v += bias[col] + xpm32[(size_t)row * CDIM + col];
        }
        CAT[(size_t)row * HIDD + catoff + col] = f2b(v);
      }
    }
  }
}

// -------- atrous attention, lane-pair split: thread = (pix, head, half16) ------
// grid 3072 blocks: grp = bid>>10, r = grp+1. Lanes 2k/2k+1 share one (pix,head);
// QK dot completes via shfl_xor(1); softmax redundant per pair; V lane-local.
__global__ __launch_bounds__(256) void k_attn3(const unsigned short* __restrict__ QKV3,
                                               unsigned short* __restrict__ F3){
  int grp = blockIdx.x >> 10;                 // 0..2, r = grp+1
  int r = grp + 1;
  int t = (blockIdx.x & 1023) * 256 + threadIdx.x;  // 0 .. 262143
  int half = t & 1, head = (t >> 1) & 7, pix = t >> 4;
  int hw = pix & 4095, h = hw >> 6, w = hw & 63;
  const unsigned short* base = QKV3 + (size_t)pix * 2304 + grp * 768 + head * 32 + half * 16;

  float q[16];
  #pragma unroll
  for (int c8 = 0; c8 < 2; ++c8){
    int4v d = *(const int4v*)(base + c8 * 8);
    unsigned short tmp[8]; __builtin_memcpy(tmp, &d, 16);
    #pragma unroll
    for (int j = 0; j < 8; ++j) q[c8 * 8 + j] = b2f(tmp[j]);
  }
  float logit[9];
  #pragma unroll
  for (int jj = 0; jj < 9; ++jj){
    int dh = (jj / 3 - 1) * r, dw = (jj % 3 - 1) * r;
    int hh = h + dh, ww = w + dw;
    float d = 0.0f;
    if (hh >= 0 && hh < 64 && ww >= 0 && ww < 64){
      const unsigned short* kr = base + (dh * 64 + dw) * 2304 + 256;
      #pragma unroll
      for (int c8 = 0; c8 < 2; ++c8){
        int4v dd = *(const int4v*)(kr + c8 * 8);
        unsigned short tmp[8]; __builtin_memcpy(tmp, &dd, 16);
        #pragma unroll
        for (int j = 0; j < 8; ++j) d += q[c8 * 8 + j] * b2f(tmp[j]);
      }
    }
    d += __shfl_xor(d, 1);                  // combine the two 16-channel halves
    logit[jj] = d * 0.17677669529663687f;   // hd^-0.5; OOB taps keep logit 0 (zero-pad)
  }
  float m = logit[0];
  #pragma unroll
  for (int jj = 1; jj < 9; ++jj) m = fmaxf(m, logit[jj]);
  float p[9], s = 0.0f;
  #pragma unroll
  for (int jj = 0; jj < 9; ++jj){ p[jj] = __expf(logit[jj] - m); s += p[jj]; }
  float inv = 1.0f / s;
  float o[16];
  #pragma unroll
  for (int j = 0; j < 16; ++j) o[j] = 0.0f;
  #pragma unroll
  for (int jj = 0; jj < 9; ++jj){
    int dh = (jj / 3 - 1) * r, dw = (jj % 3 - 1) * r;
    int hh = h + dh, ww = w + dw;
    if (hh >= 0 && hh < 64 && ww >= 0 && ww < 64){
      float pj = p[jj] * inv;
      const unsigned short* vr = base + (dh * 64 + dw) * 2304 + 512;
      #pragma unroll
      for (int c8 = 0; c8 < 2; ++c8){
        int4v dd = *(const int4v*)(vr + c8 * 8);
        unsigned short tmp[8]; __builtin_memcpy(tmp, &dd, 16);
        #pragma unroll
        for (int j = 0; j < 8; ++j) o[c8 * 8 + j] += pj * b2f(tmp[j]);
      }
    }
  }
  unsigned short ob[16];
  #pragma unroll
  for (int j = 0; j < 16; ++j) ob[j] = f2b(o[j]);
  unsigned short* op = F3 + (size_t)pix * 768 + grp * 256 + head * 32 + half * 16;
  *(int4v*)(op)     = *(int4v*)&ob[0];
  *(int4v*)(op + 8) = *(int4v*)&ob[8];
}

// ---------------- depthwise 3x3 + gelu + bn2 -----------------------------------
__global__ __launch_bounds__(256) void k_dwconv(const unsigned short* __restrict__ H,
    const unsigned short* __restrict__ dwwT, const float* __restrict__ dwb,
    const float* __restrict__ g, const float* __restrict__ bb,
    unsigned short* __restrict__ H2){
  int t = blockIdx.x * 256 + threadIdx.x;   // 16384 * 128
  int chunk = t & 127, pix = t >> 7;
  int hw = pix & 4095, h = hw >> 6, w = hw & 63;
  int c0 = chunk * 8;
  float acc[8], hc[8];
  {
    int4v dd = *(const int4v*)(H + (size_t)pix * HIDD + c0);
    unsigned short tmp[8]; __builtin_memcpy(tmp, &dd, 16);
    #pragma unroll
    for (int j = 0; j < 8; ++j){ hc[j] = b2f(tmp[j]); acc[j] = 0.0f; }
  }
  #pragma unroll
  for (int di = -1; di <= 1; ++di)
    #pragma unroll
    for (int dj = -1; dj <= 1; ++dj){
      int hh = h + di, ww = w + dj;
      if (hh < 0 || hh >= 64 || ww < 0 || ww >= 64) continue;
      int kk = (di + 1) * 3 + (dj + 1);
      int4v dd = *(const int4v*)(H + ((size_t)(pix + di * 64 + dj)) * HIDD + c0);
      int4v wv = *(const int4v*)(dwwT + kk * 1024 + c0);
      unsigned short tmp[8], wt[8];
      __builtin_memcpy(tmp, &dd, 16);
      __builtin_memcpy(wt,  &wv, 16);
      #pragma unroll
      for (int j = 0; j < 8; ++j) acc[j] += b2f(wt[j]) * b2f(tmp[j]);
    }
  f32x4 bv0 = *(const f32x4*)(dwb + c0), bv1 = *(const f32x4*)(dwb + c0 + 4);
  f32x4 gv0 = *(const f32x4*)(g   + c0), gv1 = *(const f32x4*)(g   + c0 + 4);
  f32x4 cv0 = *(const f32x4*)(bb  + c0), cv1 = *(const f32x4*)(bb  + c0 + 4);
  float bvv[8], gvv[8], cvv[8];
  #pragma unroll
  for (int j = 0; j < 4; ++j){
    bvv[j] = bv0[j]; bvv[4 + j] = bv1[j];
    gvv[j] = gv0[j]; gvv[4 + j] = gv1[j];
    cvv[j] = cv0[j]; cvv[4 + j] = cv1[j];
  }
  unsigned short ob[8];
  #pragma unroll
  for (int j = 0; j < 8; ++j){
    float v = acc[j] + bvv[j] + hc[j];
    v = geluf(v);
    v = v * (gvv[j] * BNS) + cvv[j];
    ob[j] = f2b(v);
  }
  *(int4v*)(H2 + (size_t)pix * HIDD + c0) = *(int4v*)ob;
}

// fused pool tail: pf = relu(bn(poolw @ mean)); pb = trw[:,1024:1280] @ pf
__global__ __launch_bounds__(256) void k_poolfb(const float* __restrict__ pm,
    const float* __restrict__ pw, const float* __restrict__ g,
    const float* __restrict__ bb, const float* __restrict__ tw,
    float* __restrict__ pb){
  int b = blockIdx.x, o = threadIdx.x;
  __shared__ float v[256];
  __shared__ float pfs[256];
  v[o] = pm[b * 256 + o] * (1.0f / 4096.0f);
  __syncthreads();
  float acc = 0.0f;
  const float* wr = pw + (size_t)o * 256;
  for (int c = 0; c < 256; ++c) acc += v[c] * wr[c];
  float val = acc * (g[o] * BNS) + bb[o];
  pfs[o] = fmaxf(val, 0.0f);
  __syncthreads();
  float acc2 = 0.0f;
  const float* tr = tw + (size_t)o * 1280 + 1024;
  for (int c = 0; c < 256; ++c) acc2 += pfs[c] * tr[c];
  pb[b * 256 + o] = acc2;
}

// ---------------- launch -------------------------------------------------------
extern "C" void kernel_launch(void* const* d_in, const int* in_sizes, int n_in,
                              void* d_out, int out_size, void* d_ws, size_t ws_size,
                              hipStream_t stream){
  const float* x     = (const float*)d_in[0];
  const float* ln1w  = (const float*)d_in[1];
  const float* ln1b  = (const float*)d_in[2];
  const float* ln2w  = (const float*)d_in[3];
  const float* ln2b  = (const float*)d_in[4];
  const float* qkvw[3]  = {(const float*)d_in[5], (const float*)d_in[8],  (const float*)d_in[11]};
  const float* projw[3] = {(const float*)d_in[6], (const float*)d_in[9],  (const float*)d_in[12]};
  const float* projb[3] = {(const float*)d_in[7], (const float*)d_in[10], (const float*)d_in[13]};
  const float* tcw   = (const float*)d_in[14];
  const float* tcb   = (const float*)d_in[15];
  const float* bn1g  = (const float*)d_in[16];
  const float* bn1b  = (const float*)d_in[17];
  const float* poolw = (const float*)d_in[18];
  const float* bn2g  = (const float*)d_in[19];
  const float* bn2b  = (const float*)d_in[20];
  const float* trw   = (const float*)d_in[21];
  const float* trb   = (const float*)d_in[22];
  const float* bn3g  = (const float*)d_in[23];
  const float* bn3b  = (const float*)d_in[24];
  const float* c1w   = (const float*)d_in[25];
  const float* c1b   = (const float*)d_in[26];
  const float* mbn1g = (const float*)d_in[27];
  const float* mbn1b = (const float*)d_in[28];
  const float* dww   = (const float*)d_in[29];
  const float* dwb   = (const float*)d_in[30];
  const float* mbn2g = (const float*)d_in[31];
  const float* mbn2b = (const float*)d_in[32];
  const float* c2w   = (const float*)d_in[33];
  const float* c2b   = (const float*)d_in[34];
  const float* mbn3g = (const float*)d_in[35];
  const float* mbn3b = (const float*)d_in[36];

  char* ws = (char*)d_ws;
  unsigned short* Xpm = (unsigned short*)(ws);                 //  8.4 MB [N,256] bf16
  unsigned short* N1  = (unsigned short*)(ws + 8388608);       //  8.4 MB [N,256] (later N2)
  unsigned short* CAT = (unsigned short*)(ws + 16777216);      // 33.6 MB [N,1024]
  float*          TR  = (float*)        (ws + 50331648);       // 16.8 MB: Xpm32 early, TR late
  float*          Xpm32 = TR;                                  // alias — disjoint live ranges
  unsigned short* H   = (unsigned short*)(ws + 67108864);      // 33.6 MB mlp hidden
  unsigned short* H2  = (unsigned short*)(ws + 100663296);     // 33.6 MB mlp hidden 2
  unsigned short* Wb  = (unsigned short*)(ws + 134217728);     // bf16 weights, contiguous
  unsigned short* projbw[3] = {Wb + 589824, Wb + 655360, Wb + 720896};
  unsigned short* tcwb  = Wb + 786432;
  unsigned short* trwb  = Wb + 851968;
  unsigned short* c1wb  = Wb + 1179648;
  unsigned short* c2wb  = Wb + 1441792;
  unsigned short* dwwT  = Wb + 1703936;
  float*          pm  = (float*)(ws + 134217728 + 3428352);    // 1024 f32 pool sums
  float*          pb  = pm + 1024;                             // 1024 f32 pool bias
  unsigned short* E3  = (unsigned short*)(ws + 140509184);     // 75.5 MB [N,2304] qkv x3
  unsigned short* F3  = (unsigned short*)(ws + 216006656);     // 25.2 MB [N,768] att x3

  k_cvt_all<<<dim3(160, 10), 256, 0, stream>>>(qkvw[0], qkvw[1], qkvw[2],
                                               projw[0], projw[1], projw[2],
                                               tcw, trw, c1w, c2w, Wb);
  k_dwwT<<<36, 256, 0, stream>>>(dww, dwwT, pm);
  k_transpose<<<dim3(64, 4, 4), 256, 0, stream>>>(x, Xpm, Xpm32, pm);
  k_ln<unsigned short><<<4096, 256, 0, stream>>>(Xpm, ln1w, ln1b, N1);
  k_poolfb<<<4, 256, 0, stream>>>(pm, poolw, bn2g, bn2b, trw, pb);

  // fused QKV: one GEMM over concatenated weights [2304,256] -> E3 [N,2304]
  k_gemm<0, 64><<<dim3(18, 256), 256, 0, stream>>>(N1, Wb, 256, 2304, 256, E3,
                                                   nullptr, nullptr, nullptr, nullptr, 0);
  // all 3 attention branches, lane-pair split
  k_attn3<<<3072, 256, 0, stream>>>(E3, F3);
  // grouped proj x3 + tc_conv -> CAT
  {
    GrpArgs ga;
    ga.A[0] = F3;       ga.A[1] = F3 + 256; ga.A[2] = F3 + 512; ga.A[3] = Xpm;
    ga.B[0] = projbw[0]; ga.B[1] = projbw[1]; ga.B[2] = projbw[2]; ga.B[3] = tcwb;
    ga.bias[0] = projb[0]; ga.bias[1] = projb[1]; ga.bias[2] = projb[2]; ga.bias[3] = tcb;
    ga.lda[0] = 768; ga.lda[1] = 768; ga.lda[2] = 768; ga.lda[3] = 256;
    ga.catoff[0] = 256; ga.catoff[1] = 512; ga.catoff[2] = 768; ga.catoff[3] = 0;
    k_gemm_grp<<<dim3(8, 256), 256, 0, stream>>>(ga, Xpm32, bn1g, bn1b, CAT);
  }
  k_gemm<3, 32><<<dim3(2, 512), 256, 0, stream>>>(CAT, trwb, 1024, 256, 1280, TR,
                                                  trb, bn3g, bn3b, pb, 0);
  k_ln<float><<<4096, 256, 0, stream>>>(TR, ln2w, ln2b, N1);   // N2 reuses N1
  k_gemm<4, 64><<<dim3(8, 256), 256, 0, stream>>>(N1, c1wb, 256, 1024, 256, H,
                                                  c1b, mbn1g, mbn1b, nullptr, 0);
  k_dwconv<<<8192, 256, 0, stream>>>(H, dwwT, dwb, mbn2g, mbn2b, H2);
  k_gemm<5, 32><<<dim3(2, 512), 256, 0, stream>>>(H2, c2wb, 1024, 256, 1024, d_out,
                                                  c2b, mbn3g, mbn3b, TR, 0);
}

// Round 11
// 398.281 us; speedup vs baseline: 2.0323x; 1.0098x over previous
//
#include <hip/hip_runtime.h>

#define N_PIX 16384
#define CDIM  256
#define HIDD  1024
#define BNS   0.9999950000374997f   // (1+1e-5)^-0.5

typedef __attribute__((ext_vector_type(8))) short  short8;
typedef __attribute__((ext_vector_type(4))) float  f32x4;
typedef __attribute__((ext_vector_type(4))) int    int4v;
typedef __attribute__((ext_vector_type(2))) int    int2v;

__device__ __forceinline__ float b2f(unsigned short u){
  unsigned int x = ((unsigned int)u) << 16; float f;
  __builtin_memcpy(&f, &x, 4); return f;
}
__device__ __forceinline__ unsigned short f2b(float f){
  unsigned int x; __builtin_memcpy(&x, &f, 4);
  unsigned int r = (x + 0x7fffu + ((x >> 16) & 1u)) >> 16;
  return (unsigned short)r;
}
__device__ __forceinline__ float geluf(float x){
  return 0.5f * x * (1.0f + erff(x * 0.70710678118654752f));
}

// async global->LDS DMA, 16B per lane, wave-uniform LDS base + lane*16
typedef const __attribute__((address_space(1))) unsigned int* gas_t;
typedef __attribute__((address_space(3))) unsigned int*       las_t;
__device__ __forceinline__ void gload16(const void* g, void* l){
  __builtin_amdgcn_global_load_lds((gas_t)g, (las_t)l, 16, 0, 0);
}

// ---------------- fused fp32 -> bf16 weight conversion (10 segments) ----------
__global__ __launch_bounds__(256) void k_cvt_all(
    const float* __restrict__ s0, const float* __restrict__ s1, const float* __restrict__ s2,
    const float* __restrict__ s3, const float* __restrict__ s4, const float* __restrict__ s5,
    const float* __restrict__ s6, const float* __restrict__ s7, const float* __restrict__ s8,
    const float* __restrict__ s9, unsigned short* __restrict__ wb){
  const float* srcs[10] = {s0,s1,s2,s3,s4,s5,s6,s7,s8,s9};
  const int n[10]   = {196608,196608,196608,65536,65536,65536,65536,327680,262144,262144};
  const int off[10] = {0,196608,393216,589824,655360,720896,786432,851968,1179648,1441792};
  int seg = blockIdx.y;
  int i = (blockIdx.x * 256 + threadIdx.x) * 8;
  if (i >= n[seg]) return;
  const float* src = srcs[seg];
  unsigned short* dst = wb + off[seg];
  f32x4 a = *(const f32x4*)(src + i);
  f32x4 b = *(const f32x4*)(src + i + 4);
  unsigned short o[8];
  #pragma unroll
  for (int j = 0; j < 4; ++j){ o[j] = f2b(a[j]); o[4 + j] = f2b(b[j]); }
  *(int4v*)(dst + i) = *(int4v*)o;
}

// ------ dw weights: [1024,1,3,3] f32 -> [9][1024] bf16 ; also zero pm ---------
__global__ __launch_bounds__(256) void k_dwwT(const float* __restrict__ dww,
                                              unsigned short* __restrict__ dwwT,
                                              float* __restrict__ pm){
  int i = blockIdx.x * 256 + threadIdx.x;     // 0..9215
  if (i < 1024) pm[i] = 0.0f;                 // zero pool accumulator (pre-transpose)
  if (i >= 9216) return;
  int kk = i >> 10, c = i & 1023;
  dwwT[i] = f2b(dww[c * 9 + kk]);
}

// transpose: x [B,C,4096] f32 -> Xpm [N,256] bf16 + Xpm32 [N,256] f32
// + accumulates per-(b,c) pixel sums into pm via atomics (pool path)
__global__ __launch_bounds__(256) void k_transpose(const float* __restrict__ x,
                                                   unsigned short* __restrict__ xpm,
                                                   float* __restrict__ xpm32,
                                                   float* __restrict__ pm){
  __shared__ __align__(16) float tile[64][65];
  int b = blockIdx.z, c0 = blockIdx.y * 64, p0 = blockIdx.x * 64;
  int t = threadIdx.x;
  int r = t >> 3, k = t & 7;
  float psum[2];
  for (int s = 0; s < 2; ++s){
    int rr = r + s * 32;
    const float* src = x + (((size_t)(b * CDIM + c0 + rr)) << 12) + p0 + k * 8;
    f32x4 a = *(const f32x4*)src;
    f32x4 c = *(const f32x4*)(src + 4);
    psum[s] = a[0] + a[1] + a[2] + a[3] + c[0] + c[1] + c[2] + c[3];
    #pragma unroll
    for (int j = 0; j < 4; ++j){ tile[rr][k * 8 + j] = a[j]; tile[rr][k * 8 + 4 + j] = c[j]; }
  }
  #pragma unroll
  for (int s = 0; s < 2; ++s){
    float v = psum[s];
    v += __shfl_xor(v, 1); v += __shfl_xor(v, 2); v += __shfl_xor(v, 4);
    if ((t & 7) == 0) atomicAdd(&pm[b * 256 + c0 + r + s * 32], v);
  }
  __syncthreads();
  for (int s = 0; s < 2; ++s){
    int pr = r + s * 32;
    float tf[8];
    unsigned short tb[8];
    #pragma unroll
    for (int j = 0; j < 8; ++j){ tf[j] = tile[k * 8 + j][pr]; tb[j] = f2b(tf[j]); }
    size_t rowoff = ((size_t)(b * 4096 + p0 + pr)) << 8;
    *(int4v*)(xpm + rowoff + c0 + k * 8) = *(int4v*)tb;
    *(f32x4*)(xpm32 + rowoff + c0 + k * 8)     = *(f32x4*)&tf[0];
    *(f32x4*)(xpm32 + rowoff + c0 + k * 8 + 4) = *(f32x4*)&tf[4];
  }
}

// ---------------- LayerNorm over C=256 (one row per wave) ----------------------
template<typename IT>
__global__ __launch_bounds__(256) void k_ln(const IT* __restrict__ in,
    const float* __restrict__ w, const float* __restrict__ bia,
    unsigned short* __restrict__ out){
  int row  = blockIdx.x * 4 + (threadIdx.x >> 6);
  int lane = threadIdx.x & 63;
  float v[4];
  const IT* p = in + (size_t)row * CDIM + lane * 4;
  if constexpr (sizeof(IT) == 2){
    int2v d = *(const int2v*)p;
    unsigned short tmp[4]; __builtin_memcpy(tmp, &d, 8);
    #pragma unroll
    for (int j = 0; j < 4; ++j) v[j] = b2f(tmp[j]);
  } else {
    f32x4 d = *(const f32x4*)p;
    #pragma unroll
    for (int j = 0; j < 4; ++j) v[j] = d[j];
  }
  float s  = v[0] + v[1] + v[2] + v[3];
  float s2 = v[0]*v[0] + v[1]*v[1] + v[2]*v[2] + v[3]*v[3];
  #pragma unroll
  for (int m = 1; m < 64; m <<= 1){
    s  += __shfl_xor(s,  m);
    s2 += __shfl_xor(s2, m);
  }
  float mu   = s * (1.0f / 256.0f);
  float var  = s2 * (1.0f / 256.0f) - mu * mu;
  float rstd = rsqrtf(var + 1e-5f);
  unsigned short o[4];
  #pragma unroll
  for (int j = 0; j < 4; ++j){
    int c = lane * 4 + j;
    o[j] = f2b((v[j] - mu) * rstd * w[c] + bia[c]);
  }
  *(int2v*)(out + (size_t)row * CDIM + lane * 4) = *(int2v*)o;
}

// ---------------- MFMA GEMM: C[M,Nout] = A[M,K] * Bw[Nout,ldb]^T + epilogue ----
// BMx128 tile, 4 waves, double-buffered global_load_lds staging.
// LDS XOR swizzle (both-sides): source chunk c -> c ^ ((row>>1)&3) pre-applied to
// the per-lane GLOBAL address (DMA dest stays linear); read chunk kb -> kb ^
// ((lr>>1)&3). Makes the quarter-wave ds_read_b128 hit all 8 bank-quads 2x
// (conflict-free) instead of 2 quads 8x.
// Counted-vmcnt barriers: s_waitcnt vmcnt(3) keeps next-tile prefetch in flight
// across the barrier (raw s_barrier, no vmcnt(0) drain).
template<int MODE, int BM>
__global__ __launch_bounds__(256) void k_gemm(
    const unsigned short* __restrict__ A, const unsigned short* __restrict__ Bw,
    int K, int Nout, int ldb, void* __restrict__ outp,
    const float* __restrict__ bias,
    const float* __restrict__ bng,
    const float* __restrict__ bnb,
    const float* __restrict__ auxf,   // MODE3: pool_bias; MODE5: TR f32
    int catoff)
{
  constexpr int NI = BM / 32;     // A fragments per wave
  __shared__ __align__(16) unsigned short As[2][BM * 32];
  __shared__ __align__(16) unsigned short Bs[2][128 * 32];
  int t = threadIdx.x;
  int m0 = blockIdx.y * BM, n0 = blockIdx.x * 128;
  int lane = t & 63;
  int w  = __builtin_amdgcn_readfirstlane(t >> 6);   // wave id (uniform)
  int wm = w >> 1, wn = w & 1;
  int lr = lane & 15, kb = lane >> 4;
  const bool doA = (w * 16 < BM);

  f32x4 acc[NI][4];
  f32x4 z = {0.f, 0.f, 0.f, 0.f};
  #pragma unroll
  for (int i = 0; i < NI; ++i)
    #pragma unroll
    for (int j = 0; j < 4; ++j) acc[i][j] = z;

  // staging: lane l -> LDS row l>>2 chunk l&3 (linear dest); swizzled source chunk
  int srow = lane >> 2;
  int schunk = (((lane & 3) ^ ((lane >> 3) & 3))) * 8;
  const unsigned short* gA  = A  + (size_t)(m0 + w * 16 + srow) * K   + schunk;
  const unsigned short* gB0 = Bw + (size_t)(n0 + w * 16 + srow) * ldb + schunk;
  const unsigned short* gB1 = Bw + (size_t)(n0 + 64 + w * 16 + srow) * ldb + schunk;
  int kbx = (kb ^ ((lr >> 1) & 3)) * 8;   // swizzled read chunk (shorts)

  const int nt = K >> 5;
  if (doA) gload16(gA, As[0] + w * 512);
  gload16(gB0, Bs[0] + w * 512);
  gload16(gB1, Bs[0] + 2048 + w * 512);

  for (int tt = 0; tt < nt; ++tt){
    int cur = tt & 1;
    if (tt + 1 < nt){
      int k1 = (tt + 1) << 5;
      if (doA) gload16(gA + k1, As[cur ^ 1] + w * 512);
      gload16(gB0 + k1, Bs[cur ^ 1] + w * 512);
      gload16(gB1 + k1, Bs[cur ^ 1] + 2048 + w * 512);
      if (doA) asm volatile("s_waitcnt vmcnt(3)" ::: "memory");
      else     asm volatile("s_waitcnt vmcnt(2)" ::: "memory");
    } else {
      asm volatile("s_waitcnt vmcnt(0)" ::: "memory");
    }
    __builtin_amdgcn_s_barrier();          // all waves' tile-tt loads landed
    short8 af[NI], bf_[4];
    #pragma unroll
    for (int i = 0; i < NI; ++i)
      af [i] = *(const short8*)&As[cur][(wm * (BM / 2) + i * 16 + lr) * 32 + kbx];
    #pragma unroll
    for (int j = 0; j < 4; ++j)
      bf_[j] = *(const short8*)&Bs[cur][(wn * 64 + j * 16 + lr) * 32 + kbx];
    #pragma unroll
    for (int i = 0; i < NI; ++i)
      #pragma unroll
      for (int j = 0; j < 4; ++j)
        acc[i][j] = __builtin_amdgcn_mfma_f32_16x16x32_bf16(af[i], bf_[j], acc[i][j], 0, 0, 0);
    asm volatile("s_waitcnt lgkmcnt(0)" ::: "memory");  // LDS reads drained
    __builtin_amdgcn_sched_barrier(0);
    __builtin_amdgcn_s_barrier();          // buffer free for next overwrite
  }

  #pragma unroll
  for (int i = 0; i < NI; ++i){
    int rowb = m0 + wm * (BM / 2) + i * 16 + kb * 4;
    #pragma unroll
    for (int j = 0; j < 4; ++j){
      int col = n0 + wn * 64 + j * 16 + lr;
      #pragma unroll
      for (int rr = 0; rr < 4; ++rr){
        int row = rowb + rr;
        float v = acc[i][j][rr];
        if constexpr (MODE == 0){            // QKV fused: plain bf16 store [N,2304]
          ((unsigned short*)outp)[(size_t)row * Nout + col] = f2b(v);
        } else if constexpr (MODE == 3){     // tc_trans: + bias + pool_bias, bn3, relu -> TR f32
          v += bias[col] + auxf[((row >> 12) << 8) + col];
          v = v * (bng[col] * BNS) + bnb[col];
          v = fmaxf(v, 0.0f);
          ((float*)outp)[(size_t)row * CDIM + col] = v;
        } else if constexpr (MODE == 4){     // mlp_c1: bias, gelu, bn1 -> H bf16
          v = geluf(v + bias[col]);
          v = v * (bng[col] * BNS) + bnb[col];
          ((unsigned short*)outp)[(size_t)row * HIDD + col] = f2b(v);
        } else {                             // MODE 5: mlp_c2: bias, bn3, +TR, store NCHW f32
          v = (v + bias[col]) * (bng[col] * BNS) + bnb[col];
          v += auxf[(size_t)row * CDIM + col];
          int b = row >> 12, hw = row & 4095;
          ((float*)outp)[(((size_t)(b * CDIM + col)) << 12) + hw] = v;
        }
      }
    }
  }
}

// -------- grouped GEMM: groups 0-2 = proj_i (bias+residual->CAT), 3 = tc_conv --
struct GrpArgs {
  const unsigned short* A[4];
  const unsigned short* B[4];
  const float* bias[4];
  int lda[4];
  int catoff[4];
};

__global__ __launch_bounds__(256) void k_gemm_grp(GrpArgs ga,
    const float* __restrict__ xpm32, const float* __restrict__ bng,
    const float* __restrict__ bnb, unsigned short* __restrict__ CAT)
{
  __shared__ __align__(16) unsigned short As[2][64 * 32];
  __shared__ __align__(16) unsigned short Bs[2][128 * 32];
  int t = threadIdx.x;
  int g  = blockIdx.x >> 1;               // group 0..3 (uniform)
  int n0 = (blockIdx.x & 1) * 128;        // column tile within group's 256
  int m0 = blockIdx.y * 64;
  const unsigned short* A  = ga.A[g];
  const unsigned short* Bw = ga.B[g];
  const float* bias = ga.bias[g];
  int lda = ga.lda[g];
  int catoff = ga.catoff[g];

  int lane = t & 63;
  int w  = __builtin_amdgcn_readfirstlane(t >> 6);
  int wm = w >> 1, wn = w & 1;
  int lr = lane & 15, kb = lane >> 4;

  f32x4 acc[2][4];
  f32x4 z = {0.f, 0.f, 0.f, 0.f};
  #pragma unroll
  for (int i = 0; i < 2; ++i)
    #pragma unroll
    for (int j = 0; j < 4; ++j) acc[i][j] = z;

  int srow = lane >> 2;
  int schunk = (((lane & 3) ^ ((lane >> 3) & 3))) * 8;
  const unsigned short* gA  = A  + (size_t)(m0 + w * 16 + srow) * lda + schunk;
  const unsigned short* gB0 = Bw + (size_t)(n0 + w * 16 + srow) * 256 + schunk;
  const unsigned short* gB1 = Bw + (size_t)(n0 + 64 + w * 16 + srow) * 256 + schunk;
  int kbx = (kb ^ ((lr >> 1) & 3)) * 8;

  gload16(gA,  As[0] + w * 512);
  gload16(gB0, Bs[0] + w * 512);
  gload16(gB1, Bs[0] + 2048 + w * 512);

  for (int tt = 0; tt < 8; ++tt){         // K = 256
    int cur = tt & 1;
    if (tt + 1 < 8){
      int k1 = (tt + 1) << 5;
      gload16(gA  + k1, As[cur ^ 1] + w * 512);
      gload16(gB0 + k1, Bs[cur ^ 1] + w * 512);
      gload16(gB1 + k1, Bs[cur ^ 1] + 2048 + w * 512);
      asm volatile("s_waitcnt vmcnt(3)" ::: "memory");
    } else {
      asm volatile("s_waitcnt vmcnt(0)" ::: "memory");
    }
    __builtin_amdgcn_s_barrier();
    short8 af[2], bf_[4];
    #pragma unroll
    for (int i = 0; i < 2; ++i)
      af [i] = *(const short8*)&As[cur][(wm * 32 + i * 16 + lr) * 32 + kbx];
    #pragma unroll
    for (int j = 0; j < 4; ++j)
      bf_[j] = *(const short8*)&Bs[cur][(wn * 64 + j * 16 + lr) * 32 + kbx];
    #pragma unroll
    for (int i = 0; i < 2; ++i)
      #pragma unroll
      for (int j = 0; j < 4; ++j)
        acc[i][j] = __builtin_amdgcn_mfma_f32_16x16x32_bf16(af[i], bf_[j], acc[i][j], 0, 0, 0);
    asm volatile("s_waitcnt lgkmcnt(0)" ::: "memory");
    __builtin_amdgcn_sched_barrier(0);
    __builtin_amdgcn_s_barrier();
  }

  #pragma unroll
  for (int i = 0; i < 2; ++i){
    int rowb = m0 + wm * 32 + i * 16 + kb * 4;
    #pragma unroll
    for (int j = 0; j < 4; ++j){
      int col = n0 + wn * 64 + j * 16 + lr;
      #pragma unroll
      for (int rr = 0; rr < 4; ++rr){
        int row = rowb + rr;
        float v = acc[i][j][rr];
        if (g == 3){                         // tc_conv: bias, bn1, relu
          v = (v + bias[col]) * (bng[col] * BNS) + bnb[col];
          v = fmaxf(v, 0.0f);
        } else {                             // proj: bias + residual(Xpm32)
          v += bias[col] + xpm32[(size_t)row * CDIM + col];
        }
        CAT[(size_t)row * HIDD + catoff + col] = f2b(v);
      }
    }
  }
}

// -------- atrous attention, lane-pair split: thread = (pix, head, half16) ------
__global__ __launch_bounds__(256) void k_attn3(const unsigned short* __restrict__ QKV3,
                                               unsigned short* __restrict__ F3){
  int grp = blockIdx.x >> 10;                 // 0..2, r = grp+1
  int r = grp + 1;
  int t = (blockIdx.x & 1023) * 256 + threadIdx.x;  // 0 .. 262143
  int half = t & 1, head = (t >> 1) & 7, pix = t >> 4;
  int hw = pix & 4095, h = hw >> 6, w = hw & 63;
  const unsigned short* base = QKV3 + (size_t)pix * 2304 + grp * 768 + head * 32 + half * 16;

  float q[16];
  #pragma unroll
  for (int c8 = 0; c8 < 2; ++c8){
    int4v d = *(const int4v*)(base + c8 * 8);
    unsigned short tmp[8]; __builtin_memcpy(tmp, &d, 16);
    #pragma unroll
    for (int j = 0; j < 8; ++j) q[c8 * 8 + j] = b2f(tmp[j]);
  }
  float logit[9];
  #pragma unroll
  for (int jj = 0; jj < 9; ++jj){
    int dh = (jj / 3 - 1) * r, dw = (jj % 3 - 1) * r;
    int hh = h + dh, ww = w + dw;
    float d = 0.0f;
    if (hh >= 0 && hh < 64 && ww >= 0 && ww < 64){
      const unsigned short* kr = base + (dh * 64 + dw) * 2304 + 256;
      #pragma unroll
      for (int c8 = 0; c8 < 2; ++c8){
        int4v dd = *(const int4v*)(kr + c8 * 8);
        unsigned short tmp[8]; __builtin_memcpy(tmp, &dd, 16);
        #pragma unroll
        for (int j = 0; j < 8; ++j) d += q[c8 * 8 + j] * b2f(tmp[j]);
      }
    }
    d += __shfl_xor(d, 1);                  // combine the two 16-channel halves
    logit[jj] = d * 0.17677669529663687f;   // hd^-0.5; OOB taps keep logit 0 (zero-pad)
  }
  float m = logit[0];
  #pragma unroll
  for (int jj = 1; jj < 9; ++jj) m = fmaxf(m, logit[jj]);
  float p[9], s = 0.0f;
  #pragma unroll
  for (int jj = 0; jj < 9; ++jj){ p[jj] = __expf(logit[jj] - m); s += p[jj]; }
  float inv = 1.0f / s;
  float o[16];
  #pragma unroll
  for (int j = 0; j < 16; ++j) o[j] = 0.0f;
  #pragma unroll
  for (int jj = 0; jj < 9; ++jj){
    int dh = (jj / 3 - 1) * r, dw = (jj % 3 - 1) * r;
    int hh = h + dh, ww = w + dw;
    if (hh >= 0 && hh < 64 && ww >= 0 && ww < 64){
      float pj = p[jj] * inv;
      const unsigned short* vr = base + (dh * 64 + dw) * 2304 + 512;
      #pragma unroll
      for (int c8 = 0; c8 < 2; ++c8){
        int4v dd = *(const int4v*)(vr + c8 * 8);
        unsigned short tmp[8]; __builtin_memcpy(tmp, &dd, 16);
        #pragma unroll
        for (int j = 0; j < 8; ++j) o[c8 * 8 + j] += pj * b2f(tmp[j]);
      }
    }
  }
  unsigned short ob[16];
  #pragma unroll
  for (int j = 0; j < 16; ++j) ob[j] = f2b(o[j]);
  unsigned short* op = F3 + (size_t)pix * 768 + grp * 256 + head * 32 + half * 16;
  *(int4v*)(op)     = *(int4v*)&ob[0];
  *(int4v*)(op + 8) = *(int4v*)&ob[8];
}

// ---------------- depthwise 3x3 + gelu + bn2 -----------------------------------
__global__ __launch_bounds__(256) void k_dwconv(const unsigned short* __restrict__ H,
    const unsigned short* __restrict__ dwwT, const float* __restrict__ dwb,
    const float* __restrict__ g, const float* __restrict__ bb,
    unsigned short* __restrict__ H2){
  int t = blockIdx.x * 256 + threadIdx.x;   // 16384 * 128
  int chunk = t & 127, pix = t >> 7;
  int hw = pix & 4095, h = hw >> 6, w = hw & 63;
  int c0 = chunk * 8;
  float acc[8], hc[8];
  {
    int4v dd = *(const int4v*)(H + (size_t)pix * HIDD + c0);
    unsigned short tmp[8]; __builtin_memcpy(tmp, &dd, 16);
    #pragma unroll
    for (int j = 0; j < 8; ++j){ hc[j] = b2f(tmp[j]); acc[j] = 0.0f; }
  }
  #pragma unroll
  for (int di = -1; di <= 1; ++di)
    #pragma unroll
    for (int dj = -1; dj <= 1; ++dj){
      int hh = h + di, ww = w + dj;
      if (hh < 0 || hh >= 64 || ww < 0 || ww >= 64) continue;
      int kk = (di + 1) * 3 + (dj + 1);
      int4v dd = *(const int4v*)(H + ((size_t)(pix + di * 64 + dj)) * HIDD + c0);
      int4v wv = *(const int4v*)(dwwT + kk * 1024 + c0);
      unsigned short tmp[8], wt[8];
      __builtin_memcpy(tmp, &dd, 16);
      __builtin_memcpy(wt,  &wv, 16);
      #pragma unroll
      for (int j = 0; j < 8; ++j) acc[j] += b2f(wt[j]) * b2f(tmp[j]);
    }
  f32x4 bv0 = *(const f32x4*)(dwb + c0), bv1 = *(const f32x4*)(dwb + c0 + 4);
  f32x4 gv0 = *(const f32x4*)(g   + c0), gv1 = *(const f32x4*)(g   + c0 + 4);
  f32x4 cv0 = *(const f32x4*)(bb  + c0), cv1 = *(const f32x4*)(bb  + c0 + 4);
  float bvv[8], gvv[8], cvv[8];
  #pragma unroll
  for (int j = 0; j < 4; ++j){
    bvv[j] = bv0[j]; bvv[4 + j] = bv1[j];
    gvv[j] = gv0[j]; gvv[4 + j] = gv1[j];
    cvv[j] = cv0[j]; cvv[4 + j] = cv1[j];
  }
  unsigned short ob[8];
  #pragma unroll
  for (int j = 0; j < 8; ++j){
    float v = acc[j] + bvv[j] + hc[j];
    v = geluf(v);
    v = v * (gvv[j] * BNS) + cvv[j];
    ob[j] = f2b(v);
  }
  *(int4v*)(H2 + (size_t)pix * HIDD + c0) = *(int4v*)ob;
}

// fused pool tail: pf = relu(bn(poolw @ mean)); pb = trw[:,1024:1280] @ pf
__global__ __launch_bounds__(256) void k_poolfb(const float* __restrict__ pm,
    const float* __restrict__ pw, const float* __restrict__ g,
    const float* __restrict__ bb, const float* __restrict__ tw,
    float* __restrict__ pb){
  int b = blockIdx.x, o = threadIdx.x;
  __shared__ float v[256];
  __shared__ float pfs[256];
  v[o] = pm[b * 256 + o] * (1.0f / 4096.0f);
  __syncthreads();
  float acc = 0.0f;
  const float* wr = pw + (size_t)o * 256;
  for (int c = 0; c < 256; ++c) acc += v[c] * wr[c];
  float val = acc * (g[o] * BNS) + bb[o];
  pfs[o] = fmaxf(val, 0.0f);
  __syncthreads();
  float acc2 = 0.0f;
  const float* tr = tw + (size_t)o * 1280 + 1024;
  for (int c = 0; c < 256; ++c) acc2 += pfs[c] * tr[c];
  pb[b * 256 + o] = acc2;
}

// ---------------- launch -------------------------------------------------------
extern "C" void kernel_launch(void* const* d_in, const int* in_sizes, int n_in,
                              void* d_out, int out_size, void* d_ws, size_t ws_size,
                              hipStream_t stream){
  const float* x     = (const float*)d_in[0];
  const float* ln1w  = (const float*)d_in[1];
  const float* ln1b  = (const float*)d_in[2];
  const float* ln2w  = (const float*)d_in[3];
  const float* ln2b  = (const float*)d_in[4];
  const float* qkvw[3]  = {(const float*)d_in[5], (const float*)d_in[8],  (const float*)d_in[11]};
  const float* projw[3] = {(const float*)d_in[6], (const float*)d_in[9],  (const float*)d_in[12]};
  const float* projb[3] = {(const float*)d_in[7], (const float*)d_in[10], (const float*)d_in[13]};
  const float* tcw   = (const float*)d_in[14];
  const float* tcb   = (const float*)d_in[15];
  const float* bn1g  = (const float*)d_in[16];
  const float* bn1b  = (const float*)d_in[17];
  const float* poolw = (const float*)d_in[18];
  const float* bn2g  = (const float*)d_in[19];
  const float* bn2b  = (const float*)d_in[20];
  const float* trw   = (const float*)d_in[21];
  const float* trb   = (const float*)d_in[22];
  const float* bn3g  = (const float*)d_in[23];
  const float* bn3b  = (const float*)d_in[24];
  const float* c1w   = (const float*)d_in[25];
  const float* c1b   = (const float*)d_in[26];
  const float* mbn1g = (const float*)d_in[27];
  const float* mbn1b = (const float*)d_in[28];
  const float* dww   = (const float*)d_in[29];
  const float* dwb   = (const float*)d_in[30];
  const float* mbn2g = (const float*)d_in[31];
  const float* mbn2b = (const float*)d_in[32];
  const float* c2w   = (const float*)d_in[33];
  const float* c2b   = (const float*)d_in[34];
  const float* mbn3g = (const float*)d_in[35];
  const float* mbn3b = (const float*)d_in[36];

  char* ws = (char*)d_ws;
  unsigned short* Xpm = (unsigned short*)(ws);                 //  8.4 MB [N,256] bf16
  unsigned short* N1  = (unsigned short*)(ws + 8388608);       //  8.4 MB [N,256] (later N2)
  unsigned short* CAT = (unsigned short*)(ws + 16777216);      // 33.6 MB [N,1024]
  float*          TR  = (float*)        (ws + 50331648);       // 16.8 MB: Xpm32 early, TR late
  float*          Xpm32 = TR;                                  // alias — disjoint live ranges
  unsigned short* H   = (unsigned short*)(ws + 67108864);      // 33.6 MB mlp hidden
  unsigned short* H2  = (unsigned short*)(ws + 100663296);     // 33.6 MB mlp hidden 2
  unsigned short* Wb  = (unsigned short*)(ws + 134217728);     // bf16 weights, contiguous
  unsigned short* projbw[3] = {Wb + 589824, Wb + 655360, Wb + 720896};
  unsigned short* tcwb  = Wb + 786432;
  unsigned short* trwb  = Wb + 851968;
  unsigned short* c1wb  = Wb + 1179648;
  unsigned short* c2wb  = Wb + 1441792;
  unsigned short* dwwT  = Wb + 1703936;
  float*          pm  = (float*)(ws + 134217728 + 3428352);    // 1024 f32 pool sums
  float*          pb  = pm + 1024;                             // 1024 f32 pool bias
  unsigned short* E3  = (unsigned short*)(ws + 140509184);     // 75.5 MB [N,2304] qkv x3
  unsigned short* F3  = (unsigned short*)(ws + 216006656);     // 25.2 MB [N,768] att x3

  k_cvt_all<<<dim3(160, 10), 256, 0, stream>>>(qkvw[0], qkvw[1], qkvw[2],
                                               projw[0], projw[1], projw[2],
                                               tcw, trw, c1w, c2w, Wb);
  k_dwwT<<<36, 256, 0, stream>>>(dww, dwwT, pm);
  k_transpose<<<dim3(64, 4, 4), 256, 0, stream>>>(x, Xpm, Xpm32, pm);
  k_ln<unsigned short><<<4096, 256, 0, stream>>>(Xpm, ln1w, ln1b, N1);
  k_poolfb<<<4, 256, 0, stream>>>(pm, poolw, bn2g, bn2b, trw, pb);

  // fused QKV: one GEMM over concatenated weights [2304,256] -> E3 [N,2304]
  k_gemm<0, 64><<<dim3(18, 256), 256, 0, stream>>>(N1, Wb, 256, 2304, 256, E3,
                                                   nullptr, nullptr, nullptr, nullptr, 0);
  // all 3 attention branches, lane-pair split
  k_attn3<<<3072, 256, 0, stream>>>(E3, F3);
  // grouped proj x3 + tc_conv -> CAT
  {
    GrpArgs ga;
    ga.A[0] = F3;       ga.A[1] = F3 + 256; ga.A[2] = F3 + 512; ga.A[3] = Xpm;
    ga.B[0] = projbw[0]; ga.B[1] = projbw[1]; ga.B[2] = projbw[2]; ga.B[3] = tcwb;
    ga.bias[0] = projb[0]; ga.bias[1] = projb[1]; ga.bias[2] = projb[2]; ga.bias[3] = tcb;
    ga.lda[0] = 768; ga.lda[1] = 768; ga.lda[2] = 768; ga.lda[3] = 256;
    ga.catoff[0] = 256; ga.catoff[1] = 512; ga.catoff[2] = 768; ga.catoff[3] = 0;
    k_gemm_grp<<<dim3(8, 256), 256, 0, stream>>>(ga, Xpm32, bn1g, bn1b, CAT);
  }
  k_gemm<3, 32><<<dim3(2, 512), 256, 0, stream>>>(CAT, trwb, 1024, 256, 1280, TR,
                                                  trb, bn3g, bn3b, pb, 0);
  k_ln<float><<<4096, 256, 0, stream>>>(TR, ln2w, ln2b, N1);   // N2 reuses N1
  k_gemm<4, 64><<<dim3(8, 256), 256, 0, stream>>>(N1, c1wb, 256, 1024, 256, H,
                                                  c1b, mbn1g, mbn1b, nullptr, 0);
  k_dwconv<<<8192, 256, 0, stream>>>(H, dwwT, dwb, mbn2g, mbn2b, H2);
  k_gemm<5, 32><<<dim3(2, 512), 256, 0, stream>>>(H2, c2wb, 1024, 256, 1024, d_out,
                                                  c2b, mbn3g, mbn3b, TR, 0);
}